// Round 1
// baseline (1854.387 us; speedup 1.0000x reference)
//
#include <hip/hip_runtime.h>

#define BB 8
#define NP 4096    // NPTS == NQ
#define NN 1024
#define NE 8192
#define FF 256
#define TS 264     // padded LDS row stride (words) for [32][256] tiles
#define NSTEP 16

// ---------------- graph preprocessing ----------------
__global__ __launch_bounds__(256) void k_deg_init(int* degI) {
  int n = blockIdx.x * 256 + threadIdx.x;
  if (n < NN) degI[n] = 1;                       // self loop
}

__global__ __launch_bounds__(256) void k_deg_count(const int* dst, int* degI) {
  int e = blockIdx.x * 256 + threadIdx.x;
  if (e < NE) atomicAdd(&degI[dst[e]], 1);       // int atomics: deterministic
}

__global__ __launch_bounds__(1024) void k_scan(const int* degI, float* dinv, int* csr_off) {
  __shared__ int s[NN];
  int n = threadIdx.x;
  int c = degI[n];
  dinv[n] = rsqrtf((float)c);                    // deg >= 1 always
  s[n] = c;
  __syncthreads();
  for (int st = 1; st < NN; st <<= 1) {
    int v = (n >= st) ? s[n - st] : 0;
    __syncthreads();
    s[n] += v;
    __syncthreads();
  }
  csr_off[n] = s[n] - c;
  if (n == NN - 1) csr_off[NN] = s[n];
}

__global__ __launch_bounds__(256) void k_fill(const int* srcA, const int* dstA,
    const float* dinv, const int* csr_off, int* csr_src, float* csr_w) {
  int t = blockIdx.x * 256 + threadIdx.x;
  if (t < NE) {
    int d = dstA[t];
    int rank = 0;
    for (int e = 0; e < t; e++) rank += (dstA[e] == d) ? 1 : 0;  // stable order
    int pos = csr_off[d] + rank;
    int sv = srcA[t];
    csr_src[pos] = sv;
    csr_w[pos] = dinv[sv] * dinv[d];
  } else if (t < NE + NN) {
    int n = t - NE;
    int pos = csr_off[n + 1] - 1;                // self loop last
    csr_src[pos] = n;
    csr_w[pos] = dinv[n] * dinv[n];
  }
}

__global__ __launch_bounds__(256) void k_spos(const float* npos, const int* csr_off,
    const int* csr_src, const float* csr_w, float* spos) {
  int n = blockIdx.x * 256 + threadIdx.x;
  if (n >= NN) return;
  float sx = 0.f, sy = 0.f;
  int e1 = csr_off[n + 1];
  for (int e = csr_off[n]; e < e1; e++) {
    float w = csr_w[e]; int s = csr_src[e];
    sx += w * npos[2 * s]; sy += w * npos[2 * s + 1];
  }
  spos[2 * n] = sx; spos[2 * n + 1] = sy;
}

// ---------------- softmax stats (max, 1/sum) per point ----------------
__global__ __launch_bounds__(256) void k_stats(const float* xy, const float* npos,
                                               float* mOut, float* liOut) {
  int wv = threadIdx.x >> 6, lane = threadIdx.x & 63;
  int pt = blockIdx.x * 4 + wv;
  float px = xy[pt * 2], py = xy[pt * 2 + 1];
  float s[16];
  float m = -1e30f;
  #pragma unroll
  for (int k = 0; k < 16; k++) {
    int n = lane + 64 * k;
    float2 np = ((const float2*)npos)[n];
    float dx = px - np.x, dy = py - np.y;
    float v = -(dx * dx + dy * dy);
    s[k] = v; m = fmaxf(m, v);
  }
  #pragma unroll
  for (int o = 32; o; o >>= 1) m = fmaxf(m, __shfl_xor(m, o));
  float l = 0.f;
  #pragma unroll
  for (int k = 0; k < 16; k++) l += __expf(s[k] - m);
  #pragma unroll
  for (int o = 32; o; o >>= 1) l += __shfl_xor(l, o);
  if (lane == 0) { mOut[pt] = m; liOut[pt] = 1.0f / l; }
}

// ---------------- encoder MLP: enc = relu(cat(x,y)@We1+b)@We2+b ----------------
__global__ __launch_bounds__(256) void k_encoder(const float* inx, const float* iny,
    const float* We1, const float* be1, const float* We2, const float* be2, float* enc) {
  __shared__ float xin[32][8];
  __shared__ float h[32][TS];
  __shared__ float wc[32][TS];
  int tid = threadIdx.x;
  int row0 = blockIdx.x * 32;
  if (tid < 160) {
    int pt = tid / 5, d = tid % 5;
    int r = row0 + pt;
    xin[pt][d] = (d < 2) ? inx[r * 2 + d] : iny[r * 3 + (d - 2)];
  }
  __syncthreads();
  {
    int f = tid;
    float w0 = We1[f], w1 = We1[256 + f], w2 = We1[512 + f], w3 = We1[768 + f], w4 = We1[1024 + f];
    float bb = be1[f];
    #pragma unroll 4
    for (int pt = 0; pt < 32; pt++) {
      float v = bb + xin[pt][0]*w0 + xin[pt][1]*w1 + xin[pt][2]*w2 + xin[pt][3]*w3 + xin[pt][4]*w4;
      h[pt][f] = fmaxf(v, 0.f);
    }
  }
  int fgrp = tid & 31, rgrp = tid >> 5, r0 = rgrp * 4;
  float2 acc[4][4];
  #pragma unroll
  for (int j = 0; j < 4; j++) {
    float2 b2 = *(const float2*)&be2[fgrp * 2 + j * 64];
    #pragma unroll
    for (int i = 0; i < 4; i++) acc[i][j] = b2;
  }
  for (int kc = 0; kc < 8; kc++) {
    __syncthreads();
    float v[32];
    #pragma unroll
    for (int it = 0; it < 32; it++) v[it] = We2[(kc * 32 + it) * FF + tid];
    #pragma unroll
    for (int it = 0; it < 32; it++) wc[it][tid] = v[it];
    __syncthreads();
    for (int kk = 0; kk < 32; kk++) {
      int k = kc * 32 + kk;
      float c0 = h[r0 + 0][k], c1 = h[r0 + 1][k], c2 = h[r0 + 2][k], c3 = h[r0 + 3][k];
      #pragma unroll
      for (int j = 0; j < 4; j++) {
        float2 w = *(const float2*)&wc[kk][fgrp * 2 + j * 64];
        acc[0][j].x += c0 * w.x; acc[0][j].y += c0 * w.y;
        acc[1][j].x += c1 * w.x; acc[1][j].y += c1 * w.y;
        acc[2][j].x += c2 * w.x; acc[2][j].y += c2 * w.y;
        acc[3][j].x += c3 * w.x; acc[3][j].y += c3 * w.y;
      }
    }
  }
  #pragma unroll
  for (int i = 0; i < 4; i++) {
    int r = row0 + r0 + i;
    #pragma unroll
    for (int j = 0; j < 4; j++)
      *(float2*)&enc[r * FF + fgrp * 2 + j * 64] = acc[i][j];
  }
}

// ---------------- projection 1: x[b,n,f] = sum_p coord[b,p,n]*enc[b,p,f] ----------------
__global__ __launch_bounds__(256) void k_proj1(const float* inx, const float* mI,
    const float* liI, const float* npos, const float* enc, float* x) {
  __shared__ float et[32][TS];
  __shared__ float ct[32][36];
  __shared__ float pd[32][4];
  int tid = threadIdx.x;
  int b = blockIdx.y;
  int n0 = blockIdx.x * 32;
  int fgrp = tid & 31, rgrp = tid >> 5, r0 = rgrp * 4;
  int cr = tid & 31, cj = tid >> 5;
  float2 np = ((const float2*)npos)[n0 + cr];
  float2 acc[4][4];
  #pragma unroll
  for (int i = 0; i < 4; i++)
    #pragma unroll
    for (int j = 0; j < 4; j++) acc[i][j] = make_float2(0.f, 0.f);
  for (int pc = 0; pc < NP / 32; pc++) {
    int p0 = b * NP + pc * 32;
    if (tid < 128) {
      int j = tid >> 2, c = tid & 3;
      int pr = p0 + j;
      pd[j][c] = (c == 0) ? inx[pr * 2] : (c == 1) ? inx[pr * 2 + 1] : (c == 2) ? mI[pr] : liI[pr];
    }
    {
      float v[32];
      #pragma unroll
      for (int it = 0; it < 32; it++) v[it] = enc[(p0 + it) * FF + tid];
      #pragma unroll
      for (int it = 0; it < 32; it++) et[it][tid] = v[it];
    }
    __syncthreads();
    #pragma unroll
    for (int jj = 0; jj < 4; jj++) {
      int j = cj * 4 + jj;
      float dx = pd[j][0] - np.x, dy = pd[j][1] - np.y;
      ct[j][cr] = __expf(-(dx * dx + dy * dy) - pd[j][2]) * pd[j][3];
    }
    __syncthreads();
    for (int j = 0; j < 32; j++) {
      float4 cv = *(const float4*)&ct[j][r0];
      #pragma unroll
      for (int jj = 0; jj < 4; jj++) {
        float2 w = *(const float2*)&et[j][fgrp * 2 + jj * 64];
        acc[0][jj].x += cv.x * w.x; acc[0][jj].y += cv.x * w.y;
        acc[1][jj].x += cv.y * w.x; acc[1][jj].y += cv.y * w.y;
        acc[2][jj].x += cv.z * w.x; acc[2][jj].y += cv.z * w.y;
        acc[3][jj].x += cv.w * w.x; acc[3][jj].y += cv.w * w.y;
      }
    }
    __syncthreads();
  }
  #pragma unroll
  for (int i = 0; i < 4; i++) {
    int r = b * NN + n0 + r0 + i;
    #pragma unroll
    for (int j = 0; j < 4; j++)
      *(float2*)&x[r * FF + fgrp * 2 + j * 64] = acc[i][j];
  }
}

// ---------------- projection 2: lat[b,q,f] = sum_n coord[b,q,n]*x[b,n,f] ----------------
__global__ __launch_bounds__(256) void k_proj2(const float* qxy, const float* mQ,
    const float* liQ, const float* npos, const float* x, float* lat) {
  __shared__ float xt[32][TS];
  __shared__ float ct[32][36];
  int tid = threadIdx.x;
  int b = blockIdx.y;
  int q0 = blockIdx.x * 32;
  int fgrp = tid & 31, rgrp = tid >> 5, r0 = rgrp * 4;
  int cr = tid & 31, cj = tid >> 5;
  int qr = b * NP + q0 + cr;
  float qx = qxy[qr * 2], qy = qxy[qr * 2 + 1], m = mQ[qr], li = liQ[qr];
  float2 acc[4][4];
  #pragma unroll
  for (int i = 0; i < 4; i++)
    #pragma unroll
    for (int j = 0; j < 4; j++) acc[i][j] = make_float2(0.f, 0.f);
  for (int nc = 0; nc < NN / 32; nc++) {
    int nb = nc * 32;
    {
      float v[32];
      #pragma unroll
      for (int it = 0; it < 32; it++) v[it] = x[(b * NN + nb + it) * FF + tid];
      #pragma unroll
      for (int it = 0; it < 32; it++) xt[it][tid] = v[it];
    }
    #pragma unroll
    for (int jj = 0; jj < 4; jj++) {
      int j = cj * 4 + jj;
      float2 np = ((const float2*)npos)[nb + j];
      float dx = qx - np.x, dy = qy - np.y;
      ct[j][cr] = __expf(-(dx * dx + dy * dy) - m) * li;
    }
    __syncthreads();
    for (int j = 0; j < 32; j++) {
      float4 cv = *(const float4*)&ct[j][r0];
      #pragma unroll
      for (int jj = 0; jj < 4; jj++) {
        float2 w = *(const float2*)&xt[j][fgrp * 2 + jj * 64];
        acc[0][jj].x += cv.x * w.x; acc[0][jj].y += cv.x * w.y;
        acc[1][jj].x += cv.y * w.x; acc[1][jj].y += cv.y * w.y;
        acc[2][jj].x += cv.z * w.x; acc[2][jj].y += cv.z * w.y;
        acc[3][jj].x += cv.w * w.x; acc[3][jj].y += cv.w * w.y;
      }
    }
    __syncthreads();
  }
  #pragma unroll
  for (int i = 0; i < 4; i++) {
    int r = b * NP + q0 + r0 + i;
    #pragma unroll
    for (int j = 0; j < 4; j++)
      *(float2*)&lat[r * FF + fgrp * 2 + j * 64] = acc[i][j];
  }
}

// ---------------- fused msg step: LN(x + (S@cat(pos,x))@Wg + bg) ----------------
__global__ __launch_bounds__(256) void k_msg(const float* x_in, float* x_out,
    const float* spos, const int* csr_off, const int* csr_src, const float* csr_w,
    const float* Wg, const float* bg, const float* lng, const float* lnb) {
  __shared__ float st[32][TS];
  __shared__ float wc[32][TS];
  int tid = threadIdx.x;
  int b = blockIdx.y;
  int n0 = blockIdx.x * 32;
  {
    int gr = tid >> 3, sub = tid & 7;
    int n = n0 + gr;
    float4 sa[8];
    #pragma unroll
    for (int mm = 0; mm < 8; mm++) sa[mm] = make_float4(0.f, 0.f, 0.f, 0.f);
    int e1 = csr_off[n + 1];
    for (int e = csr_off[n]; e < e1; e++) {
      float w = csr_w[e];
      const float4* xr = (const float4*)(x_in + (b * NN + csr_src[e]) * FF + sub * 32);
      #pragma unroll
      for (int mm = 0; mm < 8; mm++) {
        float4 vv = xr[mm];
        sa[mm].x += w * vv.x; sa[mm].y += w * vv.y; sa[mm].z += w * vv.z; sa[mm].w += w * vv.w;
      }
    }
    #pragma unroll
    for (int mm = 0; mm < 8; mm++) {
      int d = sub * 32 + mm * 4;
      st[gr][d + 0] = sa[mm].x; st[gr][d + 1] = sa[mm].y;
      st[gr][d + 2] = sa[mm].z; st[gr][d + 3] = sa[mm].w;
    }
  }
  int fgrp = tid & 31, rgrp = tid >> 5, r0 = rgrp * 4;
  float2 acc[4][4];
  float2 sp[4];
  #pragma unroll
  for (int i = 0; i < 4; i++) sp[i] = ((const float2*)spos)[n0 + r0 + i];
  #pragma unroll
  for (int j = 0; j < 4; j++) {
    int f = fgrp * 2 + j * 64;
    float2 w0 = *(const float2*)&Wg[f];
    float2 w1 = *(const float2*)&Wg[FF + f];
    float2 bb = *(const float2*)&bg[f];
    #pragma unroll
    for (int i = 0; i < 4; i++) {
      acc[i][j].x = bb.x + sp[i].x * w0.x + sp[i].y * w1.x;
      acc[i][j].y = bb.y + sp[i].x * w0.y + sp[i].y * w1.y;
    }
  }
  for (int kc = 0; kc < 8; kc++) {
    __syncthreads();
    float v[32];
    #pragma unroll
    for (int it = 0; it < 32; it++) v[it] = Wg[(2 + kc * 32 + it) * FF + tid];
    #pragma unroll
    for (int it = 0; it < 32; it++) wc[it][tid] = v[it];
    __syncthreads();
    for (int kk = 0; kk < 32; kk++) {
      int k = kc * 32 + kk;
      float c0 = st[r0 + 0][k], c1 = st[r0 + 1][k], c2 = st[r0 + 2][k], c3 = st[r0 + 3][k];
      #pragma unroll
      for (int j = 0; j < 4; j++) {
        float2 w = *(const float2*)&wc[kk][fgrp * 2 + j * 64];
        acc[0][j].x += c0 * w.x; acc[0][j].y += c0 * w.y;
        acc[1][j].x += c1 * w.x; acc[1][j].y += c1 * w.y;
        acc[2][j].x += c2 * w.x; acc[2][j].y += c2 * w.y;
        acc[3][j].x += c3 * w.x; acc[3][j].y += c3 * w.y;
      }
    }
  }
  #pragma unroll
  for (int i = 0; i < 4; i++) {
    int r = b * NN + n0 + r0 + i;
    float2 y[4];
    float sm = 0.f, sq = 0.f;
    #pragma unroll
    for (int j = 0; j < 4; j++) {
      float2 xv = *(const float2*)&x_in[r * FF + fgrp * 2 + j * 64];
      y[j].x = xv.x + acc[i][j].x;
      y[j].y = xv.y + acc[i][j].y;
      sm += y[j].x + y[j].y;
      sq += y[j].x * y[j].x + y[j].y * y[j].y;
    }
    #pragma unroll
    for (int o = 16; o; o >>= 1) { sm += __shfl_xor(sm, o); sq += __shfl_xor(sq, o); }
    float mean = sm * (1.f / 256.f);
    float var = sq * (1.f / 256.f) - mean * mean;
    float rs = rsqrtf(var + 1e-5f);
    #pragma unroll
    for (int j = 0; j < 4; j++) {
      int f = fgrp * 2 + j * 64;
      float2 g = *(const float2*)&lng[f];
      float2 bt = *(const float2*)&lnb[f];
      float2 o2;
      o2.x = (y[j].x - mean) * rs * g.x + bt.x;
      o2.y = (y[j].y - mean) * rs * g.y + bt.y;
      *(float2*)&x_out[r * FF + f] = o2;
    }
  }
}

// ---------------- decoder: out = relu(cat(lat,q)@Wd1+b)@Wd2+b ----------------
__global__ __launch_bounds__(256) void k_decoder(const float* lat, const float* qxy,
    const float* Wd1, const float* bd1, const float* Wd2, const float* bd2, float* out) {
  __shared__ float lt[32][TS];
  __shared__ float wc[32][TS];
  __shared__ float qs[32][2];
  int tid = threadIdx.x;
  int row0 = blockIdx.x * 32;
  {
    float v[32];
    #pragma unroll
    for (int it = 0; it < 32; it++) v[it] = lat[(row0 + it) * FF + tid];
    #pragma unroll
    for (int it = 0; it < 32; it++) lt[it][tid] = v[it];
  }
  if (tid < 64) qs[tid >> 1][tid & 1] = qxy[(row0 + (tid >> 1)) * 2 + (tid & 1)];
  int fgrp = tid & 31, rgrp = tid >> 5, r0 = rgrp * 4;
  float2 acc[4][4];
  #pragma unroll
  for (int j = 0; j < 4; j++) {
    float2 b2 = *(const float2*)&bd1[fgrp * 2 + j * 64];
    #pragma unroll
    for (int i = 0; i < 4; i++) acc[i][j] = b2;
  }
  for (int kc = 0; kc < 8; kc++) {
    __syncthreads();
    float v[32];
    #pragma unroll
    for (int it = 0; it < 32; it++) v[it] = Wd1[(kc * 32 + it) * FF + tid];
    #pragma unroll
    for (int it = 0; it < 32; it++) wc[it][tid] = v[it];
    __syncthreads();
    for (int kk = 0; kk < 32; kk++) {
      int k = kc * 32 + kk;
      float c0 = lt[r0 + 0][k], c1 = lt[r0 + 1][k], c2 = lt[r0 + 2][k], c3 = lt[r0 + 3][k];
      #pragma unroll
      for (int j = 0; j < 4; j++) {
        float2 w = *(const float2*)&wc[kk][fgrp * 2 + j * 64];
        acc[0][j].x += c0 * w.x; acc[0][j].y += c0 * w.y;
        acc[1][j].x += c1 * w.x; acc[1][j].y += c1 * w.y;
        acc[2][j].x += c2 * w.x; acc[2][j].y += c2 * w.y;
        acc[3][j].x += c3 * w.x; acc[3][j].y += c3 * w.y;
      }
    }
  }
  #pragma unroll
  for (int j = 0; j < 4; j++) {
    int f = fgrp * 2 + j * 64;
    float2 wa = *(const float2*)&Wd1[256 * FF + f];
    float2 wb = *(const float2*)&Wd1[257 * FF + f];
    #pragma unroll
    for (int i = 0; i < 4; i++) {
      float qx = qs[r0 + i][0], qy = qs[r0 + i][1];
      acc[i][j].x += qx * wa.x + qy * wb.x;
      acc[i][j].y += qx * wa.y + qy * wb.y;
    }
  }
  float po[4][3];
  #pragma unroll
  for (int i = 0; i < 4; i++) { po[i][0] = 0.f; po[i][1] = 0.f; po[i][2] = 0.f; }
  #pragma unroll
  for (int i = 0; i < 4; i++)
    #pragma unroll
    for (int j = 0; j < 4; j++) {
      int f = fgrp * 2 + j * 64;
      float hx = fmaxf(acc[i][j].x, 0.f), hy = fmaxf(acc[i][j].y, 0.f);
      #pragma unroll
      for (int o = 0; o < 3; o++)
        po[i][o] += hx * Wd2[f * 3 + o] + hy * Wd2[(f + 1) * 3 + o];
    }
  #pragma unroll
  for (int o = 16; o; o >>= 1)
    #pragma unroll
    for (int i = 0; i < 4; i++) {
      po[i][0] += __shfl_xor(po[i][0], o);
      po[i][1] += __shfl_xor(po[i][1], o);
      po[i][2] += __shfl_xor(po[i][2], o);
    }
  if (fgrp == 0) {
    #pragma unroll
    for (int i = 0; i < 4; i++) {
      int r = row0 + r0 + i;
      out[r * 3 + 0] = po[i][0] + bd2[0];
      out[r * 3 + 1] = po[i][1] + bd2[1];
      out[r * 3 + 2] = po[i][2] + bd2[2];
    }
  }
}

extern "C" void kernel_launch(void* const* d_in, const int* in_sizes, int n_in,
                              void* d_out, int out_size, void* d_ws, size_t ws_size,
                              hipStream_t stream) {
  const float* inx = (const float*)d_in[0];
  const float* iny = (const float*)d_in[1];
  const float* qxy = (const float*)d_in[2];
  const float* npos = (const float*)d_in[3];
  const float* We1 = (const float*)d_in[4];
  const float* be1 = (const float*)d_in[5];
  const float* We2 = (const float*)d_in[6];
  const float* be2 = (const float*)d_in[7];
  const float* Wg  = (const float*)d_in[8];
  const float* bg  = (const float*)d_in[9];
  const float* lng = (const float*)d_in[10];
  const float* lnb = (const float*)d_in[11];
  const float* Wd1 = (const float*)d_in[12];
  const float* bd1 = (const float*)d_in[13];
  const float* Wd2 = (const float*)d_in[14];
  const float* bd2 = (const float*)d_in[15];
  const int* eidx  = (const int*)d_in[16];
  float* out = (float*)d_out;

  char* w = (char*)d_ws;
  auto carve = [&](size_t n) { char* p = w; w += (n + 255) & ~(size_t)255; return p; };
  float* enc  = (float*)carve((size_t)BB * NP * FF * 4);
  float* xA   = (float*)carve((size_t)BB * NN * FF * 4);
  float* xB   = (float*)carve((size_t)BB * NN * FF * 4);
  float* lat  = (float*)carve((size_t)BB * NP * FF * 4);
  float* mI   = (float*)carve((size_t)BB * NP * 4);
  float* liI  = (float*)carve((size_t)BB * NP * 4);
  float* mQ   = (float*)carve((size_t)BB * NP * 4);
  float* liQ  = (float*)carve((size_t)BB * NP * 4);
  float* dinv = (float*)carve(NN * 4);
  float* spos = (float*)carve(NN * 2 * 4);
  float* csw  = (float*)carve((NE + NN) * 4);
  int* degI   = (int*)carve(NN * 4);
  int* coff   = (int*)carve((NN + 1) * 4);
  int* csrc   = (int*)carve((NE + NN) * 4);

  const int* esrc = eidx;
  const int* edst = eidx + NE;

  k_deg_init<<<dim3((NN + 255) / 256), dim3(256), 0, stream>>>(degI);
  k_deg_count<<<dim3((NE + 255) / 256), dim3(256), 0, stream>>>(edst, degI);
  k_scan<<<dim3(1), dim3(1024), 0, stream>>>(degI, dinv, coff);
  k_fill<<<dim3((NE + NN + 255) / 256), dim3(256), 0, stream>>>(esrc, edst, dinv, coff, csrc, csw);
  k_spos<<<dim3((NN + 255) / 256), dim3(256), 0, stream>>>(npos, coff, csrc, csw, spos);

  k_stats<<<dim3(BB * NP / 4), dim3(256), 0, stream>>>(inx, npos, mI, liI);
  k_encoder<<<dim3(BB * NP / 32), dim3(256), 0, stream>>>(inx, iny, We1, be1, We2, be2, enc);
  k_proj1<<<dim3(NN / 32, BB), dim3(256), 0, stream>>>(inx, mI, liI, npos, enc, xA);
  for (int s = 0; s < NSTEP; s++) {
    const float* xi = (s & 1) ? xB : xA;
    float* xo = (s & 1) ? xA : xB;
    k_msg<<<dim3(NN / 32, BB), dim3(256), 0, stream>>>(xi, xo, spos, coff, csrc, csw,
                                                       Wg, bg, lng, lnb);
  }
  const float* xf = (NSTEP & 1) ? xB : xA;
  k_stats<<<dim3(BB * NP / 4), dim3(256), 0, stream>>>(qxy, npos, mQ, liQ);
  k_proj2<<<dim3(NP / 32, BB), dim3(256), 0, stream>>>(qxy, mQ, liQ, npos, xf, lat);
  k_decoder<<<dim3(BB * NP / 32), dim3(256), 0, stream>>>(lat, qxy, Wd1, bd1, Wd2, bd2, out);
}

// Round 2
// 1265.291 us; speedup vs baseline: 1.4656x; 1.4656x over previous
//
#include <hip/hip_runtime.h>

#define BB 8
#define NP 4096    // NPTS == NQ
#define NN 1024
#define NE 8192
#define FF 256
#define TS 264
#define NSTEP 16

typedef float f32x4_t __attribute__((ext_vector_type(4)));
typedef __bf16 bf16x8_t __attribute__((ext_vector_type(8)));
typedef unsigned int u32x4_t __attribute__((ext_vector_type(4)));
typedef unsigned int u32x2_t __attribute__((ext_vector_type(2)));

static __device__ __forceinline__ unsigned short f2bf(float f) {
  union { float f; unsigned u; } v; v.f = f;
  unsigned u = v.u + 0x7FFFu + ((v.u >> 16) & 1u);
  return (unsigned short)(u >> 16);
}
static __device__ __forceinline__ unsigned pk2(float a, float b) {
  return (unsigned)f2bf(a) | ((unsigned)f2bf(b) << 16);
}
static __device__ __forceinline__ f32x4_t mfma16(u32x4_t a, u32x4_t b, f32x4_t c) {
  return __builtin_amdgcn_mfma_f32_16x16x32_bf16(
      __builtin_bit_cast(bf16x8_t, a), __builtin_bit_cast(bf16x8_t, b), c, 0, 0, 0);
}

// ---------------- graph preprocessing (unchanged, deterministic) ----------------
__global__ __launch_bounds__(256) void k_deg_init(int* degI) {
  int n = blockIdx.x * 256 + threadIdx.x;
  if (n < NN) degI[n] = 1;
}

__global__ __launch_bounds__(256) void k_deg_count(const int* dst, int* degI) {
  int e = blockIdx.x * 256 + threadIdx.x;
  if (e < NE) atomicAdd(&degI[dst[e]], 1);
}

__global__ __launch_bounds__(1024) void k_scan(const int* degI, float* dinv, int* csr_off) {
  __shared__ int s[NN];
  int n = threadIdx.x;
  int c = degI[n];
  dinv[n] = rsqrtf((float)c);
  s[n] = c;
  __syncthreads();
  for (int st = 1; st < NN; st <<= 1) {
    int v = (n >= st) ? s[n - st] : 0;
    __syncthreads();
    s[n] += v;
    __syncthreads();
  }
  csr_off[n] = s[n] - c;
  if (n == NN - 1) csr_off[NN] = s[n];
}

__global__ __launch_bounds__(256) void k_fill(const int* srcA, const int* dstA,
    const float* dinv, const int* csr_off, int* csr_src, float* csr_w) {
  int t = blockIdx.x * 256 + threadIdx.x;
  if (t < NE) {
    int d = dstA[t];
    int rank = 0;
    for (int e = 0; e < t; e++) rank += (dstA[e] == d) ? 1 : 0;
    int pos = csr_off[d] + rank;
    int sv = srcA[t];
    csr_src[pos] = sv;
    csr_w[pos] = dinv[sv] * dinv[d];
  } else if (t < NE + NN) {
    int n = t - NE;
    int pos = csr_off[n + 1] - 1;
    csr_src[pos] = n;
    csr_w[pos] = dinv[n] * dinv[n];
  }
}

__global__ __launch_bounds__(256) void k_spos(const float* npos, const int* csr_off,
    const int* csr_src, const float* csr_w, float* spos) {
  int n = blockIdx.x * 256 + threadIdx.x;
  if (n >= NN) return;
  float sx = 0.f, sy = 0.f;
  int e1 = csr_off[n + 1];
  for (int e = csr_off[n]; e < e1; e++) {
    float w = csr_w[e]; int s = csr_src[e];
    sx += w * npos[2 * s]; sy += w * npos[2 * s + 1];
  }
  spos[2 * n] = sx; spos[2 * n + 1] = sy;
}

// ---------------- softmax stats ----------------
__global__ __launch_bounds__(256) void k_stats(const float* xy, const float* npos,
                                               float* mOut, float* liOut) {
  int wv = threadIdx.x >> 6, lane = threadIdx.x & 63;
  int pt = blockIdx.x * 4 + wv;
  float px = xy[pt * 2], py = xy[pt * 2 + 1];
  float s[16];
  float m = -1e30f;
  #pragma unroll
  for (int k = 0; k < 16; k++) {
    int n = lane + 64 * k;
    float2 np = ((const float2*)npos)[n];
    float dx = px - np.x, dy = py - np.y;
    float v = -(dx * dx + dy * dy);
    s[k] = v; m = fmaxf(m, v);
  }
  #pragma unroll
  for (int o = 32; o; o >>= 1) m = fmaxf(m, __shfl_xor(m, o));
  float l = 0.f;
  #pragma unroll
  for (int k = 0; k < 16; k++) l += __expf(s[k] - m);
  #pragma unroll
  for (int o = 32; o; o >>= 1) l += __shfl_xor(l, o);
  if (lane == 0) { mOut[pt] = m; liOut[pt] = 1.0f / l; }
}

// ---------------- weight prepack: WT[kc][n][kk] bf16 ----------------
__global__ __launch_bounds__(256) void k_pack_w(const float* We2, const float* Wg,
    const float* Wd1, unsigned short* WTe2, unsigned short* WTg, unsigned short* WTd1) {
  int kc = blockIdx.x, which = blockIdx.y, n = threadIdx.x;
  const float* W = (which == 0) ? We2 : (which == 1) ? (Wg + 2 * FF) : Wd1;
  unsigned short* D = (which == 0) ? WTe2 : (which == 1) ? WTg : WTd1;
  unsigned u[16];
  #pragma unroll
  for (int i = 0; i < 16; i++) {
    float a = W[(kc * 32 + 2 * i) * FF + n];
    float b = W[(kc * 32 + 2 * i + 1) * FF + n];
    u[i] = pk2(a, b);
  }
  u32x4_t* dv = (u32x4_t*)(D + ((size_t)kc * 256 + n) * 32);
  #pragma unroll
  for (int i = 0; i < 4; i++) {
    u32x4_t t = {u[4 * i], u[4 * i + 1], u[4 * i + 2], u[4 * i + 3]};
    dv[i] = t;
  }
}

// ---------------- encoder: L1 fp32 VALU, L2 MFMA; writes encT bf16 ----------------
__global__ __launch_bounds__(256) void k_encoder(const float* inx, const float* iny,
    const float* We1, const float* be1, const unsigned short* WTe2, const float* be2,
    unsigned short* encT) {
  __shared__ float xin[32][8];
  __shared__ float h[32][TS];
  __shared__ unsigned short Bst[2][8192];
  int tid = threadIdx.x;
  int row0 = blockIdx.x * 32;
  int wv = tid >> 6, L = tid & 63, lhi = L >> 4, llo = L & 15;

  if (tid < 160) {
    int pt = tid / 5, d = tid % 5;
    int r = row0 + pt;
    xin[pt][d] = (d < 2) ? inx[r * 2 + d] : iny[r * 3 + (d - 2)];
  }
  __syncthreads();
  {
    int f = tid;
    float w0 = We1[f], w1 = We1[256 + f], w2 = We1[512 + f], w3 = We1[768 + f], w4 = We1[1024 + f];
    float bb = be1[f];
    #pragma unroll 4
    for (int pt = 0; pt < 32; pt++) {
      float v = bb + xin[pt][0]*w0 + xin[pt][1]*w1 + xin[pt][2]*w2 + xin[pt][3]*w3 + xin[pt][4]*w4;
      h[pt][f] = fmaxf(v, 0.f);
    }
  }
  auto stageB = [&](int kc, int buf) {
    const u32x4_t* s = (const u32x4_t*)(WTe2 + (size_t)kc * 8192);
    u32x4_t* d = (u32x4_t*)Bst[buf];
    #pragma unroll
    for (int i = 0; i < 4; i++) d[tid + i * 256] = s[tid + i * 256];
  };
  stageB(0, 0);

  f32x4_t acc[2][4];
  #pragma unroll
  for (int cb = 0; cb < 4; cb++) {
    float bc = be2[wv * 64 + cb * 16 + llo];
    f32x4_t t = {bc, bc, bc, bc};
    acc[0][cb] = t; acc[1][cb] = t;
  }
  __syncthreads();

  for (int kc = 0; kc < 8; kc++) {
    int cur = kc & 1;
    if (kc < 7) stageB(kc + 1, cur ^ 1);
    int kbase = kc * 32 + lhi * 8;
    u32x4_t a0, a1;
    {
      f32x4_t p0 = *(const f32x4_t*)&h[llo][kbase];
      f32x4_t p1 = *(const f32x4_t*)&h[llo][kbase + 4];
      u32x4_t t = {pk2(p0[0], p0[1]), pk2(p0[2], p0[3]), pk2(p1[0], p1[1]), pk2(p1[2], p1[3])};
      a0 = t;
    }
    {
      f32x4_t p0 = *(const f32x4_t*)&h[llo + 16][kbase];
      f32x4_t p1 = *(const f32x4_t*)&h[llo + 16][kbase + 4];
      u32x4_t t = {pk2(p0[0], p0[1]), pk2(p0[2], p0[3]), pk2(p1[0], p1[1]), pk2(p1[2], p1[3])};
      a1 = t;
    }
    #pragma unroll
    for (int cb = 0; cb < 4; cb++) {
      u32x4_t bb = *(const u32x4_t*)&Bst[cur][(wv * 64 + cb * 16 + llo) * 32 + lhi * 8];
      acc[0][cb] = mfma16(a0, bb, acc[0][cb]);
      acc[1][cb] = mfma16(a1, bb, acc[1][cb]);
    }
    __syncthreads();
  }
  // epilogue: encT[tile][f][kk]
  #pragma unroll
  for (int rb = 0; rb < 2; rb++)
    #pragma unroll
    for (int cb = 0; cb < 4; cb++) {
      int col = wv * 64 + cb * 16 + llo;
      f32x4_t v = acc[rb][cb];
      size_t idx = ((size_t)blockIdx.x * 256 + col) * 32 + rb * 16 + lhi * 4;
      u32x2_t w; w.x = pk2(v[0], v[1]); w.y = pk2(v[2], v[3]);
      *(u32x2_t*)&encT[idx] = w;
    }
}

// ---------------- proj1 (split-K MFMA): part[z][b][n][f] ----------------
__global__ __launch_bounds__(256) void k_proj1(const float* inx, const float* mI,
    const float* liI, const float* npos, const unsigned short* encT, float* part) {
  __shared__ unsigned short Bst[2][8192];
  __shared__ unsigned short Ast[2][1024];
  int tid = threadIdx.x;
  int n0 = blockIdx.x * 32, b = blockIdx.y, z = blockIdx.z;
  int wv = tid >> 6, L = tid & 63, lhi = L >> 4, llo = L & 15;
  int an = tid >> 3, ap = (tid & 7) * 4;
  float2 npv = ((const float2*)npos)[n0 + an];
  int pbase0 = b * NP + z * 1024;

  auto stageA = [&](int kc, int buf) {
    int p = pbase0 + kc * 32 + ap;
    float c[4];
    #pragma unroll
    for (int j = 0; j < 4; j++) {
      float2 pxy = ((const float2*)inx)[p + j];
      float mm = mI[p + j], ll = liI[p + j];
      float dx = pxy.x - npv.x, dy = pxy.y - npv.y;
      c[j] = __expf(-(dx * dx + dy * dy) - mm) * ll;
    }
    u32x2_t w; w.x = pk2(c[0], c[1]); w.y = pk2(c[2], c[3]);
    *(u32x2_t*)&Ast[buf][an * 32 + ap] = w;
  };
  auto stageB = [&](int kc, int buf) {
    const u32x4_t* s = (const u32x4_t*)(encT + (size_t)(b * 128 + z * 32 + kc) * 8192);
    u32x4_t* d = (u32x4_t*)Bst[buf];
    #pragma unroll
    for (int i = 0; i < 4; i++) d[tid + i * 256] = s[tid + i * 256];
  };

  f32x4_t acc[2][4];
  #pragma unroll
  for (int i = 0; i < 2; i++)
    #pragma unroll
    for (int j = 0; j < 4; j++) { f32x4_t t = {0.f, 0.f, 0.f, 0.f}; acc[i][j] = t; }

  stageA(0, 0); stageB(0, 0);
  __syncthreads();
  for (int kc = 0; kc < 32; kc++) {
    int cur = kc & 1;
    if (kc < 31) { stageA(kc + 1, cur ^ 1); stageB(kc + 1, cur ^ 1); }
    u32x4_t a0 = *(const u32x4_t*)&Ast[cur][llo * 32 + lhi * 8];
    u32x4_t a1 = *(const u32x4_t*)&Ast[cur][(llo + 16) * 32 + lhi * 8];
    #pragma unroll
    for (int cb = 0; cb < 4; cb++) {
      u32x4_t bb = *(const u32x4_t*)&Bst[cur][(wv * 64 + cb * 16 + llo) * 32 + lhi * 8];
      acc[0][cb] = mfma16(a0, bb, acc[0][cb]);
      acc[1][cb] = mfma16(a1, bb, acc[1][cb]);
    }
    __syncthreads();
  }
  float* op = part + (((size_t)(z * BB + b)) * NN + n0) * FF;
  #pragma unroll
  for (int rb = 0; rb < 2; rb++)
    #pragma unroll
    for (int cb = 0; cb < 4; cb++) {
      int col = wv * 64 + cb * 16 + llo;
      f32x4_t v = acc[rb][cb];
      #pragma unroll
      for (int r = 0; r < 4; r++) op[(rb * 16 + lhi * 4 + r) * FF + col] = v[r];
    }
}

__global__ __launch_bounds__(256) void k_reduce(const float* part, float* x) {
  size_t i = ((size_t)blockIdx.x * 256 + threadIdx.x) * 4;
  const size_t S = (size_t)BB * NN * FF;
  f32x4_t a = *(const f32x4_t*)&part[i];
  f32x4_t b = *(const f32x4_t*)&part[S + i];
  f32x4_t c = *(const f32x4_t*)&part[2 * S + i];
  f32x4_t d = *(const f32x4_t*)&part[3 * S + i];
  f32x4_t r = (a + b) + (c + d);
  *(f32x4_t*)&x[i] = r;
}

// ---------------- fused msg step (UNCHANGED fp32 — precision anchor) ----------------
__global__ __launch_bounds__(256) void k_msg(const float* x_in, float* x_out,
    const float* spos, const int* csr_off, const int* csr_src, const float* csr_w,
    const float* Wg, const float* bg, const float* lng, const float* lnb) {
  __shared__ float st[32][TS];
  __shared__ float wc[32][TS];
  int tid = threadIdx.x;
  int b = blockIdx.y;
  int n0 = blockIdx.x * 32;
  {
    int gr = tid >> 3, sub = tid & 7;
    int n = n0 + gr;
    float4 sa[8];
    #pragma unroll
    for (int mm = 0; mm < 8; mm++) sa[mm] = make_float4(0.f, 0.f, 0.f, 0.f);
    int e1 = csr_off[n + 1];
    for (int e = csr_off[n]; e < e1; e++) {
      float w = csr_w[e];
      const float4* xr = (const float4*)(x_in + (b * NN + csr_src[e]) * FF + sub * 32);
      #pragma unroll
      for (int mm = 0; mm < 8; mm++) {
        float4 vv = xr[mm];
        sa[mm].x += w * vv.x; sa[mm].y += w * vv.y; sa[mm].z += w * vv.z; sa[mm].w += w * vv.w;
      }
    }
    #pragma unroll
    for (int mm = 0; mm < 8; mm++) {
      int d = sub * 32 + mm * 4;
      st[gr][d + 0] = sa[mm].x; st[gr][d + 1] = sa[mm].y;
      st[gr][d + 2] = sa[mm].z; st[gr][d + 3] = sa[mm].w;
    }
  }
  int fgrp = tid & 31, rgrp = tid >> 5, r0 = rgrp * 4;
  float2 acc[4][4];
  float2 sp[4];
  #pragma unroll
  for (int i = 0; i < 4; i++) sp[i] = ((const float2*)spos)[n0 + r0 + i];
  #pragma unroll
  for (int j = 0; j < 4; j++) {
    int f = fgrp * 2 + j * 64;
    float2 w0 = *(const float2*)&Wg[f];
    float2 w1 = *(const float2*)&Wg[FF + f];
    float2 bb = *(const float2*)&bg[f];
    #pragma unroll
    for (int i = 0; i < 4; i++) {
      acc[i][j].x = bb.x + sp[i].x * w0.x + sp[i].y * w1.x;
      acc[i][j].y = bb.y + sp[i].x * w0.y + sp[i].y * w1.y;
    }
  }
  for (int kc = 0; kc < 8; kc++) {
    __syncthreads();
    float v[32];
    #pragma unroll
    for (int it = 0; it < 32; it++) v[it] = Wg[(2 + kc * 32 + it) * FF + tid];
    #pragma unroll
    for (int it = 0; it < 32; it++) wc[it][tid] = v[it];
    __syncthreads();
    for (int kk = 0; kk < 32; kk++) {
      int k = kc * 32 + kk;
      float c0 = st[r0 + 0][k], c1 = st[r0 + 1][k], c2 = st[r0 + 2][k], c3 = st[r0 + 3][k];
      #pragma unroll
      for (int j = 0; j < 4; j++) {
        float2 w = *(const float2*)&wc[kk][fgrp * 2 + j * 64];
        acc[0][j].x += c0 * w.x; acc[0][j].y += c0 * w.y;
        acc[1][j].x += c1 * w.x; acc[1][j].y += c1 * w.y;
        acc[2][j].x += c2 * w.x; acc[2][j].y += c2 * w.y;
        acc[3][j].x += c3 * w.x; acc[3][j].y += c3 * w.y;
      }
    }
  }
  #pragma unroll
  for (int i = 0; i < 4; i++) {
    int r = b * NN + n0 + r0 + i;
    float2 y[4];
    float sm = 0.f, sq = 0.f;
    #pragma unroll
    for (int j = 0; j < 4; j++) {
      float2 xv = *(const float2*)&x_in[r * FF + fgrp * 2 + j * 64];
      y[j].x = xv.x + acc[i][j].x;
      y[j].y = xv.y + acc[i][j].y;
      sm += y[j].x + y[j].y;
      sq += y[j].x * y[j].x + y[j].y * y[j].y;
    }
    #pragma unroll
    for (int o = 16; o; o >>= 1) { sm += __shfl_xor(sm, o); sq += __shfl_xor(sq, o); }
    float mean = sm * (1.f / 256.f);
    float var = sq * (1.f / 256.f) - mean * mean;
    float rs = rsqrtf(var + 1e-5f);
    #pragma unroll
    for (int j = 0; j < 4; j++) {
      int f = fgrp * 2 + j * 64;
      float2 g = *(const float2*)&lng[f];
      float2 bt = *(const float2*)&lnb[f];
      float2 o2;
      o2.x = (y[j].x - mean) * rs * g.x + bt.x;
      o2.y = (y[j].y - mean) * rs * g.y + bt.y;
      *(float2*)&x_out[r * FF + f] = o2;
    }
  }
}

// ---------------- x -> xT bf16 [b][nc][f][kk] ----------------
__global__ __launch_bounds__(256) void k_xT(const float* x, unsigned short* xT) {
  int nc = blockIdx.x, b = blockIdx.y, f = threadIdx.x;
  const float* src = x + ((size_t)b * NN + nc * 32) * FF + f;
  unsigned u[16];
  #pragma unroll
  for (int i = 0; i < 16; i++) u[i] = pk2(src[(2 * i) * FF], src[(2 * i + 1) * FF]);
  u32x4_t* dv = (u32x4_t*)(xT + (((size_t)b * 32 + nc) * 256 + f) * 32);
  #pragma unroll
  for (int i = 0; i < 4; i++) {
    u32x4_t t = {u[4 * i], u[4 * i + 1], u[4 * i + 2], u[4 * i + 3]};
    dv[i] = t;
  }
}

// ---------------- proj2 (MFMA): latT[bt][fc][row][kk] bf16 ----------------
__global__ __launch_bounds__(256) void k_proj2(const float* qxy, const float* mQ,
    const float* liQ, const float* npos, const unsigned short* xT, unsigned short* latT) {
  __shared__ unsigned short Bst[2][8192];
  __shared__ unsigned short Ast[2][1024];
  __shared__ float nps[NN * 2];
  int tid = threadIdx.x;
  int q0 = blockIdx.x * 32, b = blockIdx.y;
  int bt = b * 128 + blockIdx.x;
  int wv = tid >> 6, L = tid & 63, lhi = L >> 4, llo = L & 15;
  int aq = tid >> 3, an4 = (tid & 7) * 4;

  {
    const f32x4_t* s4 = (const f32x4_t*)npos;
    *(f32x4_t*)&nps[tid * 4] = s4[tid];
    *(f32x4_t*)&nps[(tid + 256) * 4] = s4[tid + 256];
  }
  int qg = b * NP + q0 + aq;
  float2 qv = ((const float2*)qxy)[qg];
  float qm = mQ[qg], qli = liQ[qg];
  __syncthreads();

  auto stageA = [&](int kc, int buf) {
    int nb = kc * 32 + an4;
    float c[4];
    #pragma unroll
    for (int j = 0; j < 4; j++) {
      float nx = nps[(nb + j) * 2], ny = nps[(nb + j) * 2 + 1];
      float dx = qv.x - nx, dy = qv.y - ny;
      c[j] = __expf(-(dx * dx + dy * dy) - qm) * qli;
    }
    u32x2_t w; w.x = pk2(c[0], c[1]); w.y = pk2(c[2], c[3]);
    *(u32x2_t*)&Ast[buf][aq * 32 + an4] = w;
  };
  auto stageB = [&](int kc, int buf) {
    const u32x4_t* s = (const u32x4_t*)(xT + (size_t)(b * 32 + kc) * 8192);
    u32x4_t* d = (u32x4_t*)Bst[buf];
    #pragma unroll
    for (int i = 0; i < 4; i++) d[tid + i * 256] = s[tid + i * 256];
  };

  f32x4_t acc[2][4];
  #pragma unroll
  for (int i = 0; i < 2; i++)
    #pragma unroll
    for (int j = 0; j < 4; j++) { f32x4_t t = {0.f, 0.f, 0.f, 0.f}; acc[i][j] = t; }

  stageA(0, 0); stageB(0, 0);
  __syncthreads();
  for (int kc = 0; kc < 32; kc++) {
    int cur = kc & 1;
    if (kc < 31) { stageA(kc + 1, cur ^ 1); stageB(kc + 1, cur ^ 1); }
    u32x4_t a0 = *(const u32x4_t*)&Ast[cur][llo * 32 + lhi * 8];
    u32x4_t a1 = *(const u32x4_t*)&Ast[cur][(llo + 16) * 32 + lhi * 8];
    #pragma unroll
    for (int cb = 0; cb < 4; cb++) {
      u32x4_t bb = *(const u32x4_t*)&Bst[cur][(wv * 64 + cb * 16 + llo) * 32 + lhi * 8];
      acc[0][cb] = mfma16(a0, bb, acc[0][cb]);
      acc[1][cb] = mfma16(a1, bb, acc[1][cb]);
    }
    __syncthreads();
  }
  #pragma unroll
  for (int rb = 0; rb < 2; rb++)
    #pragma unroll
    for (int cb = 0; cb < 4; cb++) {
      int col = wv * 64 + cb * 16 + llo;
      int fc = col >> 5, kk = col & 31;
      f32x4_t v = acc[rb][cb];
      #pragma unroll
      for (int r = 0; r < 4; r++)
        latT[((size_t)bt * 8 + fc) * 1024 + (rb * 16 + lhi * 4 + r) * 32 + kk] = f2bf(v[r]);
    }
}

// ---------------- decoder (MFMA + fused second GEMM) ----------------
__global__ __launch_bounds__(256) void k_decoder(const unsigned short* latT, const float* qxy,
    const unsigned short* WTd1, const float* bd1, const float* Wd1,
    const float* Wd2, const float* bd2, float* out) {
  __shared__ unsigned short Bst[2][8192];
  __shared__ unsigned short Ast[2][1024];
  __shared__ float qs[32][2];
  __shared__ float red[4][32][3];
  int tid = threadIdx.x;
  int bt = blockIdx.x;
  int wv = tid >> 6, L = tid & 63, lhi = L >> 4, llo = L & 15;

  auto stageA = [&](int kc, int buf) {
    if (tid < 128)
      ((u32x4_t*)Ast[buf])[tid] = ((const u32x4_t*)(latT + ((size_t)bt * 8 + kc) * 1024))[tid];
  };
  auto stageB = [&](int kc, int buf) {
    const u32x4_t* s = (const u32x4_t*)(WTd1 + (size_t)kc * 8192);
    u32x4_t* d = (u32x4_t*)Bst[buf];
    #pragma unroll
    for (int i = 0; i < 4; i++) d[tid + i * 256] = s[tid + i * 256];
  };

  if (tid < 64) qs[tid >> 1][tid & 1] = qxy[((size_t)bt * 32 + (tid >> 1)) * 2 + (tid & 1)];
  stageA(0, 0); stageB(0, 0);
  __syncthreads();

  f32x4_t acc[2][4];
  #pragma unroll
  for (int cb = 0; cb < 4; cb++) {
    int col = wv * 64 + cb * 16 + llo;
    float wa = Wd1[256 * FF + col], wb = Wd1[257 * FF + col], bc = bd1[col];
    #pragma unroll
    for (int rb = 0; rb < 2; rb++) {
      f32x4_t t;
      #pragma unroll
      for (int r = 0; r < 4; r++) {
        int row = rb * 16 + lhi * 4 + r;
        t[r] = bc + qs[row][0] * wa + qs[row][1] * wb;
      }
      acc[rb][cb] = t;
    }
  }

  for (int kc = 0; kc < 8; kc++) {
    int cur = kc & 1;
    if (kc < 7) { stageA(kc + 1, cur ^ 1); stageB(kc + 1, cur ^ 1); }
    u32x4_t a0 = *(const u32x4_t*)&Ast[cur][llo * 32 + lhi * 8];
    u32x4_t a1 = *(const u32x4_t*)&Ast[cur][(llo + 16) * 32 + lhi * 8];
    #pragma unroll
    for (int cb = 0; cb < 4; cb++) {
      u32x4_t bb = *(const u32x4_t*)&Bst[cur][(wv * 64 + cb * 16 + llo) * 32 + lhi * 8];
      acc[0][cb] = mfma16(a0, bb, acc[0][cb]);
      acc[1][cb] = mfma16(a1, bb, acc[1][cb]);
    }
    __syncthreads();
  }

  float po[2][4][3];
  #pragma unroll
  for (int rb = 0; rb < 2; rb++)
    #pragma unroll
    for (int r = 0; r < 4; r++) { po[rb][r][0] = 0.f; po[rb][r][1] = 0.f; po[rb][r][2] = 0.f; }
  #pragma unroll
  for (int rb = 0; rb < 2; rb++)
    #pragma unroll
    for (int cb = 0; cb < 4; cb++) {
      int col = wv * 64 + cb * 16 + llo;
      float w0 = Wd2[col * 3], w1 = Wd2[col * 3 + 1], w2 = Wd2[col * 3 + 2];
      f32x4_t v = acc[rb][cb];
      #pragma unroll
      for (int r = 0; r < 4; r++) {
        float hv = fmaxf(v[r], 0.f);
        po[rb][r][0] += hv * w0; po[rb][r][1] += hv * w1; po[rb][r][2] += hv * w2;
      }
    }
  #pragma unroll
  for (int o = 8; o; o >>= 1)
    #pragma unroll
    for (int rb = 0; rb < 2; rb++)
      #pragma unroll
      for (int r = 0; r < 4; r++) {
        po[rb][r][0] += __shfl_xor(po[rb][r][0], o);
        po[rb][r][1] += __shfl_xor(po[rb][r][1], o);
        po[rb][r][2] += __shfl_xor(po[rb][r][2], o);
      }
  if (llo == 0) {
    #pragma unroll
    for (int rb = 0; rb < 2; rb++)
      #pragma unroll
      for (int r = 0; r < 4; r++) {
        int row = rb * 16 + lhi * 4 + r;
        red[wv][row][0] = po[rb][r][0];
        red[wv][row][1] = po[rb][r][1];
        red[wv][row][2] = po[rb][r][2];
      }
  }
  __syncthreads();
  if (tid < 96) {
    int row = tid / 3, o = tid % 3;
    float s = red[0][row][o] + red[1][row][o] + red[2][row][o] + red[3][row][o] + bd2[o];
    out[((size_t)bt * 32 + row) * 3 + o] = s;
  }
}

extern "C" void kernel_launch(void* const* d_in, const int* in_sizes, int n_in,
                              void* d_out, int out_size, void* d_ws, size_t ws_size,
                              hipStream_t stream) {
  const float* inx = (const float*)d_in[0];
  const float* iny = (const float*)d_in[1];
  const float* qxy = (const float*)d_in[2];
  const float* npos = (const float*)d_in[3];
  const float* We1 = (const float*)d_in[4];
  const float* be1 = (const float*)d_in[5];
  const float* We2 = (const float*)d_in[6];
  const float* be2 = (const float*)d_in[7];
  const float* Wg  = (const float*)d_in[8];
  const float* bg  = (const float*)d_in[9];
  const float* lng = (const float*)d_in[10];
  const float* lnb = (const float*)d_in[11];
  const float* Wd1 = (const float*)d_in[12];
  const float* bd1 = (const float*)d_in[13];
  const float* Wd2 = (const float*)d_in[14];
  const float* bd2 = (const float*)d_in[15];
  const int* eidx  = (const int*)d_in[16];
  float* out = (float*)d_out;

  char* w = (char*)d_ws;
  auto carve = [&](size_t n) { char* p = w; w += (n + 255) & ~(size_t)255; return p; };
  unsigned short* encT = (unsigned short*)carve((size_t)BB * NP * FF * 2);   // 16 MB
  float* xA   = (float*)carve((size_t)BB * NN * FF * 4);                     // 8 MB
  float* xB   = (float*)carve((size_t)BB * NN * FF * 4);                     // 8 MB
  unsigned short* xT   = (unsigned short*)carve((size_t)BB * NN * FF * 2);   // 4 MB
  float* part = (float*)carve((size_t)4 * BB * NN * FF * 4);                 // 32 MB
  unsigned short* latT = (unsigned short*)carve((size_t)BB * NP * FF * 2);   // 16 MB
  float* mI   = (float*)carve((size_t)BB * NP * 4);
  float* liI  = (float*)carve((size_t)BB * NP * 4);
  float* mQ   = (float*)carve((size_t)BB * NP * 4);
  float* liQ  = (float*)carve((size_t)BB * NP * 4);
  unsigned short* WTe2 = (unsigned short*)carve((size_t)8 * 256 * 32 * 2);
  unsigned short* WTg  = (unsigned short*)carve((size_t)8 * 256 * 32 * 2);
  unsigned short* WTd1 = (unsigned short*)carve((size_t)8 * 256 * 32 * 2);
  float* dinv = (float*)carve(NN * 4);
  float* spos = (float*)carve(NN * 2 * 4);
  float* csw  = (float*)carve((NE + NN) * 4);
  int* degI   = (int*)carve(NN * 4);
  int* coff   = (int*)carve((NN + 1) * 4);
  int* csrc   = (int*)carve((NE + NN) * 4);

  const int* esrc = eidx;
  const int* edst = eidx + NE;

  k_deg_init<<<dim3((NN + 255) / 256), dim3(256), 0, stream>>>(degI);
  k_deg_count<<<dim3((NE + 255) / 256), dim3(256), 0, stream>>>(edst, degI);
  k_scan<<<dim3(1), dim3(1024), 0, stream>>>(degI, dinv, coff);
  k_fill<<<dim3((NE + NN + 255) / 256), dim3(256), 0, stream>>>(esrc, edst, dinv, coff, csrc, csw);
  k_spos<<<dim3((NN + 255) / 256), dim3(256), 0, stream>>>(npos, coff, csrc, csw, spos);
  k_pack_w<<<dim3(8, 3), dim3(256), 0, stream>>>(We2, Wg, Wd1, WTe2, WTg, WTd1);

  k_stats<<<dim3(BB * NP / 4), dim3(256), 0, stream>>>(inx, npos, mI, liI);
  k_encoder<<<dim3(BB * NP / 32), dim3(256), 0, stream>>>(inx, iny, We1, be1, WTe2, be2, encT);
  k_proj1<<<dim3(32, 8, 4), dim3(256), 0, stream>>>(inx, mI, liI, npos, encT, part);
  k_reduce<<<dim3(BB * NN * FF / 1024), dim3(256), 0, stream>>>(part, xA);
  for (int s = 0; s < NSTEP; s++) {
    const float* xi = (s & 1) ? xB : xA;
    float* xo = (s & 1) ? xA : xB;
    k_msg<<<dim3(NN / 32, BB), dim3(256), 0, stream>>>(xi, xo, spos, coff, csrc, csw,
                                                       Wg, bg, lng, lnb);
  }
  const float* xf = (NSTEP & 1) ? xB : xA;
  k_xT<<<dim3(32, 8), dim3(256), 0, stream>>>(xf, xT);
  k_stats<<<dim3(BB * NP / 4), dim3(256), 0, stream>>>(qxy, npos, mQ, liQ);
  k_proj2<<<dim3(128, 8), dim3(256), 0, stream>>>(qxy, mQ, liQ, npos, xT, latT);
  k_decoder<<<dim3(BB * NP / 32), dim3(256), 0, stream>>>(latT, qxy, WTd1, bd1, Wd1, Wd2, bd2, out);
}

// Round 4
// 914.288 us; speedup vs baseline: 2.0282x; 1.3839x over previous
//
#include <hip/hip_runtime.h>

#define BB 8
#define NP 4096    // NPTS == NQ
#define NN 1024
#define NE 8192
#define FF 256
#define TS 264
#define NSTEP 16

typedef float f32x4_t __attribute__((ext_vector_type(4)));
typedef __bf16 bf16x8_t __attribute__((ext_vector_type(8)));
typedef unsigned int u32x4_t __attribute__((ext_vector_type(4)));
typedef unsigned int u32x2_t __attribute__((ext_vector_type(2)));

static __device__ __forceinline__ unsigned short f2bf(float f) {
  union { float f; unsigned u; } v; v.f = f;
  unsigned u = v.u + 0x7FFFu + ((v.u >> 16) & 1u);
  return (unsigned short)(u >> 16);
}
static __device__ __forceinline__ float ashf(unsigned short s) {
  union { unsigned u; float f; } t; t.u = (unsigned)s << 16; return t.f;
}
// split a,b into hi/lo bf16 pairs packed as u32
static __device__ __forceinline__ void split_pk(float a, float b, unsigned& h, unsigned& l) {
  unsigned short ha = f2bf(a), hb = f2bf(b);
  unsigned short la = f2bf(a - ashf(ha)), lb = f2bf(b - ashf(hb));
  h = (unsigned)ha | ((unsigned)hb << 16);
  l = (unsigned)la | ((unsigned)lb << 16);
}
static __device__ __forceinline__ f32x4_t mfma16(u32x4_t a, u32x4_t b, f32x4_t c) {
  return __builtin_amdgcn_mfma_f32_16x16x32_bf16(
      __builtin_bit_cast(bf16x8_t, a), __builtin_bit_cast(bf16x8_t, b), c, 0, 0, 0);
}

// ---------------- graph preprocessing ----------------
__global__ __launch_bounds__(256) void k_deg_init(int* degI) {
  int n = blockIdx.x * 256 + threadIdx.x;
  if (n < NN) degI[n] = 1;
}

__global__ __launch_bounds__(256) void k_deg_count(const int* dst, int* degI) {
  int e = blockIdx.x * 256 + threadIdx.x;
  if (e < NE) atomicAdd(&degI[dst[e]], 1);
}

__global__ __launch_bounds__(1024) void k_scan(const int* degI, float* dinv, int* csr_off) {
  __shared__ int s[NN];
  int n = threadIdx.x;
  int c = degI[n];
  dinv[n] = rsqrtf((float)c);
  s[n] = c;
  __syncthreads();
  for (int st = 1; st < NN; st <<= 1) {
    int v = (n >= st) ? s[n - st] : 0;
    __syncthreads();
    s[n] += v;
    __syncthreads();
  }
  csr_off[n] = s[n] - c;
  if (n == NN - 1) csr_off[NN] = s[n];
}

// pass 1: per-(segment, node) match counts. 8 segments of 1024 edges.
__global__ __launch_bounds__(1024) void k_cnt(const int* dstA, int* cntg) {
  int seg = blockIdx.x, n = threadIdx.x;
  int e0 = seg * 1024;
  int c = 0;
  for (int e = 0; e < 1024; e++) c += (dstA[e0 + e] == n) ? 1 : 0;
  cntg[seg * NN + n] = c;
}

// pass 2: fill CSR deterministically (edge order preserved); block 8 = self loops
__global__ __launch_bounds__(1024) void k_fill2(const int* srcA, const int* dstA,
    const float* dinv, const int* csr_off, const int* cntg, int* csr_src, float* csr_w) {
  int n = threadIdx.x;
  if (blockIdx.x == 8) {
    int pos = csr_off[n + 1] - 1;               // self loop last
    csr_src[pos] = n;
    csr_w[pos] = dinv[n] * dinv[n];
    return;
  }
  int seg = blockIdx.x;
  int base = csr_off[n];
  for (int s = 0; s < seg; s++) base += cntg[s * NN + n];
  int e0 = seg * 1024;
  float dn = dinv[n];
  for (int e = 0; e < 1024; e++) {
    if (dstA[e0 + e] == n) {
      int sv = srcA[e0 + e];
      csr_src[base] = sv;
      csr_w[base] = dinv[sv] * dn;
      base++;
    }
  }
}

__global__ __launch_bounds__(256) void k_spos(const float* npos, const int* csr_off,
    const int* csr_src, const float* csr_w, float* spos) {
  int n = blockIdx.x * 256 + threadIdx.x;
  if (n >= NN) return;
  float sx = 0.f, sy = 0.f;
  int e1 = csr_off[n + 1];
  for (int e = csr_off[n]; e < e1; e++) {
    float w = csr_w[e]; int s = csr_src[e];
    sx += w * npos[2 * s]; sy += w * npos[2 * s + 1];
  }
  spos[2 * n] = sx; spos[2 * n + 1] = sy;
}

// sposW[n][f] = spos[n] @ Wg[0:2] + bg  (step-invariant part of agg)
__global__ __launch_bounds__(256) void k_posb(const float* spos, const float* Wg,
                                              const float* bg, float* sposW) {
  int n = blockIdx.x, f = threadIdx.x;
  sposW[(size_t)n * FF + f] = spos[2 * n] * Wg[f] + spos[2 * n + 1] * Wg[FF + f] + bg[f];
}

// ---------------- softmax stats ----------------
__global__ __launch_bounds__(256) void k_stats(const float* xy, const float* npos,
                                               float* mOut, float* liOut) {
  int wv = threadIdx.x >> 6, lane = threadIdx.x & 63;
  int pt = blockIdx.x * 4 + wv;
  float px = xy[pt * 2], py = xy[pt * 2 + 1];
  float s[16];
  float m = -1e30f;
  #pragma unroll
  for (int k = 0; k < 16; k++) {
    int n = lane + 64 * k;
    float2 np = ((const float2*)npos)[n];
    float dx = px - np.x, dy = py - np.y;
    float v = -(dx * dx + dy * dy);
    s[k] = v; m = fmaxf(m, v);
  }
  #pragma unroll
  for (int o = 32; o; o >>= 1) m = fmaxf(m, __shfl_xor(m, o));
  float l = 0.f;
  #pragma unroll
  for (int k = 0; k < 16; k++) l += __expf(s[k] - m);
  #pragma unroll
  for (int o = 32; o; o >>= 1) l += __shfl_xor(l, o);
  if (lane == 0) { mOut[pt] = m; liOut[pt] = 1.0f / l; }
}

// ---------------- weight prepack: WT[kc][n][kk] bf16 hi+lo ----------------
__global__ __launch_bounds__(256) void k_pack_w(const float* We2, const float* Wg,
    const float* Wd1, unsigned short* WTe2h, unsigned short* WTe2l,
    unsigned short* WTgh, unsigned short* WTgl,
    unsigned short* WTd1h, unsigned short* WTd1l) {
  int kc = blockIdx.x, which = blockIdx.y, n = threadIdx.x;
  const float* W = (which == 0) ? We2 : (which == 1) ? (Wg + 2 * FF) : Wd1;
  unsigned short* Dh = (which == 0) ? WTe2h : (which == 1) ? WTgh : WTd1h;
  unsigned short* Dl = (which == 0) ? WTe2l : (which == 1) ? WTgl : WTd1l;
  unsigned hu[16], lu[16];
  #pragma unroll
  for (int i = 0; i < 16; i++) {
    float a = W[(kc * 32 + 2 * i) * FF + n];
    float b = W[(kc * 32 + 2 * i + 1) * FF + n];
    split_pk(a, b, hu[i], lu[i]);
  }
  u32x4_t* dvh = (u32x4_t*)(Dh + ((size_t)kc * 256 + n) * 32);
  u32x4_t* dvl = (u32x4_t*)(Dl + ((size_t)kc * 256 + n) * 32);
  #pragma unroll
  for (int i = 0; i < 4; i++) {
    u32x4_t th = {hu[4 * i], hu[4 * i + 1], hu[4 * i + 2], hu[4 * i + 3]};
    u32x4_t tl = {lu[4 * i], lu[4 * i + 1], lu[4 * i + 2], lu[4 * i + 3]};
    dvh[i] = th; dvl[i] = tl;
  }
}

// ---------------- encoder: L1 fp32 VALU, L2 split-MFMA; writes encT hi+lo ----------------
__global__ __launch_bounds__(256) void k_encoder(const float* inx, const float* iny,
    const float* We1, const float* be1, const unsigned short* WTe2h,
    const unsigned short* WTe2l, const float* be2,
    unsigned short* encTh, unsigned short* encTl) {
  __shared__ float xin[32][8];
  __shared__ float h[32][TS];
  __shared__ unsigned short Bh[8192];
  __shared__ unsigned short Bl[8192];
  int tid = threadIdx.x;
  int row0 = blockIdx.x * 32;
  int wv = tid >> 6, L = tid & 63, lhi = L >> 4, llo = L & 15;

  if (tid < 160) {
    int pt = tid / 5, d = tid % 5;
    int r = row0 + pt;
    xin[pt][d] = (d < 2) ? inx[r * 2 + d] : iny[r * 3 + (d - 2)];
  }
  __syncthreads();
  {
    int f = tid;
    float w0 = We1[f], w1 = We1[256 + f], w2 = We1[512 + f], w3 = We1[768 + f], w4 = We1[1024 + f];
    float bb = be1[f];
    #pragma unroll 4
    for (int pt = 0; pt < 32; pt++) {
      float v = bb + xin[pt][0]*w0 + xin[pt][1]*w1 + xin[pt][2]*w2 + xin[pt][3]*w3 + xin[pt][4]*w4;
      h[pt][f] = fmaxf(v, 0.f);
    }
  }

  f32x4_t acc[2][4];
  #pragma unroll
  for (int cb = 0; cb < 4; cb++) {
    float bc = be2[wv * 64 + cb * 16 + llo];
    f32x4_t t = {bc, bc, bc, bc};
    acc[0][cb] = t; acc[1][cb] = t;
  }

  for (int kc = 0; kc < 8; kc++) {
    __syncthreads();
    {
      const u32x4_t* sh = (const u32x4_t*)(WTe2h + (size_t)kc * 8192);
      const u32x4_t* sl = (const u32x4_t*)(WTe2l + (size_t)kc * 8192);
      u32x4_t* dh = (u32x4_t*)Bh;
      u32x4_t* dl = (u32x4_t*)Bl;
      #pragma unroll
      for (int i = 0; i < 4; i++) { dh[tid + i * 256] = sh[tid + i * 256]; dl[tid + i * 256] = sl[tid + i * 256]; }
    }
    __syncthreads();
    int kbase = kc * 32 + lhi * 8;
    u32x4_t a0h, a0l, a1h, a1l;
    {
      float p[8];
      *(f32x4_t*)p = *(const f32x4_t*)&h[llo][kbase];
      *(f32x4_t*)(p + 4) = *(const f32x4_t*)&h[llo][kbase + 4];
      unsigned hw[4], lw[4];
      #pragma unroll
      for (int i = 0; i < 4; i++) split_pk(p[2 * i], p[2 * i + 1], hw[i], lw[i]);
      u32x4_t th = {hw[0], hw[1], hw[2], hw[3]}; a0h = th;
      u32x4_t tl = {lw[0], lw[1], lw[2], lw[3]}; a0l = tl;
    }
    {
      float p[8];
      *(f32x4_t*)p = *(const f32x4_t*)&h[llo + 16][kbase];
      *(f32x4_t*)(p + 4) = *(const f32x4_t*)&h[llo + 16][kbase + 4];
      unsigned hw[4], lw[4];
      #pragma unroll
      for (int i = 0; i < 4; i++) split_pk(p[2 * i], p[2 * i + 1], hw[i], lw[i]);
      u32x4_t th = {hw[0], hw[1], hw[2], hw[3]}; a1h = th;
      u32x4_t tl = {lw[0], lw[1], lw[2], lw[3]}; a1l = tl;
    }
    #pragma unroll
    for (int cb = 0; cb < 4; cb++) {
      int off = (wv * 64 + cb * 16 + llo) * 32 + lhi * 8;
      u32x4_t bh = *(const u32x4_t*)&Bh[off];
      u32x4_t bl = *(const u32x4_t*)&Bl[off];
      acc[0][cb] = mfma16(a0h, bh, mfma16(a0h, bl, mfma16(a0l, bh, acc[0][cb])));
      acc[1][cb] = mfma16(a1h, bh, mfma16(a1h, bl, mfma16(a1l, bh, acc[1][cb])));
    }
  }
  #pragma unroll
  for (int rb = 0; rb < 2; rb++)
    #pragma unroll
    for (int cb = 0; cb < 4; cb++) {
      int col = wv * 64 + cb * 16 + llo;
      f32x4_t v = acc[rb][cb];
      size_t idx = ((size_t)blockIdx.x * 256 + col) * 32 + rb * 16 + lhi * 4;
      unsigned hw0, lw0, hw1, lw1;
      split_pk(v[0], v[1], hw0, lw0);
      split_pk(v[2], v[3], hw1, lw1);
      u32x2_t wh = {hw0, hw1}; *(u32x2_t*)&encTh[idx] = wh;
      u32x2_t wl = {lw0, lw1}; *(u32x2_t*)&encTl[idx] = wl;
    }
}

// ---------------- proj1 (split-K, 3-term split MFMA): part[z][b][n][f] ----------------
__global__ __launch_bounds__(256) void k_proj1(const float* inx, const float* mI,
    const float* liI, const float* npos, const unsigned short* encTh,
    const unsigned short* encTl, float* part) {
  __shared__ unsigned short BstH[2][8192];
  __shared__ unsigned short BstL[2][8192];
  __shared__ unsigned short AstH[2][1024];
  __shared__ unsigned short AstL[2][1024];
  int tid = threadIdx.x;
  int n0 = blockIdx.x * 32, b = blockIdx.y, z = blockIdx.z;
  int wv = tid >> 6, L = tid & 63, lhi = L >> 4, llo = L & 15;
  int an = tid >> 3, ap = (tid & 7) * 4;
  float2 npv = ((const float2*)npos)[n0 + an];
  int pbase0 = b * NP + z * 1024;

  auto stageA = [&](int kc, int buf) {
    int p = pbase0 + kc * 32 + ap;
    float c[4];
    #pragma unroll
    for (int j = 0; j < 4; j++) {
      float2 pxy = ((const float2*)inx)[p + j];
      float mm = mI[p + j], ll = liI[p + j];
      float dx = pxy.x - npv.x, dy = pxy.y - npv.y;
      c[j] = __expf(-(dx * dx + dy * dy) - mm) * ll;
    }
    unsigned hw0, lw0, hw1, lw1;
    split_pk(c[0], c[1], hw0, lw0);
    split_pk(c[2], c[3], hw1, lw1);
    u32x2_t wh = {hw0, hw1}; *(u32x2_t*)&AstH[buf][an * 32 + ap] = wh;
    u32x2_t wl = {lw0, lw1}; *(u32x2_t*)&AstL[buf][an * 32 + ap] = wl;
  };
  auto stageB = [&](int kc, int buf) {
    const u32x4_t* sh = (const u32x4_t*)(encTh + (size_t)(b * 128 + z * 32 + kc) * 8192);
    const u32x4_t* sl = (const u32x4_t*)(encTl + (size_t)(b * 128 + z * 32 + kc) * 8192);
    u32x4_t* dh = (u32x4_t*)BstH[buf];
    u32x4_t* dl = (u32x4_t*)BstL[buf];
    #pragma unroll
    for (int i = 0; i < 4; i++) { dh[tid + i * 256] = sh[tid + i * 256]; dl[tid + i * 256] = sl[tid + i * 256]; }
  };

  f32x4_t acc[2][4];
  #pragma unroll
  for (int i = 0; i < 2; i++)
    #pragma unroll
    for (int j = 0; j < 4; j++) { f32x4_t t = {0.f, 0.f, 0.f, 0.f}; acc[i][j] = t; }

  stageA(0, 0); stageB(0, 0);
  __syncthreads();
  for (int kc = 0; kc < 32; kc++) {
    int cur = kc & 1;
    if (kc < 31) { stageA(kc + 1, cur ^ 1); stageB(kc + 1, cur ^ 1); }
    u32x4_t a0h = *(const u32x4_t*)&AstH[cur][llo * 32 + lhi * 8];
    u32x4_t a0l = *(const u32x4_t*)&AstL[cur][llo * 32 + lhi * 8];
    u32x4_t a1h = *(const u32x4_t*)&AstH[cur][(llo + 16) * 32 + lhi * 8];
    u32x4_t a1l = *(const u32x4_t*)&AstL[cur][(llo + 16) * 32 + lhi * 8];
    #pragma unroll
    for (int cb = 0; cb < 4; cb++) {
      int off = (wv * 64 + cb * 16 + llo) * 32 + lhi * 8;
      u32x4_t bh = *(const u32x4_t*)&BstH[cur][off];
      u32x4_t bl = *(const u32x4_t*)&BstL[cur][off];
      acc[0][cb] = mfma16(a0h, bh, mfma16(a0h, bl, mfma16(a0l, bh, acc[0][cb])));
      acc[1][cb] = mfma16(a1h, bh, mfma16(a1h, bl, mfma16(a1l, bh, acc[1][cb])));
    }
    __syncthreads();
  }
  float* op = part + (((size_t)(z * BB + b)) * NN + n0) * FF;
  #pragma unroll
  for (int rb = 0; rb < 2; rb++)
    #pragma unroll
    for (int cb = 0; cb < 4; cb++) {
      int col = wv * 64 + cb * 16 + llo;
      f32x4_t v = acc[rb][cb];
      #pragma unroll
      for (int r = 0; r < 4; r++) op[(rb * 16 + lhi * 4 + r) * FF + col] = v[r];
    }
}

// reduce split-K parts -> x (fp32)
__global__ __launch_bounds__(256) void k_reduce(const float* part, float* x) {
  size_t i = ((size_t)blockIdx.x * 256 + threadIdx.x) * 4;
  const size_t S = (size_t)BB * NN * FF;
  f32x4_t a = *(const f32x4_t*)&part[i];
  f32x4_t b = *(const f32x4_t*)&part[S + i];
  f32x4_t c = *(const f32x4_t*)&part[2 * S + i];
  f32x4_t d = *(const f32x4_t*)&part[3 * S + i];
  f32x4_t r = (a + b) + (c + d);
  *(f32x4_t*)&x[i] = r;
}

// ---------------- msg step A: g = A @ x (fp32 CSR gather), write split gh/gl ----------------
__global__ __launch_bounds__(256) void k_gather(const float* x, const int* csr_off,
    const int* csr_src, const float* csr_w, unsigned short* gh, unsigned short* gl) {
  int tid = threadIdx.x;
  int gr = tid >> 5, sub = tid & 31;
  int n = blockIdx.x * 8 + gr;
  int b = blockIdx.y;
  float g[8];
  #pragma unroll
  for (int i = 0; i < 8; i++) g[i] = 0.f;
  int e0 = csr_off[n], e1 = csr_off[n + 1];
  for (int e = e0; e < e1; e++) {
    float w = csr_w[e];
    int s = csr_src[e];
    const f32x4_t* px = (const f32x4_t*)(x + ((size_t)b * NN + s) * FF + sub * 8);
    f32x4_t w0 = px[0], w1 = px[1];
    g[0] += w * w0[0]; g[1] += w * w0[1]; g[2] += w * w0[2]; g[3] += w * w0[3];
    g[4] += w * w1[0]; g[5] += w * w1[1]; g[6] += w * w1[2]; g[7] += w * w1[3];
  }
  size_t o = ((size_t)b * NN + n) * FF + sub * 8;
  unsigned hw[4], lw[4];
  #pragma unroll
  for (int i = 0; i < 4; i++) split_pk(g[2 * i], g[2 * i + 1], hw[i], lw[i]);
  u32x4_t th = {hw[0], hw[1], hw[2], hw[3]};
  u32x4_t tl = {lw[0], lw[1], lw[2], lw[3]};
  *(u32x4_t*)&gh[o] = th;
  *(u32x4_t*)&gl[o] = tl;
}

// ---------------- msg step B: x' = LN(x + g@Wgx + sposW) (3-term split MFMA) ----------------
__global__ __launch_bounds__(256) void k_gemmLN(const unsigned short* gh, const unsigned short* gl,
    const float* x_in, float* x_out, const float* sposW,
    const unsigned short* WTgh, const unsigned short* WTgl,
    const float* lng, const float* lnb) {
  __shared__ unsigned Ah[32][132];
  __shared__ unsigned Al[32][132];
  __shared__ unsigned short Bh[8192];
  __shared__ unsigned short Bl[8192];
  __shared__ float redS[32][4];
  __shared__ float redQ[32][4];
  int tid = threadIdx.x;
  int n0 = blockIdx.x * 32, b = blockIdx.y;
  int wv = tid >> 6, L = tid & 63, lhi = L >> 4, llo = L & 15;

  {
    int row = tid >> 3, seg = tid & 7;
    const u32x4_t* sh = (const u32x4_t*)(gh + ((size_t)b * NN + n0 + row) * FF) + seg * 4;
    const u32x4_t* sl = (const u32x4_t*)(gl + ((size_t)b * NN + n0 + row) * FF) + seg * 4;
    u32x4_t* dh = (u32x4_t*)&Ah[row][seg * 16];
    u32x4_t* dl = (u32x4_t*)&Al[row][seg * 16];
    #pragma unroll
    for (int i = 0; i < 4; i++) { dh[i] = sh[i]; dl[i] = sl[i]; }
  }

  f32x4_t acc[2][4];
  #pragma unroll
  for (int i = 0; i < 2; i++)
    #pragma unroll
    for (int j = 0; j < 4; j++) { f32x4_t t = {0.f, 0.f, 0.f, 0.f}; acc[i][j] = t; }

  for (int kc = 0; kc < 8; kc++) {
    __syncthreads();
    {
      const u32x4_t* sh = (const u32x4_t*)(WTgh + (size_t)kc * 8192);
      const u32x4_t* sl = (const u32x4_t*)(WTgl + (size_t)kc * 8192);
      u32x4_t* dh = (u32x4_t*)Bh;
      u32x4_t* dl = (u32x4_t*)Bl;
      #pragma unroll
      for (int i = 0; i < 4; i++) { dh[tid + i * 256] = sh[tid + i * 256]; dl[tid + i * 256] = sl[tid + i * 256]; }
    }
    __syncthreads();
    u32x4_t a0h = *(const u32x4_t*)&Ah[llo][kc * 16 + lhi * 4];
    u32x4_t a0l = *(const u32x4_t*)&Al[llo][kc * 16 + lhi * 4];
    u32x4_t a1h = *(const u32x4_t*)&Ah[llo + 16][kc * 16 + lhi * 4];
    u32x4_t a1l = *(const u32x4_t*)&Al[llo + 16][kc * 16 + lhi * 4];
    #pragma unroll
    for (int cb = 0; cb < 4; cb++) {
      int off = (wv * 64 + cb * 16 + llo) * 32 + lhi * 8;
      u32x4_t bh = *(const u32x4_t*)&Bh[off];
      u32x4_t bl = *(const u32x4_t*)&Bl[off];
      acc[0][cb] = mfma16(a0h, bh, mfma16(a0h, bl, mfma16(a0l, bh, acc[0][cb])));
      acc[1][cb] = mfma16(a1h, bh, mfma16(a1h, bl, mfma16(a1l, bh, acc[1][cb])));
    }
  }

  // epilogue: + sposW + residual, then LayerNorm
  #pragma unroll
  for (int rb = 0; rb < 2; rb++)
    #pragma unroll
    for (int cb = 0; cb < 4; cb++) {
      int col = wv * 64 + cb * 16 + llo;
      #pragma unroll
      for (int r = 0; r < 4; r++) {
        int row = rb * 16 + lhi * 4 + r;
        float sw = sposW[(size_t)(n0 + row) * FF + col];
        float xr = x_in[((size_t)b * NN + n0 + row) * FF + col];
        acc[rb][cb][r] += sw + xr;
      }
    }
  float ps[2][4], pq[2][4];
  #pragma unroll
  for (int rb = 0; rb < 2; rb++)
    #pragma unroll
    for (int r = 0; r < 4; r++) {
      float s = 0.f, q = 0.f;
      #pragma unroll
      for (int cb = 0; cb < 4; cb++) { float y = acc[rb][cb][r]; s += y; q += y * y; }
      #pragma unroll
      for (int m = 1; m < 16; m <<= 1) { s += __shfl_xor(s, m); q += __shfl_xor(q, m); }
      ps[rb][r] = s; pq[rb][r] = q;
    }
  if (llo == 0) {
    #pragma unroll
    for (int rb = 0; rb < 2; rb++)
      #pragma unroll
      for (int r = 0; r < 4; r++) {
        int row = rb * 16 + lhi * 4 + r;
        redS[row][wv] = ps[rb][r];
        redQ[row][wv] = pq[rb][r];
      }
  }
  __syncthreads();
  float mrs[2][4][2];
  #pragma unroll
  for (int rb = 0; rb < 2; rb++)
    #pragma unroll
    for (int r = 0; r < 4; r++) {
      int row = rb * 16 + lhi * 4 + r;
      float S = redS[row][0] + redS[row][1] + redS[row][2] + redS[row][3];
      float Q = redQ[row][0] + redQ[row][1] + redQ[row][2] + redQ[row][3];
      float mean = S * (1.f / 256.f);
      float var = Q * (1.f / 256.f) - mean * mean;
      mrs[rb][r][0] = mean;
      mrs[rb][r][1] = rsqrtf(var + 1e-5f);
    }
  #pragma unroll
  for (int cb = 0; cb < 4; cb++) {
    int col = wv * 64 + cb * 16 + llo;
    float gg = lng[col], bb = lnb[col];
    #pragma unroll
    for (int rb = 0; rb < 2; rb++)
      #pragma unroll
      for (int r = 0; r < 4; r++) {
        int row = rb * 16 + lhi * 4 + r;
        float o = (acc[rb][cb][r] - mrs[rb][r][0]) * mrs[rb][r][1] * gg + bb;
        x_out[((size_t)b * NN + n0 + row) * FF + col] = o;
      }
  }
}

// ---------------- x -> xT bf16 hi+lo [b][nc][f][kk] ----------------
__global__ __launch_bounds__(256) void k_xT(const float* x, unsigned short* xTh,
                                            unsigned short* xTl) {
  int nc = blockIdx.x, b = blockIdx.y, f = threadIdx.x;
  const float* src = x + ((size_t)b * NN + nc * 32) * FF + f;
  unsigned hu[16], lu[16];
  #pragma unroll
  for (int i = 0; i < 16; i++)
    split_pk(src[(2 * i) * FF], src[(2 * i + 1) * FF], hu[i], lu[i]);
  u32x4_t* dh = (u32x4_t*)(xTh + (((size_t)b * 32 + nc) * 256 + f) * 32);
  u32x4_t* dl = (u32x4_t*)(xTl + (((size_t)b * 32 + nc) * 256 + f) * 32);
  #pragma unroll
  for (int i = 0; i < 4; i++) {
    u32x4_t th = {hu[4 * i], hu[4 * i + 1], hu[4 * i + 2], hu[4 * i + 3]};
    u32x4_t tl = {lu[4 * i], lu[4 * i + 1], lu[4 * i + 2], lu[4 * i + 3]};
    dh[i] = th; dl[i] = tl;
  }
}

// ---------------- proj2 (3-term split MFMA): latT hi+lo [bt][fc][row][kk] ----------------
__global__ __launch_bounds__(256) void k_proj2(const float* qxy, const float* mQ,
    const float* liQ, const float* npos, const unsigned short* xTh,
    const unsigned short* xTl, unsigned short* latTh, unsigned short* latTl) {
  __shared__ unsigned short BstH[2][8192];
  __shared__ unsigned short BstL[2][8192];
  __shared__ unsigned short AstH[2][1024];
  __shared__ unsigned short AstL[2][1024];
  __shared__ float nps[NN * 2];
  int tid = threadIdx.x;
  int q0 = blockIdx.x * 32, b = blockIdx.y;
  int bt = b * 128 + blockIdx.x;
  int wv = tid >> 6, L = tid & 63, lhi = L >> 4, llo = L & 15;
  int aq = tid >> 3, an4 = (tid & 7) * 4;

  {
    const f32x4_t* s4 = (const f32x4_t*)npos;
    *(f32x4_t*)&nps[tid * 4] = s4[tid];
    *(f32x4_t*)&nps[(tid + 256) * 4] = s4[tid + 256];
  }
  int qg = b * NP + q0 + aq;
  float2 qv = ((const float2*)qxy)[qg];
  float qm = mQ[qg], qli = liQ[qg];
  __syncthreads();

  auto stageA = [&](int kc, int buf) {
    int nb = kc * 32 + an4;
    float c[4];
    #pragma unroll
    for (int j = 0; j < 4; j++) {
      float nx = nps[(nb + j) * 2], ny = nps[(nb + j) * 2 + 1];
      float dx = qv.x - nx, dy = qv.y - ny;
      c[j] = __expf(-(dx * dx + dy * dy) - qm) * qli;
    }
    unsigned hw0, lw0, hw1, lw1;
    split_pk(c[0], c[1], hw0, lw0);
    split_pk(c[2], c[3], hw1, lw1);
    u32x2_t wh = {hw0, hw1}; *(u32x2_t*)&AstH[buf][aq * 32 + an4] = wh;
    u32x2_t wl = {lw0, lw1}; *(u32x2_t*)&AstL[buf][aq * 32 + an4] = wl;
  };
  auto stageB = [&](int kc, int buf) {
    const u32x4_t* sh = (const u32x4_t*)(xTh + (size_t)(b * 32 + kc) * 8192);
    const u32x4_t* sl = (const u32x4_t*)(xTl + (size_t)(b * 32 + kc) * 8192);
    u32x4_t* dh = (u32x4_t*)BstH[buf];
    u32x4_t* dl = (u32x4_t*)BstL[buf];
    #pragma unroll
    for (int i = 0; i < 4; i++) { dh[tid + i * 256] = sh[tid + i * 256]; dl[tid + i * 256] = sl[tid + i * 256]; }
  };

  f32x4_t acc[2][4];
  #pragma unroll
  for (int i = 0; i < 2; i++)
    #pragma unroll
    for (int j = 0; j < 4; j++) { f32x4_t t = {0.f, 0.f, 0.f, 0.f}; acc[i][j] = t; }

  stageA(0, 0); stageB(0, 0);
  __syncthreads();
  for (int kc = 0; kc < 32; kc++) {
    int cur = kc & 1;
    if (kc < 31) { stageA(kc + 1, cur ^ 1); stageB(kc + 1, cur ^ 1); }
    u32x4_t a0h = *(const u32x4_t*)&AstH[cur][llo * 32 + lhi * 8];
    u32x4_t a0l = *(const u32x4_t*)&AstL[cur][llo * 32 + lhi * 8];
    u32x4_t a1h = *(const u32x4_t*)&AstH[cur][(llo + 16) * 32 + lhi * 8];
    u32x4_t a1l = *(const u32x4_t*)&AstL[cur][(llo + 16) * 32 + lhi * 8];
    #pragma unroll
    for (int cb = 0; cb < 4; cb++) {
      int off = (wv * 64 + cb * 16 + llo) * 32 + lhi * 8;
      u32x4_t bh = *(const u32x4_t*)&BstH[cur][off];
      u32x4_t bl = *(const u32x4_t*)&BstL[cur][off];
      acc[0][cb] = mfma16(a0h, bh, mfma16(a0h, bl, mfma16(a0l, bh, acc[0][cb])));
      acc[1][cb] = mfma16(a1h, bh, mfma16(a1h, bl, mfma16(a1l, bh, acc[1][cb])));
    }
    __syncthreads();
  }
  #pragma unroll
  for (int rb = 0; rb < 2; rb++)
    #pragma unroll
    for (int cb = 0; cb < 4; cb++) {
      int col = wv * 64 + cb * 16 + llo;
      int fc = col >> 5, kk = col & 31;
      f32x4_t v = acc[rb][cb];
      #pragma unroll
      for (int r = 0; r < 4; r++) {
        size_t idx = ((size_t)bt * 8 + fc) * 1024 + (rb * 16 + lhi * 4 + r) * 32 + kk;
        unsigned short hh = f2bf(v[r]);
        latTh[idx] = hh;
        latTl[idx] = f2bf(v[r] - ashf(hh));
      }
    }
}

// ---------------- decoder (3-term split MFMA + fused second GEMM) ----------------
__global__ __launch_bounds__(256) void k_decoder(const unsigned short* latTh,
    const unsigned short* latTl, const float* qxy,
    const unsigned short* WTd1h, const unsigned short* WTd1l, const float* bd1,
    const float* Wd1, const float* Wd2, const float* bd2, float* out) {
  __shared__ unsigned short BstH[2][8192];
  __shared__ unsigned short BstL[2][8192];
  __shared__ unsigned short AstH[2][1024];
  __shared__ unsigned short AstL[2][1024];
  __shared__ float qs[32][2];
  __shared__ float red[4][32][3];
  int tid = threadIdx.x;
  int bt = blockIdx.x;
  int wv = tid >> 6, L = tid & 63, lhi = L >> 4, llo = L & 15;

  auto stageA = [&](int kc, int buf) {
    if (tid < 128)
      ((u32x4_t*)AstH[buf])[tid] = ((const u32x4_t*)(latTh + ((size_t)bt * 8 + kc) * 1024))[tid];
    else
      ((u32x4_t*)AstL[buf])[tid - 128] = ((const u32x4_t*)(latTl + ((size_t)bt * 8 + kc) * 1024))[tid - 128];
  };
  auto stageB = [&](int kc, int buf) {
    const u32x4_t* sh = (const u32x4_t*)(WTd1h + (size_t)kc * 8192);
    const u32x4_t* sl = (const u32x4_t*)(WTd1l + (size_t)kc * 8192);
    u32x4_t* dh = (u32x4_t*)BstH[buf];
    u32x4_t* dl = (u32x4_t*)BstL[buf];
    #pragma unroll
    for (int i = 0; i < 4; i++) { dh[tid + i * 256] = sh[tid + i * 256]; dl[tid + i * 256] = sl[tid + i * 256]; }
  };

  if (tid < 64) qs[tid >> 1][tid & 1] = qxy[((size_t)bt * 32 + (tid >> 1)) * 2 + (tid & 1)];
  stageA(0, 0); stageB(0, 0);
  __syncthreads();

  f32x4_t acc[2][4];
  #pragma unroll
  for (int cb = 0; cb < 4; cb++) {
    int col = wv * 64 + cb * 16 + llo;
    float wa = Wd1[256 * FF + col], wb = Wd1[257 * FF + col], bc = bd1[col];
    #pragma unroll
    for (int rb = 0; rb < 2; rb++) {
      f32x4_t t;
      #pragma unroll
      for (int r = 0; r < 4; r++) {
        int row = rb * 16 + lhi * 4 + r;
        t[r] = bc + qs[row][0] * wa + qs[row][1] * wb;
      }
      acc[rb][cb] = t;
    }
  }

  for (int kc = 0; kc < 8; kc++) {
    int cur = kc & 1;
    if (kc < 7) { stageA(kc + 1, cur ^ 1); stageB(kc + 1, cur ^ 1); }
    u32x4_t a0h = *(const u32x4_t*)&AstH[cur][llo * 32 + lhi * 8];
    u32x4_t a0l = *(const u32x4_t*)&AstL[cur][llo * 32 + lhi * 8];
    u32x4_t a1h = *(const u32x4_t*)&AstH[cur][(llo + 16) * 32 + lhi * 8];
    u32x4_t a1l = *(const u32x4_t*)&AstL[cur][(llo + 16) * 32 + lhi * 8];
    #pragma unroll
    for (int cb = 0; cb < 4; cb++) {
      int off = (wv * 64 + cb * 16 + llo) * 32 + lhi * 8;
      u32x4_t bh = *(const u32x4_t*)&BstH[cur][off];
      u32x4_t bl = *(const u32x4_t*)&BstL[cur][off];
      acc[0][cb] = mfma16(a0h, bh, mfma16(a0h, bl, mfma16(a0l, bh, acc[0][cb])));
      acc[1][cb] = mfma16(a1h, bh, mfma16(a1h, bl, mfma16(a1l, bh, acc[1][cb])));
    }
    __syncthreads();
  }

  float po[2][4][3];
  #pragma unroll
  for (int rb = 0; rb < 2; rb++)
    #pragma unroll
    for (int r = 0; r < 4; r++) { po[rb][r][0] = 0.f; po[rb][r][1] = 0.f; po[rb][r][2] = 0.f; }
  #pragma unroll
  for (int rb = 0; rb < 2; rb++)
    #pragma unroll
    for (int cb = 0; cb < 4; cb++) {
      int col = wv * 64 + cb * 16 + llo;
      float w0 = Wd2[col * 3], w1 = Wd2[col * 3 + 1], w2 = Wd2[col * 3 + 2];
      f32x4_t v = acc[rb][cb];
      #pragma unroll
      for (int r = 0; r < 4; r++) {
        float hv = fmaxf(v[r], 0.f);
        po[rb][r][0] += hv * w0; po[rb][r][1] += hv * w1; po[rb][r][2] += hv * w2;
      }
    }
  #pragma unroll
  for (int o = 8; o; o >>= 1)
    #pragma unroll
    for (int rb = 0; rb < 2; rb++)
      #pragma unroll
      for (int r = 0; r < 4; r++) {
        po[rb][r][0] += __shfl_xor(po[rb][r][0], o);
        po[rb][r][1] += __shfl_xor(po[rb][r][1], o);
        po[rb][r][2] += __shfl_xor(po[rb][r][2], o);
      }
  if (llo == 0) {
    #pragma unroll
    for (int rb = 0; rb < 2; rb++)
      #pragma unroll
      for (int r = 0; r < 4; r++) {
        int row = rb * 16 + lhi * 4 + r;
        red[wv][row][0] = po[rb][r][0];
        red[wv][row][1] = po[rb][r][1];
        red[wv][row][2] = po[rb][r][2];
      }
  }
  __syncthreads();
  if (tid < 96) {
    int row = tid / 3, o = tid % 3;
    float s = red[0][row][o] + red[1][row][o] + red[2][row][o] + red[3][row][o] + bd2[o];
    out[((size_t)bt * 32 + row) * 3 + o] = s;
  }
}

extern "C" void kernel_launch(void* const* d_in, const int* in_sizes, int n_in,
                              void* d_out, int out_size, void* d_ws, size_t ws_size,
                              hipStream_t stream) {
  const float* inx = (const float*)d_in[0];
  const float* iny = (const float*)d_in[1];
  const float* qxy = (const float*)d_in[2];
  const float* npos = (const float*)d_in[3];
  const float* We1 = (const float*)d_in[4];
  const float* be1 = (const float*)d_in[5];
  const float* We2 = (const float*)d_in[6];
  const float* be2 = (const float*)d_in[7];
  const float* Wg  = (const float*)d_in[8];
  const float* bg  = (const float*)d_in[9];
  const float* lng = (const float*)d_in[10];
  const float* lnb = (const float*)d_in[11];
  const float* Wd1 = (const float*)d_in[12];
  const float* bd1 = (const float*)d_in[13];
  const float* Wd2 = (const float*)d_in[14];
  const float* bd2 = (const float*)d_in[15];
  const int* eidx  = (const int*)d_in[16];
  float* out = (float*)d_out;

  char* w = (char*)d_ws;
  auto carve = [&](size_t n) { char* p = w; w += (n + 255) & ~(size_t)255; return p; };
  char* encR = carve((size_t)2 * BB * NP * FF * 2);                          // 32 MB
  unsigned short* encTh = (unsigned short*)encR;                             // 16 MB
  unsigned short* encTl = (unsigned short*)(encR + (size_t)BB * NP * FF * 2);// 16 MB
  // latT hi/lo alias encT (dead after proj1)
  unsigned short* latTh = encTh;
  unsigned short* latTl = encTl;
  float* xA = (float*)carve((size_t)BB * NN * FF * 4);                       // 8 MB
  float* xB = (float*)carve((size_t)BB * NN * FF * 4);                       // 8 MB
  unsigned short* xTh = (unsigned short*)carve((size_t)BB * NN * FF * 2);    // 4 MB
  unsigned short* xTl = (unsigned short*)carve((size_t)BB * NN * FF * 2);    // 4 MB
  char* partR = carve((size_t)4 * BB * NN * FF * 4);                         // 32 MB
  float* part = (float*)partR;
  unsigned short* gh = (unsigned short*)partR;                               // alias (dead after reduce)
  unsigned short* gl = (unsigned short*)(partR + (size_t)BB * NN * FF * 2);
  float* mI   = (float*)carve((size_t)BB * NP * 4);
  float* liI  = (float*)carve((size_t)BB * NP * 4);
  float* mQ   = (float*)carve((size_t)BB * NP * 4);
  float* liQ  = (float*)carve((size_t)BB * NP * 4);
  unsigned short* WTe2h = (unsigned short*)carve((size_t)8 * 256 * 32 * 2);
  unsigned short* WTe2l = (unsigned short*)carve((size_t)8 * 256 * 32 * 2);
  unsigned short* WTgh  = (unsigned short*)carve((size_t)8 * 256 * 32 * 2);
  unsigned short* WTgl  = (unsigned short*)carve((size_t)8 * 256 * 32 * 2);
  unsigned short* WTd1h = (unsigned short*)carve((size_t)8 * 256 * 32 * 2);
  unsigned short* WTd1l = (unsigned short*)carve((size_t)8 * 256 * 32 * 2);
  float* sposW = (float*)carve((size_t)NN * FF * 4);
  float* dinv = (float*)carve(NN * 4);
  float* spos = (float*)carve(NN * 2 * 4);
  float* csw  = (float*)carve((NE + NN) * 4);
  int* degI   = (int*)carve(NN * 4);
  int* coff   = (int*)carve((NN + 1) * 4);
  int* csrc   = (int*)carve((NE + NN) * 4);
  int* cntg   = (int*)carve((size_t)8 * NN * 4);

  const int* esrc = eidx;
  const int* edst = eidx + NE;

  k_deg_init<<<dim3(4), dim3(256), 0, stream>>>(degI);
  k_deg_count<<<dim3(32), dim3(256), 0, stream>>>(edst, degI);
  k_scan<<<dim3(1), dim3(1024), 0, stream>>>(degI, dinv, coff);
  k_cnt<<<dim3(8), dim3(1024), 0, stream>>>(edst, cntg);
  k_fill2<<<dim3(9), dim3(1024), 0, stream>>>(esrc, edst, dinv, coff, cntg, csrc, csw);
  k_spos<<<dim3(4), dim3(256), 0, stream>>>(npos, coff, csrc, csw, spos);
  k_posb<<<dim3(NN), dim3(256), 0, stream>>>(spos, Wg, bg, sposW);
  k_pack_w<<<dim3(8, 3), dim3(256), 0, stream>>>(We2, Wg, Wd1, WTe2h, WTe2l, WTgh, WTgl,
                                                 WTd1h, WTd1l);

  k_stats<<<dim3(BB * NP / 4), dim3(256), 0, stream>>>(inx, npos, mI, liI);
  k_encoder<<<dim3(BB * NP / 32), dim3(256), 0, stream>>>(inx, iny, We1, be1, WTe2h, WTe2l, be2,
                                                          encTh, encTl);
  k_proj1<<<dim3(32, 8, 4), dim3(256), 0, stream>>>(inx, mI, liI, npos, encTh, encTl, part);
  k_reduce<<<dim3(BB * NN * FF / 1024), dim3(256), 0, stream>>>(part, xA);
  for (int s = 0; s < NSTEP; s++) {
    const float* xi = (s & 1) ? xB : xA;
    float* xo = (s & 1) ? xA : xB;
    k_gather<<<dim3(NN / 8, BB), dim3(256), 0, stream>>>(xi, coff, csrc, csw, gh, gl);
    k_gemmLN<<<dim3(NN / 32, BB), dim3(256), 0, stream>>>(gh, gl, xi, xo, sposW, WTgh, WTgl,
                                                          lng, lnb);
  }
  const float* xf = (NSTEP & 1) ? xB : xA;
  k_xT<<<dim3(32, 8), dim3(256), 0, stream>>>(xf, xTh, xTl);
  k_stats<<<dim3(BB * NP / 4), dim3(256), 0, stream>>>(qxy, npos, mQ, liQ);
  k_proj2<<<dim3(128, 8), dim3(256), 0, stream>>>(qxy, mQ, liQ, npos, xTh, xTl, latTh, latTl);
  k_decoder<<<dim3(BB * NP / 32), dim3(256), 0, stream>>>(latTh, latTl, qxy, WTd1h, WTd1l,
                                                          bd1, Wd1, Wd2, bd2, out);
}

// Round 5
// 765.950 us; speedup vs baseline: 2.4210x; 1.1937x over previous
//
#include <hip/hip_runtime.h>

#define BB 8
#define NP 4096    // NPTS == NQ
#define NN 1024
#define NE 8192
#define FF 256
#define TS 264
#define NSTEP 16
#define NSEG 64
#define SEGSZ 128  // NSEG*SEGSZ == NE

typedef float f32x4_t __attribute__((ext_vector_type(4)));
typedef __bf16 bf16x8_t __attribute__((ext_vector_type(8)));
typedef unsigned int u32x4_t __attribute__((ext_vector_type(4)));
typedef unsigned int u32x2_t __attribute__((ext_vector_type(2)));

static __device__ __forceinline__ unsigned short f2bf(float f) {
  union { float f; unsigned u; } v; v.f = f;
  unsigned u = v.u + 0x7FFFu + ((v.u >> 16) & 1u);
  return (unsigned short)(u >> 16);
}
static __device__ __forceinline__ float ashf(unsigned short s) {
  union { unsigned u; float f; } t; t.u = (unsigned)s << 16; return t.f;
}
// split a,b into hi/lo bf16 pairs packed as u32
static __device__ __forceinline__ void split_pk(float a, float b, unsigned& h, unsigned& l) {
  unsigned short ha = f2bf(a), hb = f2bf(b);
  unsigned short la = f2bf(a - ashf(ha)), lb = f2bf(b - ashf(hb));
  h = (unsigned)ha | ((unsigned)hb << 16);
  l = (unsigned)la | ((unsigned)lb << 16);
}
static __device__ __forceinline__ f32x4_t mfma16(u32x4_t a, u32x4_t b, f32x4_t c) {
  return __builtin_amdgcn_mfma_f32_16x16x32_bf16(
      __builtin_bit_cast(bf16x8_t, a), __builtin_bit_cast(bf16x8_t, b), c, 0, 0, 0);
}

// ---------------- graph preprocessing (segmented, deterministic) ----------------
// per-(segment, node) match counts
__global__ __launch_bounds__(1024) void k_cnt(const int* __restrict__ dstA,
                                              int* __restrict__ cntg) {
  __shared__ int ds[SEGSZ];
  int seg = blockIdx.x, n = threadIdx.x;
  if (n < SEGSZ) ds[n] = dstA[seg * SEGSZ + n];
  __syncthreads();
  int c = 0;
  #pragma unroll 8
  for (int e = 0; e < SEGSZ; e++) c += (ds[e] == n) ? 1 : 0;
  cntg[seg * NN + n] = c;
}

// degrees from segment counts (+1 self loop), rsqrt, prefix scan -> csr_off
__global__ __launch_bounds__(1024) void k_scan2(const int* __restrict__ cntg,
    float* __restrict__ dinv, int* __restrict__ csr_off) {
  __shared__ int s[NN];
  int n = threadIdx.x;
  int c = 1;
  for (int sg = 0; sg < NSEG; sg++) c += cntg[sg * NN + n];
  dinv[n] = rsqrtf((float)c);
  s[n] = c;
  __syncthreads();
  for (int st = 1; st < NN; st <<= 1) {
    int v = (n >= st) ? s[n - st] : 0;
    __syncthreads();
    s[n] += v;
    __syncthreads();
  }
  csr_off[n] = s[n] - c;
  if (n == NN - 1) csr_off[NN] = s[n];
}

// fill CSR deterministically (edge order preserved); block NSEG = self loops
__global__ __launch_bounds__(1024) void k_fill2(const int* __restrict__ srcA,
    const int* __restrict__ dstA, const float* __restrict__ dinv,
    const int* __restrict__ csr_off, const int* __restrict__ cntg,
    int* __restrict__ csr_src, float* __restrict__ csr_w) {
  int n = threadIdx.x;
  if (blockIdx.x == NSEG) {
    int pos = csr_off[n + 1] - 1;               // self loop last
    csr_src[pos] = n;
    csr_w[pos] = dinv[n] * dinv[n];
    return;
  }
  __shared__ int ds[SEGSZ], ss[SEGSZ];
  int seg = blockIdx.x;
  if (n < SEGSZ) { ds[n] = dstA[seg * SEGSZ + n]; ss[n] = srcA[seg * SEGSZ + n]; }
  __syncthreads();
  int base = csr_off[n];
  for (int s2 = 0; s2 < seg; s2++) base += cntg[s2 * NN + n];
  float dn = dinv[n];
  for (int e = 0; e < SEGSZ; e++) {
    if (ds[e] == n) {
      int sv = ss[e];
      csr_src[base] = sv;
      csr_w[base] = dinv[sv] * dn;
      base++;
    }
  }
}

__global__ __launch_bounds__(256) void k_spos(const float* __restrict__ npos,
    const int* __restrict__ csr_off, const int* __restrict__ csr_src,
    const float* __restrict__ csr_w, float* __restrict__ spos) {
  int n = blockIdx.x * 256 + threadIdx.x;
  if (n >= NN) return;
  float sx = 0.f, sy = 0.f;
  int e1 = csr_off[n + 1];
  for (int e = csr_off[n]; e < e1; e++) {
    float w = csr_w[e]; int s = csr_src[e];
    sx += w * npos[2 * s]; sy += w * npos[2 * s + 1];
  }
  spos[2 * n] = sx; spos[2 * n + 1] = sy;
}

// sposW[n][f] = spos[n] @ Wg[0:2] + bg  (step-invariant part of agg)
__global__ __launch_bounds__(256) void k_posb(const float* __restrict__ spos,
    const float* __restrict__ Wg, const float* __restrict__ bg, float* __restrict__ sposW) {
  int n = blockIdx.x, f = threadIdx.x;
  sposW[(size_t)n * FF + f] = spos[2 * n] * Wg[f] + spos[2 * n + 1] * Wg[FF + f] + bg[f];
}

// ---------------- softmax stats (inputs and queries in one launch) ----------------
__global__ __launch_bounds__(256) void k_stats(const float* __restrict__ inx,
    const float* __restrict__ qxy, const float* __restrict__ npos,
    float* __restrict__ mI, float* __restrict__ liI,
    float* __restrict__ mQ, float* __restrict__ liQ) {
  const float* xy = blockIdx.y ? qxy : inx;
  float* mOut = blockIdx.y ? mQ : mI;
  float* liOut = blockIdx.y ? liQ : liI;
  int wv = threadIdx.x >> 6, lane = threadIdx.x & 63;
  int pt = blockIdx.x * 4 + wv;
  float px = xy[pt * 2], py = xy[pt * 2 + 1];
  float s[16];
  float m = -1e30f;
  #pragma unroll
  for (int k = 0; k < 16; k++) {
    int n = lane + 64 * k;
    float2 np = ((const float2*)npos)[n];
    float dx = px - np.x, dy = py - np.y;
    float v = -(dx * dx + dy * dy);
    s[k] = v; m = fmaxf(m, v);
  }
  #pragma unroll
  for (int o = 32; o; o >>= 1) m = fmaxf(m, __shfl_xor(m, o));
  float l = 0.f;
  #pragma unroll
  for (int k = 0; k < 16; k++) l += __expf(s[k] - m);
  #pragma unroll
  for (int o = 32; o; o >>= 1) l += __shfl_xor(l, o);
  if (lane == 0) { mOut[pt] = m; liOut[pt] = 1.0f / l; }
}

// ---------------- weight prepack: WT[kc][n][kk] bf16 hi+lo ----------------
__global__ __launch_bounds__(256) void k_pack_w(const float* __restrict__ We2,
    const float* __restrict__ Wg, const float* __restrict__ Wd1,
    unsigned short* __restrict__ WTe2h, unsigned short* __restrict__ WTe2l,
    unsigned short* __restrict__ WTgh, unsigned short* __restrict__ WTgl,
    unsigned short* __restrict__ WTd1h, unsigned short* __restrict__ WTd1l) {
  int kc = blockIdx.x, which = blockIdx.y, n = threadIdx.x;
  const float* W = (which == 0) ? We2 : (which == 1) ? (Wg + 2 * FF) : Wd1;
  unsigned short* Dh = (which == 0) ? WTe2h : (which == 1) ? WTgh : WTd1h;
  unsigned short* Dl = (which == 0) ? WTe2l : (which == 1) ? WTgl : WTd1l;
  unsigned hu[16], lu[16];
  #pragma unroll
  for (int i = 0; i < 16; i++) {
    float a = W[(kc * 32 + 2 * i) * FF + n];
    float b = W[(kc * 32 + 2 * i + 1) * FF + n];
    split_pk(a, b, hu[i], lu[i]);
  }
  u32x4_t* dvh = (u32x4_t*)(Dh + ((size_t)kc * 256 + n) * 32);
  u32x4_t* dvl = (u32x4_t*)(Dl + ((size_t)kc * 256 + n) * 32);
  #pragma unroll
  for (int i = 0; i < 4; i++) {
    u32x4_t th = {hu[4 * i], hu[4 * i + 1], hu[4 * i + 2], hu[4 * i + 3]};
    u32x4_t tl = {lu[4 * i], lu[4 * i + 1], lu[4 * i + 2], lu[4 * i + 3]};
    dvh[i] = th; dvl[i] = tl;
  }
}

// ---------------- encoder: L1 fp32 VALU, L2 split-MFMA; writes encT hi+lo ----------------
__global__ __launch_bounds__(256) void k_encoder(const float* __restrict__ inx,
    const float* __restrict__ iny, const float* __restrict__ We1,
    const float* __restrict__ be1, const unsigned short* __restrict__ WTe2h,
    const unsigned short* __restrict__ WTe2l, const float* __restrict__ be2,
    unsigned short* __restrict__ encTh, unsigned short* __restrict__ encTl) {
  __shared__ float xin[32][8];
  __shared__ float h[32][TS];
  __shared__ unsigned short Bh[8192];
  __shared__ unsigned short Bl[8192];
  int tid = threadIdx.x;
  int row0 = blockIdx.x * 32;
  int wv = tid >> 6, L = tid & 63, lhi = L >> 4, llo = L & 15;

  if (tid < 160) {
    int pt = tid / 5, d = tid % 5;
    int r = row0 + pt;
    xin[pt][d] = (d < 2) ? inx[r * 2 + d] : iny[r * 3 + (d - 2)];
  }
  __syncthreads();
  {
    int f = tid;
    float w0 = We1[f], w1 = We1[256 + f], w2 = We1[512 + f], w3 = We1[768 + f], w4 = We1[1024 + f];
    float bb = be1[f];
    #pragma unroll 4
    for (int pt = 0; pt < 32; pt++) {
      float v = bb + xin[pt][0]*w0 + xin[pt][1]*w1 + xin[pt][2]*w2 + xin[pt][3]*w3 + xin[pt][4]*w4;
      h[pt][f] = fmaxf(v, 0.f);
    }
  }

  f32x4_t acc[2][4];
  #pragma unroll
  for (int cb = 0; cb < 4; cb++) {
    float bc = be2[wv * 64 + cb * 16 + llo];
    f32x4_t t = {bc, bc, bc, bc};
    acc[0][cb] = t; acc[1][cb] = t;
  }

  for (int kc = 0; kc < 8; kc++) {
    __syncthreads();
    {
      const u32x4_t* sh = (const u32x4_t*)(WTe2h + (size_t)kc * 8192);
      const u32x4_t* sl = (const u32x4_t*)(WTe2l + (size_t)kc * 8192);
      u32x4_t* dh = (u32x4_t*)Bh;
      u32x4_t* dl = (u32x4_t*)Bl;
      #pragma unroll
      for (int i = 0; i < 4; i++) { dh[tid + i * 256] = sh[tid + i * 256]; dl[tid + i * 256] = sl[tid + i * 256]; }
    }
    __syncthreads();
    int kbase = kc * 32 + lhi * 8;
    u32x4_t a0h, a0l, a1h, a1l;
    {
      float p[8];
      *(f32x4_t*)p = *(const f32x4_t*)&h[llo][kbase];
      *(f32x4_t*)(p + 4) = *(const f32x4_t*)&h[llo][kbase + 4];
      unsigned hw[4], lw[4];
      #pragma unroll
      for (int i = 0; i < 4; i++) split_pk(p[2 * i], p[2 * i + 1], hw[i], lw[i]);
      u32x4_t th = {hw[0], hw[1], hw[2], hw[3]}; a0h = th;
      u32x4_t tl = {lw[0], lw[1], lw[2], lw[3]}; a0l = tl;
    }
    {
      float p[8];
      *(f32x4_t*)p = *(const f32x4_t*)&h[llo + 16][kbase];
      *(f32x4_t*)(p + 4) = *(const f32x4_t*)&h[llo + 16][kbase + 4];
      unsigned hw[4], lw[4];
      #pragma unroll
      for (int i = 0; i < 4; i++) split_pk(p[2 * i], p[2 * i + 1], hw[i], lw[i]);
      u32x4_t th = {hw[0], hw[1], hw[2], hw[3]}; a1h = th;
      u32x4_t tl = {lw[0], lw[1], lw[2], lw[3]}; a1l = tl;
    }
    #pragma unroll
    for (int cb = 0; cb < 4; cb++) {
      int off = (wv * 64 + cb * 16 + llo) * 32 + lhi * 8;
      u32x4_t bh = *(const u32x4_t*)&Bh[off];
      u32x4_t bl = *(const u32x4_t*)&Bl[off];
      acc[0][cb] = mfma16(a0h, bh, mfma16(a0h, bl, mfma16(a0l, bh, acc[0][cb])));
      acc[1][cb] = mfma16(a1h, bh, mfma16(a1h, bl, mfma16(a1l, bh, acc[1][cb])));
    }
  }
  #pragma unroll
  for (int rb = 0; rb < 2; rb++)
    #pragma unroll
    for (int cb = 0; cb < 4; cb++) {
      int col = wv * 64 + cb * 16 + llo;
      f32x4_t v = acc[rb][cb];
      size_t idx = ((size_t)blockIdx.x * 256 + col) * 32 + rb * 16 + lhi * 4;
      unsigned hw0, lw0, hw1, lw1;
      split_pk(v[0], v[1], hw0, lw0);
      split_pk(v[2], v[3], hw1, lw1);
      u32x2_t wh = {hw0, hw1}; *(u32x2_t*)&encTh[idx] = wh;
      u32x2_t wl = {lw0, lw1}; *(u32x2_t*)&encTl[idx] = wl;
    }
}

// ---------------- proj1 (split-K, 3-term split MFMA): part[z][b][n][f] ----------------
__global__ __launch_bounds__(256) void k_proj1(const float* __restrict__ inx,
    const float* __restrict__ mI, const float* __restrict__ liI,
    const float* __restrict__ npos, const unsigned short* __restrict__ encTh,
    const unsigned short* __restrict__ encTl, float* __restrict__ part) {
  __shared__ unsigned short BstH[2][8192];
  __shared__ unsigned short BstL[2][8192];
  __shared__ unsigned short AstH[2][1024];
  __shared__ unsigned short AstL[2][1024];
  int tid = threadIdx.x;
  int n0 = blockIdx.x * 32, b = blockIdx.y, z = blockIdx.z;
  int wv = tid >> 6, L = tid & 63, lhi = L >> 4, llo = L & 15;
  int an = tid >> 3, ap = (tid & 7) * 4;
  float2 npv = ((const float2*)npos)[n0 + an];
  int pbase0 = b * NP + z * 1024;

  auto stageA = [&](int kc, int buf) {
    int p = pbase0 + kc * 32 + ap;
    float c[4];
    #pragma unroll
    for (int j = 0; j < 4; j++) {
      float2 pxy = ((const float2*)inx)[p + j];
      float mm = mI[p + j], ll = liI[p + j];
      float dx = pxy.x - npv.x, dy = pxy.y - npv.y;
      c[j] = __expf(-(dx * dx + dy * dy) - mm) * ll;
    }
    unsigned hw0, lw0, hw1, lw1;
    split_pk(c[0], c[1], hw0, lw0);
    split_pk(c[2], c[3], hw1, lw1);
    u32x2_t wh = {hw0, hw1}; *(u32x2_t*)&AstH[buf][an * 32 + ap] = wh;
    u32x2_t wl = {lw0, lw1}; *(u32x2_t*)&AstL[buf][an * 32 + ap] = wl;
  };
  auto stageB = [&](int kc, int buf) {
    const u32x4_t* sh = (const u32x4_t*)(encTh + (size_t)(b * 128 + z * 32 + kc) * 8192);
    const u32x4_t* sl = (const u32x4_t*)(encTl + (size_t)(b * 128 + z * 32 + kc) * 8192);
    u32x4_t* dh = (u32x4_t*)BstH[buf];
    u32x4_t* dl = (u32x4_t*)BstL[buf];
    #pragma unroll
    for (int i = 0; i < 4; i++) { dh[tid + i * 256] = sh[tid + i * 256]; dl[tid + i * 256] = sl[tid + i * 256]; }
  };

  f32x4_t acc[2][4];
  #pragma unroll
  for (int i = 0; i < 2; i++)
    #pragma unroll
    for (int j = 0; j < 4; j++) { f32x4_t t = {0.f, 0.f, 0.f, 0.f}; acc[i][j] = t; }

  stageA(0, 0); stageB(0, 0);
  __syncthreads();
  for (int kc = 0; kc < 32; kc++) {
    int cur = kc & 1;
    if (kc < 31) { stageA(kc + 1, cur ^ 1); stageB(kc + 1, cur ^ 1); }
    u32x4_t a0h = *(const u32x4_t*)&AstH[cur][llo * 32 + lhi * 8];
    u32x4_t a0l = *(const u32x4_t*)&AstL[cur][llo * 32 + lhi * 8];
    u32x4_t a1h = *(const u32x4_t*)&AstH[cur][(llo + 16) * 32 + lhi * 8];
    u32x4_t a1l = *(const u32x4_t*)&AstL[cur][(llo + 16) * 32 + lhi * 8];
    #pragma unroll
    for (int cb = 0; cb < 4; cb++) {
      int off = (wv * 64 + cb * 16 + llo) * 32 + lhi * 8;
      u32x4_t bh = *(const u32x4_t*)&BstH[cur][off];
      u32x4_t bl = *(const u32x4_t*)&BstL[cur][off];
      acc[0][cb] = mfma16(a0h, bh, mfma16(a0h, bl, mfma16(a0l, bh, acc[0][cb])));
      acc[1][cb] = mfma16(a1h, bh, mfma16(a1h, bl, mfma16(a1l, bh, acc[1][cb])));
    }
    __syncthreads();
  }
  float* op = part + (((size_t)(z * BB + b)) * NN + n0) * FF;
  #pragma unroll
  for (int rb = 0; rb < 2; rb++)
    #pragma unroll
    for (int cb = 0; cb < 4; cb++) {
      int col = wv * 64 + cb * 16 + llo;
      f32x4_t v = acc[rb][cb];
      #pragma unroll
      for (int r = 0; r < 4; r++) op[(rb * 16 + lhi * 4 + r) * FF + col] = v[r];
    }
}

// reduce split-K parts -> x (fp32)
__global__ __launch_bounds__(256) void k_reduce(const float* __restrict__ part,
                                                float* __restrict__ x) {
  size_t i = ((size_t)blockIdx.x * 256 + threadIdx.x) * 4;
  const size_t S = (size_t)BB * NN * FF;
  f32x4_t a = *(const f32x4_t*)&part[i];
  f32x4_t b = *(const f32x4_t*)&part[S + i];
  f32x4_t c = *(const f32x4_t*)&part[2 * S + i];
  f32x4_t d = *(const f32x4_t*)&part[3 * S + i];
  f32x4_t r = (a + b) + (c + d);
  *(f32x4_t*)&x[i] = r;
}

// ---------------- fused msg step: gather -> LDS, split MFMA, LN ----------------
__global__ __launch_bounds__(256) void k_msg2(const float* __restrict__ x_in,
    float* __restrict__ x_out, const float* __restrict__ sposW,
    const int* __restrict__ coff, const int* __restrict__ csrc,
    const float* __restrict__ csw, const unsigned short* __restrict__ WTgh,
    const unsigned short* __restrict__ WTgl, const float* __restrict__ lng,
    const float* __restrict__ lnb, int last,
    unsigned short* __restrict__ xTh, unsigned short* __restrict__ xTl) {
  __shared__ unsigned Ah[32][132];
  __shared__ unsigned Al[32][132];
  __shared__ unsigned short Bh[8192];
  __shared__ unsigned short Bl[8192];
  __shared__ float redS[32][4];
  __shared__ float redQ[32][4];
  int tid = threadIdx.x;
  int n0 = blockIdx.x * 32, b = blockIdx.y;
  int wv = tid >> 6, L = tid & 63, lhi = L >> 4, llo = L & 15;

  // gather phase: 8 threads per row, 32 features each; same edge order as before
  {
    int row = tid >> 3, seg = tid & 7;
    int n = n0 + row;
    float g[32];
    #pragma unroll
    for (int i = 0; i < 32; i++) g[i] = 0.f;
    int e0 = coff[n], e1 = coff[n + 1];
    for (int e = e0; e < e1; e++) {
      float w = csw[e];
      int s = csrc[e];
      const f32x4_t* px = (const f32x4_t*)(x_in + ((size_t)b * NN + s) * FF + seg * 32);
      #pragma unroll
      for (int i = 0; i < 8; i++) {
        f32x4_t v = px[i];
        g[4*i]   += w * v[0]; g[4*i+1] += w * v[1];
        g[4*i+2] += w * v[2]; g[4*i+3] += w * v[3];
      }
    }
    #pragma unroll
    for (int i = 0; i < 16; i++) {
      unsigned h, l;
      split_pk(g[2 * i], g[2 * i + 1], h, l);
      Ah[row][seg * 16 + i] = h;
      Al[row][seg * 16 + i] = l;
    }
  }

  f32x4_t acc[2][4];
  #pragma unroll
  for (int i = 0; i < 2; i++)
    #pragma unroll
    for (int j = 0; j < 4; j++) { f32x4_t t = {0.f, 0.f, 0.f, 0.f}; acc[i][j] = t; }

  for (int kc = 0; kc < 8; kc++) {
    __syncthreads();
    {
      const u32x4_t* sh = (const u32x4_t*)(WTgh + (size_t)kc * 8192);
      const u32x4_t* sl = (const u32x4_t*)(WTgl + (size_t)kc * 8192);
      u32x4_t* dh = (u32x4_t*)Bh;
      u32x4_t* dl = (u32x4_t*)Bl;
      #pragma unroll
      for (int i = 0; i < 4; i++) { dh[tid + i * 256] = sh[tid + i * 256]; dl[tid + i * 256] = sl[tid + i * 256]; }
    }
    __syncthreads();
    u32x4_t a0h = *(const u32x4_t*)&Ah[llo][kc * 16 + lhi * 4];
    u32x4_t a0l = *(const u32x4_t*)&Al[llo][kc * 16 + lhi * 4];
    u32x4_t a1h = *(const u32x4_t*)&Ah[llo + 16][kc * 16 + lhi * 4];
    u32x4_t a1l = *(const u32x4_t*)&Al[llo + 16][kc * 16 + lhi * 4];
    #pragma unroll
    for (int cb = 0; cb < 4; cb++) {
      int off = (wv * 64 + cb * 16 + llo) * 32 + lhi * 8;
      u32x4_t bh = *(const u32x4_t*)&Bh[off];
      u32x4_t bl = *(const u32x4_t*)&Bl[off];
      acc[0][cb] = mfma16(a0h, bh, mfma16(a0h, bl, mfma16(a0l, bh, acc[0][cb])));
      acc[1][cb] = mfma16(a1h, bh, mfma16(a1h, bl, mfma16(a1l, bh, acc[1][cb])));
    }
  }

  // epilogue: + sposW + residual, then LayerNorm
  #pragma unroll
  for (int rb = 0; rb < 2; rb++)
    #pragma unroll
    for (int cb = 0; cb < 4; cb++) {
      int col = wv * 64 + cb * 16 + llo;
      #pragma unroll
      for (int r = 0; r < 4; r++) {
        int row = rb * 16 + lhi * 4 + r;
        float sw = sposW[(size_t)(n0 + row) * FF + col];
        float xr = x_in[((size_t)b * NN + n0 + row) * FF + col];
        acc[rb][cb][r] += sw + xr;
      }
    }
  float ps[2][4], pq[2][4];
  #pragma unroll
  for (int rb = 0; rb < 2; rb++)
    #pragma unroll
    for (int r = 0; r < 4; r++) {
      float s = 0.f, q = 0.f;
      #pragma unroll
      for (int cb = 0; cb < 4; cb++) { float y = acc[rb][cb][r]; s += y; q += y * y; }
      #pragma unroll
      for (int m = 1; m < 16; m <<= 1) { s += __shfl_xor(s, m); q += __shfl_xor(q, m); }
      ps[rb][r] = s; pq[rb][r] = q;
    }
  if (llo == 0) {
    #pragma unroll
    for (int rb = 0; rb < 2; rb++)
      #pragma unroll
      for (int r = 0; r < 4; r++) {
        int row = rb * 16 + lhi * 4 + r;
        redS[row][wv] = ps[rb][r];
        redQ[row][wv] = pq[rb][r];
      }
  }
  __syncthreads();
  float mrs[2][4][2];
  #pragma unroll
  for (int rb = 0; rb < 2; rb++)
    #pragma unroll
    for (int r = 0; r < 4; r++) {
      int row = rb * 16 + lhi * 4 + r;
      float S = redS[row][0] + redS[row][1] + redS[row][2] + redS[row][3];
      float Q = redQ[row][0] + redQ[row][1] + redQ[row][2] + redQ[row][3];
      float mean = S * (1.f / 256.f);
      float var = Q * (1.f / 256.f) - mean * mean;
      mrs[rb][r][0] = mean;
      mrs[rb][r][1] = rsqrtf(var + 1e-5f);
    }
  #pragma unroll
  for (int cb = 0; cb < 4; cb++) {
    int col = wv * 64 + cb * 16 + llo;
    float gg = lng[col], bb = lnb[col];
    #pragma unroll
    for (int rb = 0; rb < 2; rb++)
      #pragma unroll
      for (int r = 0; r < 4; r++) {
        int row = rb * 16 + lhi * 4 + r;
        float o = (acc[rb][cb][r] - mrs[rb][r][0]) * mrs[rb][r][1] * gg + bb;
        if (!last) {
          x_out[((size_t)b * NN + n0 + row) * FF + col] = o;
        } else {
          size_t idx = (((size_t)b * 32 + blockIdx.x) * 256 + col) * 32 + row;
          unsigned short hh = f2bf(o);
          xTh[idx] = hh;
          xTl[idx] = f2bf(o - ashf(hh));
        }
      }
  }
}

// ---------------- proj2 (3-term split MFMA): latT hi+lo [bt][fc][row][kk] ----------------
__global__ __launch_bounds__(256) void k_proj2(const float* __restrict__ qxy,
    const float* __restrict__ mQ, const float* __restrict__ liQ,
    const float* __restrict__ npos, const unsigned short* __restrict__ xTh,
    const unsigned short* __restrict__ xTl, unsigned short* __restrict__ latTh,
    unsigned short* __restrict__ latTl) {
  __shared__ unsigned short BstH[2][8192];
  __shared__ unsigned short BstL[2][8192];
  __shared__ unsigned short AstH[2][1024];
  __shared__ unsigned short AstL[2][1024];
  __shared__ float nps[NN * 2];
  int tid = threadIdx.x;
  int q0 = blockIdx.x * 32, b = blockIdx.y;
  int bt = b * 128 + blockIdx.x;
  int wv = tid >> 6, L = tid & 63, lhi = L >> 4, llo = L & 15;
  int aq = tid >> 3, an4 = (tid & 7) * 4;

  {
    const f32x4_t* s4 = (const f32x4_t*)npos;
    *(f32x4_t*)&nps[tid * 4] = s4[tid];
    *(f32x4_t*)&nps[(tid + 256) * 4] = s4[tid + 256];
  }
  int qg = b * NP + q0 + aq;
  float2 qv = ((const float2*)qxy)[qg];
  float qm = mQ[qg], qli = liQ[qg];
  __syncthreads();

  auto stageA = [&](int kc, int buf) {
    int nb = kc * 32 + an4;
    float c[4];
    #pragma unroll
    for (int j = 0; j < 4; j++) {
      float nx = nps[(nb + j) * 2], ny = nps[(nb + j) * 2 + 1];
      float dx = qv.x - nx, dy = qv.y - ny;
      c[j] = __expf(-(dx * dx + dy * dy) - qm) * qli;
    }
    unsigned hw0, lw0, hw1, lw1;
    split_pk(c[0], c[1], hw0, lw0);
    split_pk(c[2], c[3], hw1, lw1);
    u32x2_t wh = {hw0, hw1}; *(u32x2_t*)&AstH[buf][aq * 32 + an4] = wh;
    u32x2_t wl = {lw0, lw1}; *(u32x2_t*)&AstL[buf][aq * 32 + an4] = wl;
  };
  auto stageB = [&](int kc, int buf) {
    const u32x4_t* sh = (const u32x4_t*)(xTh + (size_t)(b * 32 + kc) * 8192);
    const u32x4_t* sl = (const u32x4_t*)(xTl + (size_t)(b * 32 + kc) * 8192);
    u32x4_t* dh = (u32x4_t*)BstH[buf];
    u32x4_t* dl = (u32x4_t*)BstL[buf];
    #pragma unroll
    for (int i = 0; i < 4; i++) { dh[tid + i * 256] = sh[tid + i * 256]; dl[tid + i * 256] = sl[tid + i * 256]; }
  };

  f32x4_t acc[2][4];
  #pragma unroll
  for (int i = 0; i < 2; i++)
    #pragma unroll
    for (int j = 0; j < 4; j++) { f32x4_t t = {0.f, 0.f, 0.f, 0.f}; acc[i][j] = t; }

  stageA(0, 0); stageB(0, 0);
  __syncthreads();
  for (int kc = 0; kc < 32; kc++) {
    int cur = kc & 1;
    if (kc < 31) { stageA(kc + 1, cur ^ 1); stageB(kc + 1, cur ^ 1); }
    u32x4_t a0h = *(const u32x4_t*)&AstH[cur][llo * 32 + lhi * 8];
    u32x4_t a0l = *(const u32x4_t*)&AstL[cur][llo * 32 + lhi * 8];
    u32x4_t a1h = *(const u32x4_t*)&AstH[cur][(llo + 16) * 32 + lhi * 8];
    u32x4_t a1l = *(const u32x4_t*)&AstL[cur][(llo + 16) * 32 + lhi * 8];
    #pragma unroll
    for (int cb = 0; cb < 4; cb++) {
      int off = (wv * 64 + cb * 16 + llo) * 32 + lhi * 8;
      u32x4_t bh = *(const u32x4_t*)&BstH[cur][off];
      u32x4_t bl = *(const u32x4_t*)&BstL[cur][off];
      acc[0][cb] = mfma16(a0h, bh, mfma16(a0h, bl, mfma16(a0l, bh, acc[0][cb])));
      acc[1][cb] = mfma16(a1h, bh, mfma16(a1h, bl, mfma16(a1l, bh, acc[1][cb])));
    }
    __syncthreads();
  }
  #pragma unroll
  for (int rb = 0; rb < 2; rb++)
    #pragma unroll
    for (int cb = 0; cb < 4; cb++) {
      int col = wv * 64 + cb * 16 + llo;
      int fc = col >> 5, kk = col & 31;
      f32x4_t v = acc[rb][cb];
      #pragma unroll
      for (int r = 0; r < 4; r++) {
        size_t idx = ((size_t)bt * 8 + fc) * 1024 + (rb * 16 + lhi * 4 + r) * 32 + kk;
        unsigned short hh = f2bf(v[r]);
        latTh[idx] = hh;
        latTl[idx] = f2bf(v[r] - ashf(hh));
      }
    }
}

// ---------------- decoder (3-term split MFMA + fused second GEMM) ----------------
__global__ __launch_bounds__(256) void k_decoder(const unsigned short* __restrict__ latTh,
    const unsigned short* __restrict__ latTl, const float* __restrict__ qxy,
    const unsigned short* __restrict__ WTd1h, const unsigned short* __restrict__ WTd1l,
    const float* __restrict__ bd1, const float* __restrict__ Wd1,
    const float* __restrict__ Wd2, const float* __restrict__ bd2, float* __restrict__ out) {
  __shared__ unsigned short BstH[2][8192];
  __shared__ unsigned short BstL[2][8192];
  __shared__ unsigned short AstH[2][1024];
  __shared__ unsigned short AstL[2][1024];
  __shared__ float qs[32][2];
  __shared__ float red[4][32][3];
  int tid = threadIdx.x;
  int bt = blockIdx.x;
  int wv = tid >> 6, L = tid & 63, lhi = L >> 4, llo = L & 15;

  auto stageA = [&](int kc, int buf) {
    if (tid < 128)
      ((u32x4_t*)AstH[buf])[tid] = ((const u32x4_t*)(latTh + ((size_t)bt * 8 + kc) * 1024))[tid];
    else
      ((u32x4_t*)AstL[buf])[tid - 128] = ((const u32x4_t*)(latTl + ((size_t)bt * 8 + kc) * 1024))[tid - 128];
  };
  auto stageB = [&](int kc, int buf) {
    const u32x4_t* sh = (const u32x4_t*)(WTd1h + (size_t)kc * 8192);
    const u32x4_t* sl = (const u32x4_t*)(WTd1l + (size_t)kc * 8192);
    u32x4_t* dh = (u32x4_t*)BstH[buf];
    u32x4_t* dl = (u32x4_t*)BstL[buf];
    #pragma unroll
    for (int i = 0; i < 4; i++) { dh[tid + i * 256] = sh[tid + i * 256]; dl[tid + i * 256] = sl[tid + i * 256]; }
  };

  if (tid < 64) qs[tid >> 1][tid & 1] = qxy[((size_t)bt * 32 + (tid >> 1)) * 2 + (tid & 1)];
  stageA(0, 0); stageB(0, 0);
  __syncthreads();

  f32x4_t acc[2][4];
  #pragma unroll
  for (int cb = 0; cb < 4; cb++) {
    int col = wv * 64 + cb * 16 + llo;
    float wa = Wd1[256 * FF + col], wb = Wd1[257 * FF + col], bc = bd1[col];
    #pragma unroll
    for (int rb = 0; rb < 2; rb++) {
      f32x4_t t;
      #pragma unroll
      for (int r = 0; r < 4; r++) {
        int row = rb * 16 + lhi * 4 + r;
        t[r] = bc + qs[row][0] * wa + qs[row][1] * wb;
      }
      acc[rb][cb] = t;
    }
  }

  for (int kc = 0; kc < 8; kc++) {
    int cur = kc & 1;
    if (kc < 7) { stageA(kc + 1, cur ^ 1); stageB(kc + 1, cur ^ 1); }
    u32x4_t a0h = *(const u32x4_t*)&AstH[cur][llo * 32 + lhi * 8];
    u32x4_t a0l = *(const u32x4_t*)&AstL[cur][llo * 32 + lhi * 8];
    u32x4_t a1h = *(const u32x4_t*)&AstH[cur][(llo + 16) * 32 + lhi * 8];
    u32x4_t a1l = *(const u32x4_t*)&AstL[cur][(llo + 16) * 32 + lhi * 8];
    #pragma unroll
    for (int cb = 0; cb < 4; cb++) {
      int off = (wv * 64 + cb * 16 + llo) * 32 + lhi * 8;
      u32x4_t bh = *(const u32x4_t*)&BstH[cur][off];
      u32x4_t bl = *(const u32x4_t*)&BstL[cur][off];
      acc[0][cb] = mfma16(a0h, bh, mfma16(a0h, bl, mfma16(a0l, bh, acc[0][cb])));
      acc[1][cb] = mfma16(a1h, bh, mfma16(a1h, bl, mfma16(a1l, bh, acc[1][cb])));
    }
    __syncthreads();
  }

  float po[2][4][3];
  #pragma unroll
  for (int rb = 0; rb < 2; rb++)
    #pragma unroll
    for (int r = 0; r < 4; r++) { po[rb][r][0] = 0.f; po[rb][r][1] = 0.f; po[rb][r][2] = 0.f; }
  #pragma unroll
  for (int rb = 0; rb < 2; rb++)
    #pragma unroll
    for (int cb = 0; cb < 4; cb++) {
      int col = wv * 64 + cb * 16 + llo;
      float w0 = Wd2[col * 3], w1 = Wd2[col * 3 + 1], w2 = Wd2[col * 3 + 2];
      f32x4_t v = acc[rb][cb];
      #pragma unroll
      for (int r = 0; r < 4; r++) {
        float hv = fmaxf(v[r], 0.f);
        po[rb][r][0] += hv * w0; po[rb][r][1] += hv * w1; po[rb][r][2] += hv * w2;
      }
    }
  #pragma unroll
  for (int o = 8; o; o >>= 1)
    #pragma unroll
    for (int rb = 0; rb < 2; rb++)
      #pragma unroll
      for (int r = 0; r < 4; r++) {
        po[rb][r][0] += __shfl_xor(po[rb][r][0], o);
        po[rb][r][1] += __shfl_xor(po[rb][r][1], o);
        po[rb][r][2] += __shfl_xor(po[rb][r][2], o);
      }
  if (llo == 0) {
    #pragma unroll
    for (int rb = 0; rb < 2; rb++)
      #pragma unroll
      for (int r = 0; r < 4; r++) {
        int row = rb * 16 + lhi * 4 + r;
        red[wv][row][0] = po[rb][r][0];
        red[wv][row][1] = po[rb][r][1];
        red[wv][row][2] = po[rb][r][2];
      }
  }
  __syncthreads();
  if (tid < 96) {
    int row = tid / 3, o = tid % 3;
    float s = red[0][row][o] + red[1][row][o] + red[2][row][o] + red[3][row][o] + bd2[o];
    out[((size_t)bt * 32 + row) * 3 + o] = s;
  }
}

extern "C" void kernel_launch(void* const* d_in, const int* in_sizes, int n_in,
                              void* d_out, int out_size, void* d_ws, size_t ws_size,
                              hipStream_t stream) {
  const float* inx = (const float*)d_in[0];
  const float* iny = (const float*)d_in[1];
  const float* qxy = (const float*)d_in[2];
  const float* npos = (const float*)d_in[3];
  const float* We1 = (const float*)d_in[4];
  const float* be1 = (const float*)d_in[5];
  const float* We2 = (const float*)d_in[6];
  const float* be2 = (const float*)d_in[7];
  const float* Wg  = (const float*)d_in[8];
  const float* bg  = (const float*)d_in[9];
  const float* lng = (const float*)d_in[10];
  const float* lnb = (const float*)d_in[11];
  const float* Wd1 = (const float*)d_in[12];
  const float* bd1 = (const float*)d_in[13];
  const float* Wd2 = (const float*)d_in[14];
  const float* bd2 = (const float*)d_in[15];
  const int* eidx  = (const int*)d_in[16];
  float* out = (float*)d_out;

  char* w = (char*)d_ws;
  auto carve = [&](size_t n) { char* p = w; w += (n + 255) & ~(size_t)255; return p; };
  char* encR = carve((size_t)2 * BB * NP * FF * 2);                          // 32 MB
  unsigned short* encTh = (unsigned short*)encR;
  unsigned short* encTl = (unsigned short*)(encR + (size_t)BB * NP * FF * 2);
  unsigned short* latTh = encTh;   // alias (dead after proj1)
  unsigned short* latTl = encTl;
  float* xA = (float*)carve((size_t)BB * NN * FF * 4);                       // 8 MB
  float* xB = (float*)carve((size_t)BB * NN * FF * 4);                       // 8 MB
  unsigned short* xTh = (unsigned short*)carve((size_t)BB * NN * FF * 2);    // 4 MB
  unsigned short* xTl = (unsigned short*)carve((size_t)BB * NN * FF * 2);    // 4 MB
  float* part = (float*)carve((size_t)4 * BB * NN * FF * 4);                 // 32 MB
  float* mI   = (float*)carve((size_t)BB * NP * 4);
  float* liI  = (float*)carve((size_t)BB * NP * 4);
  float* mQ   = (float*)carve((size_t)BB * NP * 4);
  float* liQ  = (float*)carve((size_t)BB * NP * 4);
  unsigned short* WTe2h = (unsigned short*)carve((size_t)8 * 256 * 32 * 2);
  unsigned short* WTe2l = (unsigned short*)carve((size_t)8 * 256 * 32 * 2);
  unsigned short* WTgh  = (unsigned short*)carve((size_t)8 * 256 * 32 * 2);
  unsigned short* WTgl  = (unsigned short*)carve((size_t)8 * 256 * 32 * 2);
  unsigned short* WTd1h = (unsigned short*)carve((size_t)8 * 256 * 32 * 2);
  unsigned short* WTd1l = (unsigned short*)carve((size_t)8 * 256 * 32 * 2);
  float* sposW = (float*)carve((size_t)NN * FF * 4);
  float* dinv = (float*)carve(NN * 4);
  float* spos = (float*)carve(NN * 2 * 4);
  float* csw  = (float*)carve((NE + NN) * 4);
  int* coff   = (int*)carve((NN + 1) * 4);
  int* csrc   = (int*)carve((NE + NN) * 4);
  int* cntg   = (int*)carve((size_t)NSEG * NN * 4);

  const int* esrc = eidx;
  const int* edst = eidx + NE;

  k_cnt<<<dim3(NSEG), dim3(1024), 0, stream>>>(edst, cntg);
  k_scan2<<<dim3(1), dim3(1024), 0, stream>>>(cntg, dinv, coff);
  k_fill2<<<dim3(NSEG + 1), dim3(1024), 0, stream>>>(esrc, edst, dinv, coff, cntg, csrc, csw);
  k_spos<<<dim3(4), dim3(256), 0, stream>>>(npos, coff, csrc, csw, spos);
  k_posb<<<dim3(NN), dim3(256), 0, stream>>>(spos, Wg, bg, sposW);
  k_pack_w<<<dim3(8, 3), dim3(256), 0, stream>>>(We2, Wg, Wd1, WTe2h, WTe2l, WTgh, WTgl,
                                                 WTd1h, WTd1l);

  k_stats<<<dim3(BB * NP / 4, 2), dim3(256), 0, stream>>>(inx, qxy, npos, mI, liI, mQ, liQ);
  k_encoder<<<dim3(BB * NP / 32), dim3(256), 0, stream>>>(inx, iny, We1, be1, WTe2h, WTe2l, be2,
                                                          encTh, encTl);
  k_proj1<<<dim3(32, 8, 4), dim3(256), 0, stream>>>(inx, mI, liI, npos, encTh, encTl, part);
  k_reduce<<<dim3(BB * NN * FF / 1024), dim3(256), 0, stream>>>(part, xA);
  for (int s = 0; s < NSTEP; s++) {
    const float* xi = (s & 1) ? xB : xA;
    float* xo = (s & 1) ? xA : xB;
    k_msg2<<<dim3(NN / 32, BB), dim3(256), 0, stream>>>(xi, xo, sposW, coff, csrc, csw,
                                                        WTgh, WTgl, lng, lnb,
                                                        (s == NSTEP - 1) ? 1 : 0, xTh, xTl);
  }
  k_proj2<<<dim3(128, 8), dim3(256), 0, stream>>>(qxy, mQ, liQ, npos, xTh, xTl, latTh, latTl);
  k_decoder<<<dim3(BB * NP / 32), dim3(256), 0, stream>>>(latTh, latTl, qxy, WTd1h, WTd1l,
                                                          bd1, Wd1, Wd2, bd2, out);
}

// Round 6
// 696.554 us; speedup vs baseline: 2.6622x; 1.0996x over previous
//
#include <hip/hip_runtime.h>

#define BB 8
#define NP 4096    // NPTS == NQ
#define NN 1024
#define NE 8192
#define FF 256
#define TS 264
#define NSTEP 16
#define NSEG 64
#define SEGSZ 128  // NSEG*SEGSZ == NE

typedef float f32x4_t __attribute__((ext_vector_type(4)));
typedef __bf16 bf16x8_t __attribute__((ext_vector_type(8)));
typedef unsigned int u32x4_t __attribute__((ext_vector_type(4)));
typedef unsigned int u32x2_t __attribute__((ext_vector_type(2)));

static __device__ __forceinline__ unsigned short f2bf(float f) {
  union { float f; unsigned u; } v; v.f = f;
  unsigned u = v.u + 0x7FFFu + ((v.u >> 16) & 1u);
  return (unsigned short)(u >> 16);
}
static __device__ __forceinline__ float ashf(unsigned short s) {
  union { unsigned u; float f; } t; t.u = (unsigned)s << 16; return t.f;
}
// split a,b into hi/lo bf16 pairs packed as u32
static __device__ __forceinline__ void split_pk(float a, float b, unsigned& h, unsigned& l) {
  unsigned short ha = f2bf(a), hb = f2bf(b);
  unsigned short la = f2bf(a - ashf(ha)), lb = f2bf(b - ashf(hb));
  h = (unsigned)ha | ((unsigned)hb << 16);
  l = (unsigned)la | ((unsigned)lb << 16);
}
static __device__ __forceinline__ f32x4_t mfma16(u32x4_t a, u32x4_t b, f32x4_t c) {
  return __builtin_amdgcn_mfma_f32_16x16x32_bf16(
      __builtin_bit_cast(bf16x8_t, a), __builtin_bit_cast(bf16x8_t, b), c, 0, 0, 0);
}
// 16B-entry XOR swizzle: spreads 64-byte fragment rows over all 32 LDS banks
static __device__ __forceinline__ int swz16(int e) { return e ^ ((e >> 3) & 7); }

// ---------------- graph preprocessing (segmented, deterministic) ----------------
__global__ __launch_bounds__(1024) void k_cnt(const int* __restrict__ dstA,
                                              int* __restrict__ cntg) {
  __shared__ int ds[SEGSZ];
  int seg = blockIdx.x, n = threadIdx.x;
  if (n < SEGSZ) ds[n] = dstA[seg * SEGSZ + n];
  __syncthreads();
  int c = 0;
  #pragma unroll 8
  for (int e = 0; e < SEGSZ; e++) c += (ds[e] == n) ? 1 : 0;
  cntg[seg * NN + n] = c;
}

__global__ __launch_bounds__(1024) void k_scan2(const int* __restrict__ cntg,
    float* __restrict__ dinv, int* __restrict__ csr_off) {
  __shared__ int s[NN];
  int n = threadIdx.x;
  int c = 1;
  for (int sg = 0; sg < NSEG; sg++) c += cntg[sg * NN + n];
  dinv[n] = rsqrtf((float)c);
  s[n] = c;
  __syncthreads();
  for (int st = 1; st < NN; st <<= 1) {
    int v = (n >= st) ? s[n - st] : 0;
    __syncthreads();
    s[n] += v;
    __syncthreads();
  }
  csr_off[n] = s[n] - c;
  if (n == NN - 1) csr_off[NN] = s[n];
}

__global__ __launch_bounds__(1024) void k_fill2(const int* __restrict__ srcA,
    const int* __restrict__ dstA, const float* __restrict__ dinv,
    const int* __restrict__ csr_off, const int* __restrict__ cntg,
    int* __restrict__ csr_src, float* __restrict__ csr_w) {
  int n = threadIdx.x;
  if (blockIdx.x == NSEG) {
    int pos = csr_off[n + 1] - 1;               // self loop last
    csr_src[pos] = n;
    csr_w[pos] = dinv[n] * dinv[n];
    return;
  }
  __shared__ int ds[SEGSZ], ss[SEGSZ];
  int seg = blockIdx.x;
  if (n < SEGSZ) { ds[n] = dstA[seg * SEGSZ + n]; ss[n] = srcA[seg * SEGSZ + n]; }
  __syncthreads();
  int base = csr_off[n];
  for (int s2 = 0; s2 < seg; s2++) base += cntg[s2 * NN + n];
  float dn = dinv[n];
  for (int e = 0; e < SEGSZ; e++) {
    if (ds[e] == n) {
      int sv = ss[e];
      csr_src[base] = sv;
      csr_w[base] = dinv[sv] * dn;
      base++;
    }
  }
}

__global__ __launch_bounds__(256) void k_spos(const float* __restrict__ npos,
    const int* __restrict__ csr_off, const int* __restrict__ csr_src,
    const float* __restrict__ csr_w, float* __restrict__ spos) {
  int n = blockIdx.x * 256 + threadIdx.x;
  if (n >= NN) return;
  float sx = 0.f, sy = 0.f;
  int e1 = csr_off[n + 1];
  for (int e = csr_off[n]; e < e1; e++) {
    float w = csr_w[e]; int s = csr_src[e];
    sx += w * npos[2 * s]; sy += w * npos[2 * s + 1];
  }
  spos[2 * n] = sx; spos[2 * n + 1] = sy;
}

__global__ __launch_bounds__(256) void k_posb(const float* __restrict__ spos,
    const float* __restrict__ Wg, const float* __restrict__ bg, float* __restrict__ sposW) {
  int n = blockIdx.x, f = threadIdx.x;
  sposW[(size_t)n * FF + f] = spos[2 * n] * Wg[f] + spos[2 * n + 1] * Wg[FF + f] + bg[f];
}

// ---------------- softmax stats (inputs and queries in one launch) ----------------
__global__ __launch_bounds__(256) void k_stats(const float* __restrict__ inx,
    const float* __restrict__ qxy, const float* __restrict__ npos,
    float* __restrict__ mI, float* __restrict__ liI,
    float* __restrict__ mQ, float* __restrict__ liQ) {
  const float* xy = blockIdx.y ? qxy : inx;
  float* mOut = blockIdx.y ? mQ : mI;
  float* liOut = blockIdx.y ? liQ : liI;
  int wv = threadIdx.x >> 6, lane = threadIdx.x & 63;
  int pt = blockIdx.x * 4 + wv;
  float px = xy[pt * 2], py = xy[pt * 2 + 1];
  float s[16];
  float m = -1e30f;
  #pragma unroll
  for (int k = 0; k < 16; k++) {
    int n = lane + 64 * k;
    float2 np = ((const float2*)npos)[n];
    float dx = px - np.x, dy = py - np.y;
    float v = -(dx * dx + dy * dy);
    s[k] = v; m = fmaxf(m, v);
  }
  #pragma unroll
  for (int o = 32; o; o >>= 1) m = fmaxf(m, __shfl_xor(m, o));
  float l = 0.f;
  #pragma unroll
  for (int k = 0; k < 16; k++) l += __expf(s[k] - m);
  #pragma unroll
  for (int o = 32; o; o >>= 1) l += __shfl_xor(l, o);
  if (lane == 0) { mOut[pt] = m; liOut[pt] = 1.0f / l; }
}

// ---------------- weight prepack: WT[kc][n][kk] bf16 hi+lo ----------------
__global__ __launch_bounds__(256) void k_pack_w(const float* __restrict__ We2,
    const float* __restrict__ Wg, const float* __restrict__ Wd1,
    unsigned short* __restrict__ WTe2h, unsigned short* __restrict__ WTe2l,
    unsigned short* __restrict__ WTgh, unsigned short* __restrict__ WTgl,
    unsigned short* __restrict__ WTd1h, unsigned short* __restrict__ WTd1l) {
  int kc = blockIdx.x, which = blockIdx.y, n = threadIdx.x;
  const float* W = (which == 0) ? We2 : (which == 1) ? (Wg + 2 * FF) : Wd1;
  unsigned short* Dh = (which == 0) ? WTe2h : (which == 1) ? WTgh : WTd1h;
  unsigned short* Dl = (which == 0) ? WTe2l : (which == 1) ? WTgl : WTd1l;
  unsigned hu[16], lu[16];
  #pragma unroll
  for (int i = 0; i < 16; i++) {
    float a = W[(kc * 32 + 2 * i) * FF + n];
    float b = W[(kc * 32 + 2 * i + 1) * FF + n];
    split_pk(a, b, hu[i], lu[i]);
  }
  u32x4_t* dvh = (u32x4_t*)(Dh + ((size_t)kc * 256 + n) * 32);
  u32x4_t* dvl = (u32x4_t*)(Dl + ((size_t)kc * 256 + n) * 32);
  #pragma unroll
  for (int i = 0; i < 4; i++) {
    u32x4_t th = {hu[4 * i], hu[4 * i + 1], hu[4 * i + 2], hu[4 * i + 3]};
    u32x4_t tl = {lu[4 * i], lu[4 * i + 1], lu[4 * i + 2], lu[4 * i + 3]};
    dvh[i] = th; dvl[i] = tl;
  }
}

// ---------------- encoder: L1 fp32 VALU, L2 split-MFMA; writes encT hi+lo ----------------
__global__ __launch_bounds__(256) void k_encoder(const float* __restrict__ inx,
    const float* __restrict__ iny, const float* __restrict__ We1,
    const float* __restrict__ be1, const unsigned short* __restrict__ WTe2h,
    const unsigned short* __restrict__ WTe2l, const float* __restrict__ be2,
    unsigned short* __restrict__ encTh, unsigned short* __restrict__ encTl) {
  __shared__ float xin[32][8];
  __shared__ float h[32][TS];
  __shared__ unsigned short Bh[8192];
  __shared__ unsigned short Bl[8192];
  int tid = threadIdx.x;
  int row0 = blockIdx.x * 32;
  int wv = tid >> 6, L = tid & 63, lhi = L >> 4, llo = L & 15;

  if (tid < 160) {
    int pt = tid / 5, d = tid % 5;
    int r = row0 + pt;
    xin[pt][d] = (d < 2) ? inx[r * 2 + d] : iny[r * 3 + (d - 2)];
  }
  __syncthreads();
  {
    int f = tid;
    float w0 = We1[f], w1 = We1[256 + f], w2 = We1[512 + f], w3 = We1[768 + f], w4 = We1[1024 + f];
    float bb = be1[f];
    #pragma unroll 4
    for (int pt = 0; pt < 32; pt++) {
      float v = bb + xin[pt][0]*w0 + xin[pt][1]*w1 + xin[pt][2]*w2 + xin[pt][3]*w3 + xin[pt][4]*w4;
      h[pt][f] = fmaxf(v, 0.f);
    }
  }

  f32x4_t acc[2][4];
  #pragma unroll
  for (int cb = 0; cb < 4; cb++) {
    float bc = be2[wv * 64 + cb * 16 + llo];
    f32x4_t t = {bc, bc, bc, bc};
    acc[0][cb] = t; acc[1][cb] = t;
  }

  for (int kc = 0; kc < 8; kc++) {
    __syncthreads();
    {
      const u32x4_t* sh = (const u32x4_t*)(WTe2h + (size_t)kc * 8192);
      const u32x4_t* sl = (const u32x4_t*)(WTe2l + (size_t)kc * 8192);
      u32x4_t* dh = (u32x4_t*)Bh;
      u32x4_t* dl = (u32x4_t*)Bl;
      #pragma unroll
      for (int i = 0; i < 4; i++) {
        int e = tid + i * 256;
        int es = swz16(e);
        dh[es] = sh[e]; dl[es] = sl[e];
      }
    }
    __syncthreads();
    int kbase = kc * 32 + lhi * 8;
    u32x4_t a0h, a0l, a1h, a1l;
    {
      float p[8];
      *(f32x4_t*)p = *(const f32x4_t*)&h[llo][kbase];
      *(f32x4_t*)(p + 4) = *(const f32x4_t*)&h[llo][kbase + 4];
      unsigned hw[4], lw[4];
      #pragma unroll
      for (int i = 0; i < 4; i++) split_pk(p[2 * i], p[2 * i + 1], hw[i], lw[i]);
      u32x4_t th = {hw[0], hw[1], hw[2], hw[3]}; a0h = th;
      u32x4_t tl = {lw[0], lw[1], lw[2], lw[3]}; a0l = tl;
    }
    {
      float p[8];
      *(f32x4_t*)p = *(const f32x4_t*)&h[llo + 16][kbase];
      *(f32x4_t*)(p + 4) = *(const f32x4_t*)&h[llo + 16][kbase + 4];
      unsigned hw[4], lw[4];
      #pragma unroll
      for (int i = 0; i < 4; i++) split_pk(p[2 * i], p[2 * i + 1], hw[i], lw[i]);
      u32x4_t th = {hw[0], hw[1], hw[2], hw[3]}; a1h = th;
      u32x4_t tl = {lw[0], lw[1], lw[2], lw[3]}; a1l = tl;
    }
    #pragma unroll
    for (int cb = 0; cb < 4; cb++) {
      int col = wv * 64 + cb * 16 + llo;
      int off = swz16(col * 4 + lhi) * 8;
      u32x4_t bh = *(const u32x4_t*)&Bh[off];
      u32x4_t bl = *(const u32x4_t*)&Bl[off];
      acc[0][cb] = mfma16(a0h, bh, mfma16(a0h, bl, mfma16(a0l, bh, acc[0][cb])));
      acc[1][cb] = mfma16(a1h, bh, mfma16(a1h, bl, mfma16(a1l, bh, acc[1][cb])));
    }
  }
  #pragma unroll
  for (int rb = 0; rb < 2; rb++)
    #pragma unroll
    for (int cb = 0; cb < 4; cb++) {
      int col = wv * 64 + cb * 16 + llo;
      f32x4_t v = acc[rb][cb];
      size_t idx = ((size_t)blockIdx.x * 256 + col) * 32 + rb * 16 + lhi * 4;
      unsigned hw0, lw0, hw1, lw1;
      split_pk(v[0], v[1], hw0, lw0);
      split_pk(v[2], v[3], hw1, lw1);
      u32x2_t wh = {hw0, hw1}; *(u32x2_t*)&encTh[idx] = wh;
      u32x2_t wl = {lw0, lw1}; *(u32x2_t*)&encTl[idx] = wl;
    }
}

// ---------------- proj1 (split-K, 3-term split MFMA): part[z][b][n][f] ----------------
__global__ __launch_bounds__(256) void k_proj1(const float* __restrict__ inx,
    const float* __restrict__ mI, const float* __restrict__ liI,
    const float* __restrict__ npos, const unsigned short* __restrict__ encTh,
    const unsigned short* __restrict__ encTl, float* __restrict__ part) {
  __shared__ unsigned short BstH[2][8192];
  __shared__ unsigned short BstL[2][8192];
  __shared__ unsigned short AstH[2][1024];
  __shared__ unsigned short AstL[2][1024];
  int tid = threadIdx.x;
  // XCD-aware decode: each XCD owns 4 (b,z)-slices; 32 n-blocks per slice stay local
  int id = blockIdx.x;
  int xcd = id & 7, kid = id >> 3;
  int slice = xcd * 4 + (kid >> 5);
  int n0 = (kid & 31) * 32;
  int b = slice >> 2, z = slice & 3;
  int wv = tid >> 6, L = tid & 63, lhi = L >> 4, llo = L & 15;
  int an = tid >> 3, t7 = tid & 7, ap = t7 * 4;
  float2 npv = ((const float2*)npos)[n0 + an];
  int pbase0 = b * NP + z * 1024;
  int aoff = swz16(an * 4 + (t7 >> 1)) * 8 + (t7 & 1) * 4;

  auto stageA = [&](int kc, int buf) {
    int p = pbase0 + kc * 32 + ap;
    float c[4];
    #pragma unroll
    for (int j = 0; j < 4; j++) {
      float2 pxy = ((const float2*)inx)[p + j];
      float mm = mI[p + j], ll = liI[p + j];
      float dx = pxy.x - npv.x, dy = pxy.y - npv.y;
      c[j] = __expf(-(dx * dx + dy * dy) - mm) * ll;
    }
    unsigned hw0, lw0, hw1, lw1;
    split_pk(c[0], c[1], hw0, lw0);
    split_pk(c[2], c[3], hw1, lw1);
    u32x2_t wh = {hw0, hw1}; *(u32x2_t*)&AstH[buf][aoff] = wh;
    u32x2_t wl = {lw0, lw1}; *(u32x2_t*)&AstL[buf][aoff] = wl;
  };
  auto stageB = [&](int kc, int buf) {
    const u32x4_t* sh = (const u32x4_t*)(encTh + (size_t)(b * 128 + z * 32 + kc) * 8192);
    const u32x4_t* sl = (const u32x4_t*)(encTl + (size_t)(b * 128 + z * 32 + kc) * 8192);
    u32x4_t* dh = (u32x4_t*)BstH[buf];
    u32x4_t* dl = (u32x4_t*)BstL[buf];
    #pragma unroll
    for (int i = 0; i < 4; i++) {
      int e = tid + i * 256;
      int es = swz16(e);
      dh[es] = sh[e]; dl[es] = sl[e];
    }
  };

  f32x4_t acc[2][4];
  #pragma unroll
  for (int i = 0; i < 2; i++)
    #pragma unroll
    for (int j = 0; j < 4; j++) { f32x4_t t = {0.f, 0.f, 0.f, 0.f}; acc[i][j] = t; }

  stageA(0, 0); stageB(0, 0);
  __syncthreads();
  int a0off = swz16(llo * 4 + lhi) * 8;
  int a1off = swz16((llo + 16) * 4 + lhi) * 8;
  for (int kc = 0; kc < 32; kc++) {
    int cur = kc & 1;
    if (kc < 31) { stageA(kc + 1, cur ^ 1); stageB(kc + 1, cur ^ 1); }
    u32x4_t a0h = *(const u32x4_t*)&AstH[cur][a0off];
    u32x4_t a0l = *(const u32x4_t*)&AstL[cur][a0off];
    u32x4_t a1h = *(const u32x4_t*)&AstH[cur][a1off];
    u32x4_t a1l = *(const u32x4_t*)&AstL[cur][a1off];
    #pragma unroll
    for (int cb = 0; cb < 4; cb++) {
      int off = swz16((wv * 64 + cb * 16 + llo) * 4 + lhi) * 8;
      u32x4_t bh = *(const u32x4_t*)&BstH[cur][off];
      u32x4_t bl = *(const u32x4_t*)&BstL[cur][off];
      acc[0][cb] = mfma16(a0h, bh, mfma16(a0h, bl, mfma16(a0l, bh, acc[0][cb])));
      acc[1][cb] = mfma16(a1h, bh, mfma16(a1h, bl, mfma16(a1l, bh, acc[1][cb])));
    }
    __syncthreads();
  }
  float* op = part + (((size_t)(z * BB + b)) * NN + n0) * FF;
  #pragma unroll
  for (int rb = 0; rb < 2; rb++)
    #pragma unroll
    for (int cb = 0; cb < 4; cb++) {
      int col = wv * 64 + cb * 16 + llo;
      f32x4_t v = acc[rb][cb];
      #pragma unroll
      for (int r = 0; r < 4; r++) op[(rb * 16 + lhi * 4 + r) * FF + col] = v[r];
    }
}

// reduce split-K parts -> x (fp32)
__global__ __launch_bounds__(256) void k_reduce(const float* __restrict__ part,
                                                float* __restrict__ x) {
  size_t i = ((size_t)blockIdx.x * 256 + threadIdx.x) * 4;
  const size_t S = (size_t)BB * NN * FF;
  f32x4_t a = *(const f32x4_t*)&part[i];
  f32x4_t b = *(const f32x4_t*)&part[S + i];
  f32x4_t c = *(const f32x4_t*)&part[2 * S + i];
  f32x4_t d = *(const f32x4_t*)&part[3 * S + i];
  f32x4_t r = (a + b) + (c + d);
  *(f32x4_t*)&x[i] = r;
}

// ---------------- fused msg step: gather -> LDS, split MFMA, LN ----------------
__global__ __launch_bounds__(256) void k_msg2(const float* __restrict__ x_in,
    float* __restrict__ x_out, const float* __restrict__ sposW,
    const int* __restrict__ coff, const int* __restrict__ csrc,
    const float* __restrict__ csw, const unsigned short* __restrict__ WTgh,
    const unsigned short* __restrict__ WTgl, const float* __restrict__ lng,
    const float* __restrict__ lnb, int last,
    unsigned short* __restrict__ xTh, unsigned short* __restrict__ xTl) {
  __shared__ unsigned Ah[32][132];
  __shared__ unsigned Al[32][132];
  __shared__ unsigned short Bh[8192];
  __shared__ unsigned short Bl[8192];
  __shared__ float redS[32][4];
  __shared__ float redQ[32][4];
  int tid = threadIdx.x;
  // XCD-aware: batch b pinned to one XCD so x_in(b) stays in its L2
  int id = blockIdx.x;
  int b = id & 7;
  int nb = id >> 3;
  int n0 = nb * 32;
  int wv = tid >> 6, L = tid & 63, lhi = L >> 4, llo = L & 15;

  // gather phase: 8 threads per row, 32 features each; same edge order as before
  {
    int row = tid >> 3, seg = tid & 7;
    int n = n0 + row;
    float g[32];
    #pragma unroll
    for (int i = 0; i < 32; i++) g[i] = 0.f;
    int e0 = coff[n], e1 = coff[n + 1];
    for (int e = e0; e < e1; e++) {
      float w = csw[e];
      int s = csrc[e];
      const f32x4_t* px = (const f32x4_t*)(x_in + ((size_t)b * NN + s) * FF + seg * 32);
      #pragma unroll
      for (int i = 0; i < 8; i++) {
        f32x4_t v = px[i];
        g[4*i]   += w * v[0]; g[4*i+1] += w * v[1];
        g[4*i+2] += w * v[2]; g[4*i+3] += w * v[3];
      }
    }
    #pragma unroll
    for (int i = 0; i < 16; i++) {
      unsigned h, l;
      split_pk(g[2 * i], g[2 * i + 1], h, l);
      Ah[row][seg * 16 + i] = h;
      Al[row][seg * 16 + i] = l;
    }
  }

  f32x4_t acc[2][4];
  #pragma unroll
  for (int i = 0; i < 2; i++)
    #pragma unroll
    for (int j = 0; j < 4; j++) { f32x4_t t = {0.f, 0.f, 0.f, 0.f}; acc[i][j] = t; }

  for (int kc = 0; kc < 8; kc++) {
    __syncthreads();
    {
      const u32x4_t* sh = (const u32x4_t*)(WTgh + (size_t)kc * 8192);
      const u32x4_t* sl = (const u32x4_t*)(WTgl + (size_t)kc * 8192);
      u32x4_t* dh = (u32x4_t*)Bh;
      u32x4_t* dl = (u32x4_t*)Bl;
      #pragma unroll
      for (int i = 0; i < 4; i++) {
        int e = tid + i * 256;
        int es = swz16(e);
        dh[es] = sh[e]; dl[es] = sl[e];
      }
    }
    __syncthreads();
    u32x4_t a0h = *(const u32x4_t*)&Ah[llo][kc * 16 + lhi * 4];
    u32x4_t a0l = *(const u32x4_t*)&Al[llo][kc * 16 + lhi * 4];
    u32x4_t a1h = *(const u32x4_t*)&Ah[llo + 16][kc * 16 + lhi * 4];
    u32x4_t a1l = *(const u32x4_t*)&Al[llo + 16][kc * 16 + lhi * 4];
    #pragma unroll
    for (int cb = 0; cb < 4; cb++) {
      int off = swz16((wv * 64 + cb * 16 + llo) * 4 + lhi) * 8;
      u32x4_t bh = *(const u32x4_t*)&Bh[off];
      u32x4_t bl = *(const u32x4_t*)&Bl[off];
      acc[0][cb] = mfma16(a0h, bh, mfma16(a0h, bl, mfma16(a0l, bh, acc[0][cb])));
      acc[1][cb] = mfma16(a1h, bh, mfma16(a1h, bl, mfma16(a1l, bh, acc[1][cb])));
    }
  }

  // epilogue: + sposW + residual, then LayerNorm
  #pragma unroll
  for (int rb = 0; rb < 2; rb++)
    #pragma unroll
    for (int cb = 0; cb < 4; cb++) {
      int col = wv * 64 + cb * 16 + llo;
      #pragma unroll
      for (int r = 0; r < 4; r++) {
        int row = rb * 16 + lhi * 4 + r;
        float sw = sposW[(size_t)(n0 + row) * FF + col];
        float xr = x_in[((size_t)b * NN + n0 + row) * FF + col];
        acc[rb][cb][r] += sw + xr;
      }
    }
  float ps[2][4], pq[2][4];
  #pragma unroll
  for (int rb = 0; rb < 2; rb++)
    #pragma unroll
    for (int r = 0; r < 4; r++) {
      float s = 0.f, q = 0.f;
      #pragma unroll
      for (int cb = 0; cb < 4; cb++) { float y = acc[rb][cb][r]; s += y; q += y * y; }
      #pragma unroll
      for (int m = 1; m < 16; m <<= 1) { s += __shfl_xor(s, m); q += __shfl_xor(q, m); }
      ps[rb][r] = s; pq[rb][r] = q;
    }
  if (llo == 0) {
    #pragma unroll
    for (int rb = 0; rb < 2; rb++)
      #pragma unroll
      for (int r = 0; r < 4; r++) {
        int row = rb * 16 + lhi * 4 + r;
        redS[row][wv] = ps[rb][r];
        redQ[row][wv] = pq[rb][r];
      }
  }
  __syncthreads();
  float mrs[2][4][2];
  #pragma unroll
  for (int rb = 0; rb < 2; rb++)
    #pragma unroll
    for (int r = 0; r < 4; r++) {
      int row = rb * 16 + lhi * 4 + r;
      float S = redS[row][0] + redS[row][1] + redS[row][2] + redS[row][3];
      float Q = redQ[row][0] + redQ[row][1] + redQ[row][2] + redQ[row][3];
      float mean = S * (1.f / 256.f);
      float var = Q * (1.f / 256.f) - mean * mean;
      mrs[rb][r][0] = mean;
      mrs[rb][r][1] = rsqrtf(var + 1e-5f);
    }
  #pragma unroll
  for (int cb = 0; cb < 4; cb++) {
    int col = wv * 64 + cb * 16 + llo;
    float gg = lng[col], bb = lnb[col];
    #pragma unroll
    for (int rb = 0; rb < 2; rb++)
      #pragma unroll
      for (int r = 0; r < 4; r++) {
        int row = rb * 16 + lhi * 4 + r;
        float o = (acc[rb][cb][r] - mrs[rb][r][0]) * mrs[rb][r][1] * gg + bb;
        if (!last) {
          x_out[((size_t)b * NN + n0 + row) * FF + col] = o;
        } else {
          size_t idx = (((size_t)b * 32 + nb) * 256 + col) * 32 + row;
          unsigned short hh = f2bf(o);
          xTh[idx] = hh;
          xTl[idx] = f2bf(o - ashf(hh));
        }
      }
  }
}

// ---------------- proj2 (3-term split MFMA): latT hi+lo [bt][fc][row][kk] ----------------
__global__ __launch_bounds__(256) void k_proj2(const float* __restrict__ qxy,
    const float* __restrict__ mQ, const float* __restrict__ liQ,
    const float* __restrict__ npos, const unsigned short* __restrict__ xTh,
    const unsigned short* __restrict__ xTl, unsigned short* __restrict__ latTh,
    unsigned short* __restrict__ latTl) {
  __shared__ unsigned short BstH[2][8192];
  __shared__ unsigned short BstL[2][8192];
  __shared__ unsigned short AstH[2][1024];
  __shared__ unsigned short AstL[2][1024];
  __shared__ float nps[NN * 2];
  int tid = threadIdx.x;
  // XCD-aware: batch b pinned to one XCD so xT(b) stays in its L2
  int id = blockIdx.x;
  int b = id & 7;
  int q0b = id >> 3;             // 0..127
  int q0 = q0b * 32;
  int bt = b * 128 + q0b;
  int wv = tid >> 6, L = tid & 63, lhi = L >> 4, llo = L & 15;
  int aq = tid >> 3, t7 = tid & 7, an4 = t7 * 4;
  int aoff = swz16(aq * 4 + (t7 >> 1)) * 8 + (t7 & 1) * 4;

  {
    const f32x4_t* s4 = (const f32x4_t*)npos;
    *(f32x4_t*)&nps[tid * 4] = s4[tid];
    *(f32x4_t*)&nps[(tid + 256) * 4] = s4[tid + 256];
  }
  int qg = b * NP + q0 + aq;
  float2 qv = ((const float2*)qxy)[qg];
  float qm = mQ[qg], qli = liQ[qg];
  __syncthreads();

  auto stageA = [&](int kc, int buf) {
    int nb = kc * 32 + an4;
    float c[4];
    #pragma unroll
    for (int j = 0; j < 4; j++) {
      float nx = nps[(nb + j) * 2], ny = nps[(nb + j) * 2 + 1];
      float dx = qv.x - nx, dy = qv.y - ny;
      c[j] = __expf(-(dx * dx + dy * dy) - qm) * qli;
    }
    unsigned hw0, lw0, hw1, lw1;
    split_pk(c[0], c[1], hw0, lw0);
    split_pk(c[2], c[3], hw1, lw1);
    u32x2_t wh = {hw0, hw1}; *(u32x2_t*)&AstH[buf][aoff] = wh;
    u32x2_t wl = {lw0, lw1}; *(u32x2_t*)&AstL[buf][aoff] = wl;
  };
  auto stageB = [&](int kc, int buf) {
    const u32x4_t* sh = (const u32x4_t*)(xTh + (size_t)(b * 32 + kc) * 8192);
    const u32x4_t* sl = (const u32x4_t*)(xTl + (size_t)(b * 32 + kc) * 8192);
    u32x4_t* dh = (u32x4_t*)BstH[buf];
    u32x4_t* dl = (u32x4_t*)BstL[buf];
    #pragma unroll
    for (int i = 0; i < 4; i++) {
      int e = tid + i * 256;
      int es = swz16(e);
      dh[es] = sh[e]; dl[es] = sl[e];
    }
  };

  f32x4_t acc[2][4];
  #pragma unroll
  for (int i = 0; i < 2; i++)
    #pragma unroll
    for (int j = 0; j < 4; j++) { f32x4_t t = {0.f, 0.f, 0.f, 0.f}; acc[i][j] = t; }

  stageA(0, 0); stageB(0, 0);
  __syncthreads();
  int a0off = swz16(llo * 4 + lhi) * 8;
  int a1off = swz16((llo + 16) * 4 + lhi) * 8;
  for (int kc = 0; kc < 32; kc++) {
    int cur = kc & 1;
    if (kc < 31) { stageA(kc + 1, cur ^ 1); stageB(kc + 1, cur ^ 1); }
    u32x4_t a0h = *(const u32x4_t*)&AstH[cur][a0off];
    u32x4_t a0l = *(const u32x4_t*)&AstL[cur][a0off];
    u32x4_t a1h = *(const u32x4_t*)&AstH[cur][a1off];
    u32x4_t a1l = *(const u32x4_t*)&AstL[cur][a1off];
    #pragma unroll
    for (int cb = 0; cb < 4; cb++) {
      int off = swz16((wv * 64 + cb * 16 + llo) * 4 + lhi) * 8;
      u32x4_t bh = *(const u32x4_t*)&BstH[cur][off];
      u32x4_t bl = *(const u32x4_t*)&BstL[cur][off];
      acc[0][cb] = mfma16(a0h, bh, mfma16(a0h, bl, mfma16(a0l, bh, acc[0][cb])));
      acc[1][cb] = mfma16(a1h, bh, mfma16(a1h, bl, mfma16(a1l, bh, acc[1][cb])));
    }
    __syncthreads();
  }
  #pragma unroll
  for (int rb = 0; rb < 2; rb++)
    #pragma unroll
    for (int cb = 0; cb < 4; cb++) {
      int col = wv * 64 + cb * 16 + llo;
      int fc = col >> 5, kk = col & 31;
      f32x4_t v = acc[rb][cb];
      #pragma unroll
      for (int r = 0; r < 4; r++) {
        size_t idx = ((size_t)bt * 8 + fc) * 1024 + (rb * 16 + lhi * 4 + r) * 32 + kk;
        unsigned short hh = f2bf(v[r]);
        latTh[idx] = hh;
        latTl[idx] = f2bf(v[r] - ashf(hh));
      }
    }
}

// ---------------- decoder (3-term split MFMA + fused second GEMM) ----------------
__global__ __launch_bounds__(256) void k_decoder(const unsigned short* __restrict__ latTh,
    const unsigned short* __restrict__ latTl, const float* __restrict__ qxy,
    const unsigned short* __restrict__ WTd1h, const unsigned short* __restrict__ WTd1l,
    const float* __restrict__ bd1, const float* __restrict__ Wd1,
    const float* __restrict__ Wd2, const float* __restrict__ bd2, float* __restrict__ out) {
  __shared__ unsigned short BstH[2][8192];
  __shared__ unsigned short BstL[2][8192];
  __shared__ unsigned short AstH[2][1024];
  __shared__ unsigned short AstL[2][1024];
  __shared__ float qs[32][2];
  __shared__ float red[4][32][3];
  int tid = threadIdx.x;
  int bt = blockIdx.x;
  int wv = tid >> 6, L = tid & 63, lhi = L >> 4, llo = L & 15;

  auto stageA = [&](int kc, int buf) {
    if (tid < 128)
      ((u32x4_t*)AstH[buf])[swz16(tid)] = ((const u32x4_t*)(latTh + ((size_t)bt * 8 + kc) * 1024))[tid];
    else
      ((u32x4_t*)AstL[buf])[swz16(tid - 128)] = ((const u32x4_t*)(latTl + ((size_t)bt * 8 + kc) * 1024))[tid - 128];
  };
  auto stageB = [&](int kc, int buf) {
    const u32x4_t* sh = (const u32x4_t*)(WTd1h + (size_t)kc * 8192);
    const u32x4_t* sl = (const u32x4_t*)(WTd1l + (size_t)kc * 8192);
    u32x4_t* dh = (u32x4_t*)BstH[buf];
    u32x4_t* dl = (u32x4_t*)BstL[buf];
    #pragma unroll
    for (int i = 0; i < 4; i++) {
      int e = tid + i * 256;
      int es = swz16(e);
      dh[es] = sh[e]; dl[es] = sl[e];
    }
  };

  if (tid < 64) qs[tid >> 1][tid & 1] = qxy[((size_t)bt * 32 + (tid >> 1)) * 2 + (tid & 1)];
  stageA(0, 0); stageB(0, 0);
  __syncthreads();

  f32x4_t acc[2][4];
  #pragma unroll
  for (int cb = 0; cb < 4; cb++) {
    int col = wv * 64 + cb * 16 + llo;
    float wa = Wd1[256 * FF + col], wb = Wd1[257 * FF + col], bc = bd1[col];
    #pragma unroll
    for (int rb = 0; rb < 2; rb++) {
      f32x4_t t;
      #pragma unroll
      for (int r = 0; r < 4; r++) {
        int row = rb * 16 + lhi * 4 + r;
        t[r] = bc + qs[row][0] * wa + qs[row][1] * wb;
      }
      acc[rb][cb] = t;
    }
  }

  int a0off = swz16(llo * 4 + lhi) * 8;
  int a1off = swz16((llo + 16) * 4 + lhi) * 8;
  for (int kc = 0; kc < 8; kc++) {
    int cur = kc & 1;
    if (kc < 7) { stageA(kc + 1, cur ^ 1); stageB(kc + 1, cur ^ 1); }
    u32x4_t a0h = *(const u32x4_t*)&AstH[cur][a0off];
    u32x4_t a0l = *(const u32x4_t*)&AstL[cur][a0off];
    u32x4_t a1h = *(const u32x4_t*)&AstH[cur][a1off];
    u32x4_t a1l = *(const u32x4_t*)&AstL[cur][a1off];
    #pragma unroll
    for (int cb = 0; cb < 4; cb++) {
      int off = swz16((wv * 64 + cb * 16 + llo) * 4 + lhi) * 8;
      u32x4_t bh = *(const u32x4_t*)&BstH[cur][off];
      u32x4_t bl = *(const u32x4_t*)&BstL[cur][off];
      acc[0][cb] = mfma16(a0h, bh, mfma16(a0h, bl, mfma16(a0l, bh, acc[0][cb])));
      acc[1][cb] = mfma16(a1h, bh, mfma16(a1h, bl, mfma16(a1l, bh, acc[1][cb])));
    }
    __syncthreads();
  }

  float po[2][4][3];
  #pragma unroll
  for (int rb = 0; rb < 2; rb++)
    #pragma unroll
    for (int r = 0; r < 4; r++) { po[rb][r][0] = 0.f; po[rb][r][1] = 0.f; po[rb][r][2] = 0.f; }
  #pragma unroll
  for (int rb = 0; rb < 2; rb++)
    #pragma unroll
    for (int cb = 0; cb < 4; cb++) {
      int col = wv * 64 + cb * 16 + llo;
      float w0 = Wd2[col * 3], w1 = Wd2[col * 3 + 1], w2 = Wd2[col * 3 + 2];
      f32x4_t v = acc[rb][cb];
      #pragma unroll
      for (int r = 0; r < 4; r++) {
        float hv = fmaxf(v[r], 0.f);
        po[rb][r][0] += hv * w0; po[rb][r][1] += hv * w1; po[rb][r][2] += hv * w2;
      }
    }
  #pragma unroll
  for (int o = 8; o; o >>= 1)
    #pragma unroll
    for (int rb = 0; rb < 2; rb++)
      #pragma unroll
      for (int r = 0; r < 4; r++) {
        po[rb][r][0] += __shfl_xor(po[rb][r][0], o);
        po[rb][r][1] += __shfl_xor(po[rb][r][1], o);
        po[rb][r][2] += __shfl_xor(po[rb][r][2], o);
      }
  if (llo == 0) {
    #pragma unroll
    for (int rb = 0; rb < 2; rb++)
      #pragma unroll
      for (int r = 0; r < 4; r++) {
        int row = rb * 16 + lhi * 4 + r;
        red[wv][row][0] = po[rb][r][0];
        red[wv][row][1] = po[rb][r][1];
        red[wv][row][2] = po[rb][r][2];
      }
  }
  __syncthreads();
  if (tid < 96) {
    int row = tid / 3, o = tid % 3;
    float s = red[0][row][o] + red[1][row][o] + red[2][row][o] + red[3][row][o] + bd2[o];
    out[((size_t)bt * 32 + row) * 3 + o] = s;
  }
}

extern "C" void kernel_launch(void* const* d_in, const int* in_sizes, int n_in,
                              void* d_out, int out_size, void* d_ws, size_t ws_size,
                              hipStream_t stream) {
  const float* inx = (const float*)d_in[0];
  const float* iny = (const float*)d_in[1];
  const float* qxy = (const float*)d_in[2];
  const float* npos = (const float*)d_in[3];
  const float* We1 = (const float*)d_in[4];
  const float* be1 = (const float*)d_in[5];
  const float* We2 = (const float*)d_in[6];
  const float* be2 = (const float*)d_in[7];
  const float* Wg  = (const float*)d_in[8];
  const float* bg  = (const float*)d_in[9];
  const float* lng = (const float*)d_in[10];
  const float* lnb = (const float*)d_in[11];
  const float* Wd1 = (const float*)d_in[12];
  const float* bd1 = (const float*)d_in[13];
  const float* Wd2 = (const float*)d_in[14];
  const float* bd2 = (const float*)d_in[15];
  const int* eidx  = (const int*)d_in[16];
  float* out = (float*)d_out;

  char* w = (char*)d_ws;
  auto carve = [&](size_t n) { char* p = w; w += (n + 255) & ~(size_t)255; return p; };
  char* encR = carve((size_t)2 * BB * NP * FF * 2);                          // 32 MB
  unsigned short* encTh = (unsigned short*)encR;
  unsigned short* encTl = (unsigned short*)(encR + (size_t)BB * NP * FF * 2);
  unsigned short* latTh = encTh;   // alias (dead after proj1)
  unsigned short* latTl = encTl;
  float* xA = (float*)carve((size_t)BB * NN * FF * 4);                       // 8 MB
  float* xB = (float*)carve((size_t)BB * NN * FF * 4);                       // 8 MB
  unsigned short* xTh = (unsigned short*)carve((size_t)BB * NN * FF * 2);    // 4 MB
  unsigned short* xTl = (unsigned short*)carve((size_t)BB * NN * FF * 2);    // 4 MB
  float* part = (float*)carve((size_t)4 * BB * NN * FF * 4);                 // 32 MB
  float* mI   = (float*)carve((size_t)BB * NP * 4);
  float* liI  = (float*)carve((size_t)BB * NP * 4);
  float* mQ   = (float*)carve((size_t)BB * NP * 4);
  float* liQ  = (float*)carve((size_t)BB * NP * 4);
  unsigned short* WTe2h = (unsigned short*)carve((size_t)8 * 256 * 32 * 2);
  unsigned short* WTe2l = (unsigned short*)carve((size_t)8 * 256 * 32 * 2);
  unsigned short* WTgh  = (unsigned short*)carve((size_t)8 * 256 * 32 * 2);
  unsigned short* WTgl  = (unsigned short*)carve((size_t)8 * 256 * 32 * 2);
  unsigned short* WTd1h = (unsigned short*)carve((size_t)8 * 256 * 32 * 2);
  unsigned short* WTd1l = (unsigned short*)carve((size_t)8 * 256 * 32 * 2);
  float* sposW = (float*)carve((size_t)NN * FF * 4);
  float* dinv = (float*)carve(NN * 4);
  float* spos = (float*)carve(NN * 2 * 4);
  float* csw  = (float*)carve((NE + NN) * 4);
  int* coff   = (int*)carve((NN + 1) * 4);
  int* csrc   = (int*)carve((NE + NN) * 4);
  int* cntg   = (int*)carve((size_t)NSEG * NN * 4);

  const int* esrc = eidx;
  const int* edst = eidx + NE;

  k_cnt<<<dim3(NSEG), dim3(1024), 0, stream>>>(edst, cntg);
  k_scan2<<<dim3(1), dim3(1024), 0, stream>>>(cntg, dinv, coff);
  k_fill2<<<dim3(NSEG + 1), dim3(1024), 0, stream>>>(esrc, edst, dinv, coff, cntg, csrc, csw);
  k_spos<<<dim3(4), dim3(256), 0, stream>>>(npos, coff, csrc, csw, spos);
  k_posb<<<dim3(NN), dim3(256), 0, stream>>>(spos, Wg, bg, sposW);
  k_pack_w<<<dim3(8, 3), dim3(256), 0, stream>>>(We2, Wg, Wd1, WTe2h, WTe2l, WTgh, WTgl,
                                                 WTd1h, WTd1l);

  k_stats<<<dim3(BB * NP / 4, 2), dim3(256), 0, stream>>>(inx, qxy, npos, mI, liI, mQ, liQ);
  k_encoder<<<dim3(BB * NP / 32), dim3(256), 0, stream>>>(inx, iny, We1, be1, WTe2h, WTe2l, be2,
                                                          encTh, encTl);
  k_proj1<<<dim3(1024), dim3(256), 0, stream>>>(inx, mI, liI, npos, encTh, encTl, part);
  k_reduce<<<dim3(BB * NN * FF / 1024), dim3(256), 0, stream>>>(part, xA);
  for (int s = 0; s < NSTEP; s++) {
    const float* xi = (s & 1) ? xB : xA;
    float* xo = (s & 1) ? xA : xB;
    k_msg2<<<dim3(256), dim3(256), 0, stream>>>(xi, xo, sposW, coff, csrc, csw,
                                                WTgh, WTgl, lng, lnb,
                                                (s == NSTEP - 1) ? 1 : 0, xTh, xTl);
  }
  k_proj2<<<dim3(1024), dim3(256), 0, stream>>>(qxy, mQ, liQ, npos, xTh, xTl, latTh, latTl);
  k_decoder<<<dim3(BB * NP / 32), dim3(256), 0, stream>>>(latTh, latTl, qxy, WTd1h, WTd1l,
                                                          bd1, Wd1, Wd2, bd2, out);
}

// Round 8
// 598.097 us; speedup vs baseline: 3.1005x; 1.1646x over previous
//
#include <hip/hip_runtime.h>

#define BB 8
#define NP 4096    // NPTS == NQ
#define NN 1024
#define NE 8192
#define FF 256
#define TS 264
#define NSTEP 16
#define NSEG 64
#define SEGSZ 128  // NSEG*SEGSZ == NE

typedef float f32x4_t __attribute__((ext_vector_type(4)));
typedef __bf16 bf16x8_t __attribute__((ext_vector_type(8)));
typedef unsigned int u32x4_t __attribute__((ext_vector_type(4)));
typedef unsigned int u32x2_t __attribute__((ext_vector_type(2)));

// hardware RNE f32->bf16; bit-identical to SW round-to-nearest-even on normals
static __device__ __forceinline__ unsigned short f2bf(float f) {
  return __builtin_bit_cast(unsigned short, static_cast<__bf16>(f));
}
static __device__ __forceinline__ float ashf(unsigned short s) {
  union { unsigned u; float f; } t; t.u = (unsigned)s << 16; return t.f;
}
// split a,b into hi/lo bf16 pairs packed as u32
static __device__ __forceinline__ void split_pk(float a, float b, unsigned& h, unsigned& l) {
  unsigned short ha = f2bf(a), hb = f2bf(b);
  unsigned short la = f2bf(a - ashf(ha)), lb = f2bf(b - ashf(hb));
  h = (unsigned)ha | ((unsigned)hb << 16);
  l = (unsigned)la | ((unsigned)lb << 16);
}
static __device__ __forceinline__ f32x4_t mfma16(u32x4_t a, u32x4_t b, f32x4_t c) {
  return __builtin_amdgcn_mfma_f32_16x16x32_bf16(
      __builtin_bit_cast(bf16x8_t, a), __builtin_bit_cast(bf16x8_t, b), c, 0, 0, 0);
}
// 16B-entry XOR swizzle: spreads 64-byte fragment rows over all 32 LDS banks
static __device__ __forceinline__ int swz16(int e) { return e ^ ((e >> 3) & 7); }

// ---------------- graph preprocessing (segmented, deterministic) ----------------
__global__ __launch_bounds__(1024) void k_cnt(const int* __restrict__ dstA,
                                              int* __restrict__ cntg) {
  __shared__ int ds[SEGSZ];
  int seg = blockIdx.x, n = threadIdx.x;
  if (n < SEGSZ) ds[n] = dstA[seg * SEGSZ + n];
  __syncthreads();
  int c = 0;
  #pragma unroll 8
  for (int e = 0; e < SEGSZ; e++) c += (ds[e] == n) ? 1 : 0;
  cntg[seg * NN + n] = c;
}

__global__ __launch_bounds__(1024) void k_scan2(const int* __restrict__ cntg,
    float* __restrict__ dinv, int* __restrict__ csr_off) {
  __shared__ int s[NN];
  int n = threadIdx.x;
  int c = 1;
  for (int sg = 0; sg < NSEG; sg++) c += cntg[sg * NN + n];
  dinv[n] = rsqrtf((float)c);
  s[n] = c;
  __syncthreads();
  for (int st = 1; st < NN; st <<= 1) {
    int v = (n >= st) ? s[n - st] : 0;
    __syncthreads();
    s[n] += v;
    __syncthreads();
  }
  csr_off[n] = s[n] - c;
  if (n == NN - 1) csr_off[NN] = s[n];
}

__global__ __launch_bounds__(1024) void k_fill2(const int* __restrict__ srcA,
    const int* __restrict__ dstA, const float* __restrict__ dinv,
    const int* __restrict__ csr_off, const int* __restrict__ cntg,
    int* __restrict__ csr_src, float* __restrict__ csr_w) {
  int n = threadIdx.x;
  if (blockIdx.x == NSEG) {
    int pos = csr_off[n + 1] - 1;               // self loop last
    csr_src[pos] = n;
    csr_w[pos] = dinv[n] * dinv[n];
    return;
  }
  __shared__ int ds[SEGSZ], ss[SEGSZ];
  int seg = blockIdx.x;
  if (n < SEGSZ) { ds[n] = dstA[seg * SEGSZ + n]; ss[n] = srcA[seg * SEGSZ + n]; }
  __syncthreads();
  int base = csr_off[n];
  for (int s2 = 0; s2 < seg; s2++) base += cntg[s2 * NN + n];
  float dn = dinv[n];
  for (int e = 0; e < SEGSZ; e++) {
    if (ds[e] == n) {
      int sv = ss[e];
      csr_src[base] = sv;
      csr_w[base] = dinv[sv] * dn;
      base++;
    }
  }
}

__global__ __launch_bounds__(256) void k_spos(const float* __restrict__ npos,
    const int* __restrict__ csr_off, const int* __restrict__ csr_src,
    const float* __restrict__ csr_w, float* __restrict__ spos) {
  int n = blockIdx.x * 256 + threadIdx.x;
  if (n >= NN) return;
  float sx = 0.f, sy = 0.f;
  int e1 = csr_off[n + 1];
  for (int e = csr_off[n]; e < e1; e++) {
    float w = csr_w[e]; int s = csr_src[e];
    sx += w * npos[2 * s]; sy += w * npos[2 * s + 1];
  }
  spos[2 * n] = sx; spos[2 * n + 1] = sy;
}

__global__ __launch_bounds__(256) void k_posb(const float* __restrict__ spos,
    const float* __restrict__ Wg, const float* __restrict__ bg, float* __restrict__ sposW) {
  int n = blockIdx.x, f = threadIdx.x;
  sposW[(size_t)n * FF + f] = spos[2 * n] * Wg[f] + spos[2 * n + 1] * Wg[FF + f] + bg[f];
}

// ---------------- softmax stats (inputs and queries in one launch) ----------------
__global__ __launch_bounds__(256) void k_stats(const float* __restrict__ inx,
    const float* __restrict__ qxy, const float* __restrict__ npos,
    float* __restrict__ mI, float* __restrict__ liI,
    float* __restrict__ mQ, float* __restrict__ liQ) {
  const float* xy = blockIdx.y ? qxy : inx;
  float* mOut = blockIdx.y ? mQ : mI;
  float* liOut = blockIdx.y ? liQ : liI;
  int wv = threadIdx.x >> 6, lane = threadIdx.x & 63;
  int pt = blockIdx.x * 4 + wv;
  float px = xy[pt * 2], py = xy[pt * 2 + 1];
  float s[16];
  float m = -1e30f;
  #pragma unroll
  for (int k = 0; k < 16; k++) {
    int n = lane + 64 * k;
    float2 np = ((const float2*)npos)[n];
    float dx = px - np.x, dy = py - np.y;
    float v = -(dx * dx + dy * dy);
    s[k] = v; m = fmaxf(m, v);
  }
  #pragma unroll
  for (int o = 32; o; o >>= 1) m = fmaxf(m, __shfl_xor(m, o));
  float l = 0.f;
  #pragma unroll
  for (int k = 0; k < 16; k++) l += __expf(s[k] - m);
  #pragma unroll
  for (int o = 32; o; o >>= 1) l += __shfl_xor(l, o);
  if (lane == 0) { mOut[pt] = m; liOut[pt] = 1.0f / l; }
}

// ---------------- weight prepack: WT[kc][n][kk] bf16 hi+lo ----------------
__global__ __launch_bounds__(256) void k_pack_w(const float* __restrict__ We2,
    const float* __restrict__ Wg, const float* __restrict__ Wd1,
    unsigned short* __restrict__ WTe2h, unsigned short* __restrict__ WTe2l,
    unsigned short* __restrict__ WTgh, unsigned short* __restrict__ WTgl,
    unsigned short* __restrict__ WTd1h, unsigned short* __restrict__ WTd1l) {
  int kc = blockIdx.x, which = blockIdx.y, n = threadIdx.x;
  const float* W = (which == 0) ? We2 : (which == 1) ? (Wg + 2 * FF) : Wd1;
  unsigned short* Dh = (which == 0) ? WTe2h : (which == 1) ? WTgh : WTd1h;
  unsigned short* Dl = (which == 0) ? WTe2l : (which == 1) ? WTgl : WTd1l;
  unsigned hu[16], lu[16];
  #pragma unroll
  for (int i = 0; i < 16; i++) {
    float a = W[(kc * 32 + 2 * i) * FF + n];
    float b = W[(kc * 32 + 2 * i + 1) * FF + n];
    split_pk(a, b, hu[i], lu[i]);
  }
  u32x4_t* dvh = (u32x4_t*)(Dh + ((size_t)kc * 256 + n) * 32);
  u32x4_t* dvl = (u32x4_t*)(Dl + ((size_t)kc * 256 + n) * 32);
  #pragma unroll
  for (int i = 0; i < 4; i++) {
    u32x4_t th = {hu[4 * i], hu[4 * i + 1], hu[4 * i + 2], hu[4 * i + 3]};
    u32x4_t tl = {lu[4 * i], lu[4 * i + 1], lu[4 * i + 2], lu[4 * i + 3]};
    dvh[i] = th; dvl[i] = tl;
  }
}

// ---------------- encoder: L1 fp32 VALU, L2 split-MFMA; writes encT hi+lo ----------------
__global__ __launch_bounds__(256) void k_encoder(const float* __restrict__ inx,
    const float* __restrict__ iny, const float* __restrict__ We1,
    const float* __restrict__ be1, const unsigned short* __restrict__ WTe2h,
    const unsigned short* __restrict__ WTe2l, const float* __restrict__ be2,
    unsigned short* __restrict__ encTh, unsigned short* __restrict__ encTl) {
  __shared__ float xin[32][8];
  __shared__ float h[32][TS];
  __shared__ unsigned short Bh[8192];
  __shared__ unsigned short Bl[8192];
  int tid = threadIdx.x;
  int row0 = blockIdx.x * 32;
  int wv = tid >> 6, L = tid & 63, lhi = L >> 4, llo = L & 15;

  if (tid < 160) {
    int pt = tid / 5, d = tid % 5;
    int r = row0 + pt;
    xin[pt][d] = (d < 2) ? inx[r * 2 + d] : iny[r * 3 + (d - 2)];
  }
  __syncthreads();
  {
    int f = tid;
    float w0 = We1[f], w1 = We1[256 + f], w2 = We1[512 + f], w3 = We1[768 + f], w4 = We1[1024 + f];
    float bb = be1[f];
    #pragma unroll 4
    for (int pt = 0; pt < 32; pt++) {
      float v = bb + xin[pt][0]*w0 + xin[pt][1]*w1 + xin[pt][2]*w2 + xin[pt][3]*w3 + xin[pt][4]*w4;
      h[pt][f] = fmaxf(v, 0.f);
    }
  }

  f32x4_t acc[2][4];
  #pragma unroll
  for (int cb = 0; cb < 4; cb++) {
    float bc = be2[wv * 64 + cb * 16 + llo];
    f32x4_t t = {bc, bc, bc, bc};
    acc[0][cb] = t; acc[1][cb] = t;
  }

  for (int kc = 0; kc < 8; kc++) {
    __syncthreads();
    {
      const u32x4_t* sh = (const u32x4_t*)(WTe2h + (size_t)kc * 8192);
      const u32x4_t* sl = (const u32x4_t*)(WTe2l + (size_t)kc * 8192);
      u32x4_t* dh = (u32x4_t*)Bh;
      u32x4_t* dl = (u32x4_t*)Bl;
      #pragma unroll
      for (int i = 0; i < 4; i++) {
        int e = tid + i * 256;
        int es = swz16(e);
        dh[es] = sh[e]; dl[es] = sl[e];
      }
    }
    __syncthreads();
    int kbase = kc * 32 + lhi * 8;
    u32x4_t a0h, a0l, a1h, a1l;
    {
      float p[8];
      *(f32x4_t*)p = *(const f32x4_t*)&h[llo][kbase];
      *(f32x4_t*)(p + 4) = *(const f32x4_t*)&h[llo][kbase + 4];
      unsigned hw[4], lw[4];
      #pragma unroll
      for (int i = 0; i < 4; i++) split_pk(p[2 * i], p[2 * i + 1], hw[i], lw[i]);
      u32x4_t th = {hw[0], hw[1], hw[2], hw[3]}; a0h = th;
      u32x4_t tl = {lw[0], lw[1], lw[2], lw[3]}; a0l = tl;
    }
    {
      float p[8];
      *(f32x4_t*)p = *(const f32x4_t*)&h[llo + 16][kbase];
      *(f32x4_t*)(p + 4) = *(const f32x4_t*)&h[llo + 16][kbase + 4];
      unsigned hw[4], lw[4];
      #pragma unroll
      for (int i = 0; i < 4; i++) split_pk(p[2 * i], p[2 * i + 1], hw[i], lw[i]);
      u32x4_t th = {hw[0], hw[1], hw[2], hw[3]}; a1h = th;
      u32x4_t tl = {lw[0], lw[1], lw[2], lw[3]}; a1l = tl;
    }
    #pragma unroll
    for (int cb = 0; cb < 4; cb++) {
      int col = wv * 64 + cb * 16 + llo;
      int off = swz16(col * 4 + lhi) * 8;
      u32x4_t bh = *(const u32x4_t*)&Bh[off];
      u32x4_t bl = *(const u32x4_t*)&Bl[off];
      acc[0][cb] = mfma16(a0h, bh, mfma16(a0h, bl, mfma16(a0l, bh, acc[0][cb])));
      acc[1][cb] = mfma16(a1h, bh, mfma16(a1h, bl, mfma16(a1l, bh, acc[1][cb])));
    }
  }
  #pragma unroll
  for (int rb = 0; rb < 2; rb++)
    #pragma unroll
    for (int cb = 0; cb < 4; cb++) {
      int col = wv * 64 + cb * 16 + llo;
      f32x4_t v = acc[rb][cb];
      size_t idx = ((size_t)blockIdx.x * 256 + col) * 32 + rb * 16 + lhi * 4;
      unsigned hw0, lw0, hw1, lw1;
      split_pk(v[0], v[1], hw0, lw0);
      split_pk(v[2], v[3], hw1, lw1);
      u32x2_t wh = {hw0, hw1}; *(u32x2_t*)&encTh[idx] = wh;
      u32x2_t wl = {lw0, lw1}; *(u32x2_t*)&encTl[idx] = wl;
    }
}

// ---------------- proj1 (split-K, 3-term split MFMA): part[z][b][n][f] ----------------
__global__ __launch_bounds__(256) void k_proj1(const float* __restrict__ inx,
    const float* __restrict__ mI, const float* __restrict__ liI,
    const float* __restrict__ npos, const unsigned short* __restrict__ encTh,
    const unsigned short* __restrict__ encTl, float* __restrict__ part) {
  __shared__ unsigned short BstH[2][8192];
  __shared__ unsigned short BstL[2][8192];
  __shared__ unsigned short AstH[2][1024];
  __shared__ unsigned short AstL[2][1024];
  int tid = threadIdx.x;
  // XCD-aware decode: each XCD owns 4 (b,z)-slices; 32 n-blocks per slice stay local
  int id = blockIdx.x;
  int xcd = id & 7, kid = id >> 3;
  int slice = xcd * 4 + (kid >> 5);
  int n0 = (kid & 31) * 32;
  int b = slice >> 2, z = slice & 3;
  int wv = tid >> 6, L = tid & 63, lhi = L >> 4, llo = L & 15;
  int an = tid >> 3, t7 = tid & 7, ap = t7 * 4;
  float2 npv = ((const float2*)npos)[n0 + an];
  int pbase0 = b * NP + z * 1024;
  int aoff = swz16(an * 4 + (t7 >> 1)) * 8 + (t7 & 1) * 4;

  auto stageA = [&](int kc, int buf) {
    int p = pbase0 + kc * 32 + ap;
    float c[4];
    #pragma unroll
    for (int j = 0; j < 4; j++) {
      float2 pxy = ((const float2*)inx)[p + j];
      float mm = mI[p + j], ll = liI[p + j];
      float dx = pxy.x - npv.x, dy = pxy.y - npv.y;
      c[j] = __expf(-(dx * dx + dy * dy) - mm) * ll;
    }
    unsigned hw0, lw0, hw1, lw1;
    split_pk(c[0], c[1], hw0, lw0);
    split_pk(c[2], c[3], hw1, lw1);
    u32x2_t wh = {hw0, hw1}; *(u32x2_t*)&AstH[buf][aoff] = wh;
    u32x2_t wl = {lw0, lw1}; *(u32x2_t*)&AstL[buf][aoff] = wl;
  };
  auto stageB = [&](int kc, int buf) {
    const u32x4_t* sh = (const u32x4_t*)(encTh + (size_t)(b * 128 + z * 32 + kc) * 8192);
    const u32x4_t* sl = (const u32x4_t*)(encTl + (size_t)(b * 128 + z * 32 + kc) * 8192);
    u32x4_t* dh = (u32x4_t*)BstH[buf];
    u32x4_t* dl = (u32x4_t*)BstL[buf];
    #pragma unroll
    for (int i = 0; i < 4; i++) {
      int e = tid + i * 256;
      int es = swz16(e);
      dh[es] = sh[e]; dl[es] = sl[e];
    }
  };

  f32x4_t acc[2][4];
  #pragma unroll
  for (int i = 0; i < 2; i++)
    #pragma unroll
    for (int j = 0; j < 4; j++) { f32x4_t t = {0.f, 0.f, 0.f, 0.f}; acc[i][j] = t; }

  stageA(0, 0); stageB(0, 0);
  __syncthreads();
  int a0off = swz16(llo * 4 + lhi) * 8;
  int a1off = swz16((llo + 16) * 4 + lhi) * 8;
  for (int kc = 0; kc < 32; kc++) {
    int cur = kc & 1;
    if (kc < 31) { stageA(kc + 1, cur ^ 1); stageB(kc + 1, cur ^ 1); }
    u32x4_t a0h = *(const u32x4_t*)&AstH[cur][a0off];
    u32x4_t a0l = *(const u32x4_t*)&AstL[cur][a0off];
    u32x4_t a1h = *(const u32x4_t*)&AstH[cur][a1off];
    u32x4_t a1l = *(const u32x4_t*)&AstL[cur][a1off];
    #pragma unroll
    for (int cb = 0; cb < 4; cb++) {
      int off = swz16((wv * 64 + cb * 16 + llo) * 4 + lhi) * 8;
      u32x4_t bh = *(const u32x4_t*)&BstH[cur][off];
      u32x4_t bl = *(const u32x4_t*)&BstL[cur][off];
      acc[0][cb] = mfma16(a0h, bh, mfma16(a0h, bl, mfma16(a0l, bh, acc[0][cb])));
      acc[1][cb] = mfma16(a1h, bh, mfma16(a1h, bl, mfma16(a1l, bh, acc[1][cb])));
    }
    __syncthreads();
  }
  float* op = part + (((size_t)(z * BB + b)) * NN + n0) * FF;
  #pragma unroll
  for (int rb = 0; rb < 2; rb++)
    #pragma unroll
    for (int cb = 0; cb < 4; cb++) {
      int col = wv * 64 + cb * 16 + llo;
      f32x4_t v = acc[rb][cb];
      #pragma unroll
      for (int r = 0; r < 4; r++) op[(rb * 16 + lhi * 4 + r) * FF + col] = v[r];
    }
}

// reduce split-K parts -> x (fp32)
__global__ __launch_bounds__(256) void k_reduce(const float* __restrict__ part,
                                                float* __restrict__ x) {
  size_t i = ((size_t)blockIdx.x * 256 + threadIdx.x) * 4;
  const size_t S = (size_t)BB * NN * FF;
  f32x4_t a = *(const f32x4_t*)&part[i];
  f32x4_t b = *(const f32x4_t*)&part[S + i];
  f32x4_t c = *(const f32x4_t*)&part[2 * S + i];
  f32x4_t d = *(const f32x4_t*)&part[3 * S + i];
  f32x4_t r = (a + b) + (c + d);
  *(f32x4_t*)&x[i] = r;
}

// ---------------- fused msg step (512 threads / 8 waves): gather -> MFMA -> LN ----------------
__global__ __launch_bounds__(512) void k_msg2(const float* __restrict__ x_in,
    float* __restrict__ x_out, const float* __restrict__ sposW,
    const int* __restrict__ coff, const int* __restrict__ csrc,
    const float* __restrict__ csw, const unsigned short* __restrict__ WTgh,
    const unsigned short* __restrict__ WTgl, const float* __restrict__ lng,
    const float* __restrict__ lnb, int last,
    unsigned short* __restrict__ xTh, unsigned short* __restrict__ xTl) {
  __shared__ unsigned Ah[32][132];
  __shared__ unsigned Al[32][132];
  __shared__ unsigned short Bh[8192];
  __shared__ unsigned short Bl[8192];
  __shared__ float redS[32][8];
  __shared__ float redQ[32][8];
  int tid = threadIdx.x;
  // XCD-aware: batch b pinned to one XCD so x(b) stays in its L2
  int id = blockIdx.x;
  int b = id & 7;
  int nb = id >> 3;
  int n0 = nb * 32;
  int wv = tid >> 6, L = tid & 63, lhi = L >> 4, llo = L & 15;

  // gather phase: 16 threads per row, 16 features each; per-feature edge order unchanged
  {
    int row = tid >> 4, seg = tid & 15;
    int n = n0 + row;
    float g[16];
    #pragma unroll
    for (int i = 0; i < 16; i++) g[i] = 0.f;
    int e0 = coff[n], e1 = coff[n + 1];
    for (int e = e0; e < e1; e++) {
      float w = csw[e];
      int s = csrc[e];
      const f32x4_t* px = (const f32x4_t*)(x_in + ((size_t)b * NN + s) * FF + seg * 16);
      #pragma unroll
      for (int i = 0; i < 4; i++) {
        f32x4_t v = px[i];
        g[4*i]   += w * v[0]; g[4*i+1] += w * v[1];
        g[4*i+2] += w * v[2]; g[4*i+3] += w * v[3];
      }
    }
    #pragma unroll
    for (int i = 0; i < 8; i++) {
      unsigned h, l;
      split_pk(g[2 * i], g[2 * i + 1], h, l);
      Ah[row][seg * 8 + i] = h;
      Al[row][seg * 8 + i] = l;
    }
  }

  f32x4_t acc[2][2];
  #pragma unroll
  for (int i = 0; i < 2; i++)
    #pragma unroll
    for (int j = 0; j < 2; j++) { f32x4_t t = {0.f, 0.f, 0.f, 0.f}; acc[i][j] = t; }

  for (int kc = 0; kc < 8; kc++) {
    __syncthreads();
    {
      const u32x4_t* sh = (const u32x4_t*)(WTgh + (size_t)kc * 8192);
      const u32x4_t* sl = (const u32x4_t*)(WTgl + (size_t)kc * 8192);
      u32x4_t* dh = (u32x4_t*)Bh;
      u32x4_t* dl = (u32x4_t*)Bl;
      #pragma unroll
      for (int i = 0; i < 2; i++) {
        int e = tid + i * 512;
        int es = swz16(e);
        dh[es] = sh[e]; dl[es] = sl[e];
      }
    }
    __syncthreads();
    u32x4_t a0h = *(const u32x4_t*)&Ah[llo][kc * 16 + lhi * 4];
    u32x4_t a0l = *(const u32x4_t*)&Al[llo][kc * 16 + lhi * 4];
    u32x4_t a1h = *(const u32x4_t*)&Ah[llo + 16][kc * 16 + lhi * 4];
    u32x4_t a1l = *(const u32x4_t*)&Al[llo + 16][kc * 16 + lhi * 4];
    #pragma unroll
    for (int cb = 0; cb < 2; cb++) {
      int off = swz16((wv * 32 + cb * 16 + llo) * 4 + lhi) * 8;
      u32x4_t bh = *(const u32x4_t*)&Bh[off];
      u32x4_t bl = *(const u32x4_t*)&Bl[off];
      acc[0][cb] = mfma16(a0h, bh, mfma16(a0h, bl, mfma16(a0l, bh, acc[0][cb])));
      acc[1][cb] = mfma16(a1h, bh, mfma16(a1h, bl, mfma16(a1l, bh, acc[1][cb])));
    }
  }

  // epilogue: + sposW + residual, then LayerNorm
  #pragma unroll
  for (int rb = 0; rb < 2; rb++)
    #pragma unroll
    for (int cb = 0; cb < 2; cb++) {
      int col = wv * 32 + cb * 16 + llo;
      #pragma unroll
      for (int r = 0; r < 4; r++) {
        int row = rb * 16 + lhi * 4 + r;
        float sw = sposW[(size_t)(n0 + row) * FF + col];
        float xr = x_in[((size_t)b * NN + n0 + row) * FF + col];
        acc[rb][cb][r] += sw + xr;
      }
    }
  float ps[2][4], pq[2][4];
  #pragma unroll
  for (int rb = 0; rb < 2; rb++)
    #pragma unroll
    for (int r = 0; r < 4; r++) {
      float s = 0.f, q = 0.f;
      #pragma unroll
      for (int cb = 0; cb < 2; cb++) { float y = acc[rb][cb][r]; s += y; q += y * y; }
      #pragma unroll
      for (int m = 1; m < 16; m <<= 1) { s += __shfl_xor(s, m); q += __shfl_xor(q, m); }
      ps[rb][r] = s; pq[rb][r] = q;
    }
  if (llo == 0) {
    #pragma unroll
    for (int rb = 0; rb < 2; rb++)
      #pragma unroll
      for (int r = 0; r < 4; r++) {
        int row = rb * 16 + lhi * 4 + r;
        redS[row][wv] = ps[rb][r];
        redQ[row][wv] = pq[rb][r];
      }
  }
  __syncthreads();
  float mrs[2][4][2];
  #pragma unroll
  for (int rb = 0; rb < 2; rb++)
    #pragma unroll
    for (int r = 0; r < 4; r++) {
      int row = rb * 16 + lhi * 4 + r;
      float S = 0.f, Q = 0.f;
      #pragma unroll
      for (int wq = 0; wq < 8; wq++) { S += redS[row][wq]; Q += redQ[row][wq]; }
      float mean = S * (1.f / 256.f);
      float var = Q * (1.f / 256.f) - mean * mean;
      mrs[rb][r][0] = mean;
      mrs[rb][r][1] = rsqrtf(var + 1e-5f);
    }
  #pragma unroll
  for (int cb = 0; cb < 2; cb++) {
    int col = wv * 32 + cb * 16 + llo;
    float gg = lng[col], bb = lnb[col];
    #pragma unroll
    for (int rb = 0; rb < 2; rb++)
      #pragma unroll
      for (int r = 0; r < 4; r++) {
        int row = rb * 16 + lhi * 4 + r;
        float o = (acc[rb][cb][r] - mrs[rb][r][0]) * mrs[rb][r][1] * gg + bb;
        if (!last) {
          x_out[((size_t)b * NN + n0 + row) * FF + col] = o;
        } else {
          size_t idx = (((size_t)b * 32 + nb) * 256 + col) * 32 + row;
          unsigned short hh = f2bf(o);
          xTh[idx] = hh;
          xTl[idx] = f2bf(o - ashf(hh));
        }
      }
  }
}

// ---------------- proj2 (3-term split MFMA): latT hi+lo [bt][fc][row][kk] ----------------
__global__ __launch_bounds__(256) void k_proj2(const float* __restrict__ qxy,
    const float* __restrict__ mQ, const float* __restrict__ liQ,
    const float* __restrict__ npos, const unsigned short* __restrict__ xTh,
    const unsigned short* __restrict__ xTl, unsigned short* __restrict__ latTh,
    unsigned short* __restrict__ latTl) {
  __shared__ unsigned short BstH[2][8192];
  __shared__ unsigned short BstL[2][8192];
  __shared__ unsigned short AstH[2][1024];
  __shared__ unsigned short AstL[2][1024];
  __shared__ float nps[NN * 2];
  int tid = threadIdx.x;
  // XCD-aware: batch b pinned to one XCD so xT(b) stays in its L2
  int id = blockIdx.x;
  int b = id & 7;
  int q0b = id >> 3;             // 0..127
  int q0 = q0b * 32;
  int bt = b * 128 + q0b;
  int wv = tid >> 6, L = tid & 63, lhi = L >> 4, llo = L & 15;
  int aq = tid >> 3, t7 = tid & 7, an4 = t7 * 4;
  int aoff = swz16(aq * 4 + (t7 >> 1)) * 8 + (t7 & 1) * 4;

  {
    const f32x4_t* s4 = (const f32x4_t*)npos;
    *(f32x4_t*)&nps[tid * 4] = s4[tid];
    *(f32x4_t*)&nps[(tid + 256) * 4] = s4[tid + 256];
  }
  int qg = b * NP + q0 + aq;
  float2 qv = ((const float2*)qxy)[qg];
  float qm = mQ[qg], qli = liQ[qg];
  __syncthreads();

  auto stageA = [&](int kc, int buf) {
    int nb = kc * 32 + an4;
    float c[4];
    #pragma unroll
    for (int j = 0; j < 4; j++) {
      float nx = nps[(nb + j) * 2], ny = nps[(nb + j) * 2 + 1];
      float dx = qv.x - nx, dy = qv.y - ny;
      c[j] = __expf(-(dx * dx + dy * dy) - qm) * qli;
    }
    unsigned hw0, lw0, hw1, lw1;
    split_pk(c[0], c[1], hw0, lw0);
    split_pk(c[2], c[3], hw1, lw1);
    u32x2_t wh = {hw0, hw1}; *(u32x2_t*)&AstH[buf][aoff] = wh;
    u32x2_t wl = {lw0, lw1}; *(u32x2_t*)&AstL[buf][aoff] = wl;
  };
  auto stageB = [&](int kc, int buf) {
    const u32x4_t* sh = (const u32x4_t*)(xTh + (size_t)(b * 32 + kc) * 8192);
    const u32x4_t* sl = (const u32x4_t*)(xTl + (size_t)(b * 32 + kc) * 8192);
    u32x4_t* dh = (u32x4_t*)BstH[buf];
    u32x4_t* dl = (u32x4_t*)BstL[buf];
    #pragma unroll
    for (int i = 0; i < 4; i++) {
      int e = tid + i * 256;
      int es = swz16(e);
      dh[es] = sh[e]; dl[es] = sl[e];
    }
  };

  f32x4_t acc[2][4];
  #pragma unroll
  for (int i = 0; i < 2; i++)
    #pragma unroll
    for (int j = 0; j < 4; j++) { f32x4_t t = {0.f, 0.f, 0.f, 0.f}; acc[i][j] = t; }

  stageA(0, 0); stageB(0, 0);
  __syncthreads();
  int a0off = swz16(llo * 4 + lhi) * 8;
  int a1off = swz16((llo + 16) * 4 + lhi) * 8;
  for (int kc = 0; kc < 32; kc++) {
    int cur = kc & 1;
    if (kc < 31) { stageA(kc + 1, cur ^ 1); stageB(kc + 1, cur ^ 1); }
    u32x4_t a0h = *(const u32x4_t*)&AstH[cur][a0off];
    u32x4_t a0l = *(const u32x4_t*)&AstL[cur][a0off];
    u32x4_t a1h = *(const u32x4_t*)&AstH[cur][a1off];
    u32x4_t a1l = *(const u32x4_t*)&AstL[cur][a1off];
    #pragma unroll
    for (int cb = 0; cb < 4; cb++) {
      int off = swz16((wv * 64 + cb * 16 + llo) * 4 + lhi) * 8;
      u32x4_t bh = *(const u32x4_t*)&BstH[cur][off];
      u32x4_t bl = *(const u32x4_t*)&BstL[cur][off];
      acc[0][cb] = mfma16(a0h, bh, mfma16(a0h, bl, mfma16(a0l, bh, acc[0][cb])));
      acc[1][cb] = mfma16(a1h, bh, mfma16(a1h, bl, mfma16(a1l, bh, acc[1][cb])));
    }
    __syncthreads();
  }
  #pragma unroll
  for (int rb = 0; rb < 2; rb++)
    #pragma unroll
    for (int cb = 0; cb < 4; cb++) {
      int col = wv * 64 + cb * 16 + llo;
      int fc = col >> 5, kk = col & 31;
      f32x4_t v = acc[rb][cb];
      #pragma unroll
      for (int r = 0; r < 4; r++) {
        size_t idx = ((size_t)bt * 8 + fc) * 1024 + (rb * 16 + lhi * 4 + r) * 32 + kk;
        unsigned short hh = f2bf(v[r]);
        latTh[idx] = hh;
        latTl[idx] = f2bf(v[r] - ashf(hh));
      }
    }
}

// ---------------- decoder (3-term split MFMA + fused second GEMM) ----------------
__global__ __launch_bounds__(256) void k_decoder(const unsigned short* __restrict__ latTh,
    const unsigned short* __restrict__ latTl, const float* __restrict__ qxy,
    const unsigned short* __restrict__ WTd1h, const unsigned short* __restrict__ WTd1l,
    const float* __restrict__ bd1, const float* __restrict__ Wd1,
    const float* __restrict__ Wd2, const float* __restrict__ bd2, float* __restrict__ out) {
  __shared__ unsigned short BstH[2][8192];
  __shared__ unsigned short BstL[2][8192];
  __shared__ unsigned short AstH[2][1024];
  __shared__ unsigned short AstL[2][1024];
  __shared__ float qs[32][2];
  __shared__ float red[4][32][3];
  int tid = threadIdx.x;
  int bt = blockIdx.x;
  int wv = tid >> 6, L = tid & 63, lhi = L >> 4, llo = L & 15;

  auto stageA = [&](int kc, int buf) {
    if (tid < 128)
      ((u32x4_t*)AstH[buf])[swz16(tid)] = ((const u32x4_t*)(latTh + ((size_t)bt * 8 + kc) * 1024))[tid];
    else
      ((u32x4_t*)AstL[buf])[swz16(tid - 128)] = ((const u32x4_t*)(latTl + ((size_t)bt * 8 + kc) * 1024))[tid - 128];
  };
  auto stageB = [&](int kc, int buf) {
    const u32x4_t* sh = (const u32x4_t*)(WTd1h + (size_t)kc * 8192);
    const u32x4_t* sl = (const u32x4_t*)(WTd1l + (size_t)kc * 8192);
    u32x4_t* dh = (u32x4_t*)BstH[buf];
    u32x4_t* dl = (u32x4_t*)BstL[buf];
    #pragma unroll
    for (int i = 0; i < 4; i++) {
      int e = tid + i * 256;
      int es = swz16(e);
      dh[es] = sh[e]; dl[es] = sl[e];
    }
  };

  if (tid < 64) qs[tid >> 1][tid & 1] = qxy[((size_t)bt * 32 + (tid >> 1)) * 2 + (tid & 1)];
  stageA(0, 0); stageB(0, 0);
  __syncthreads();

  f32x4_t acc[2][4];
  #pragma unroll
  for (int cb = 0; cb < 4; cb++) {
    int col = wv * 64 + cb * 16 + llo;
    float wa = Wd1[256 * FF + col], wb = Wd1[257 * FF + col], bc = bd1[col];
    #pragma unroll
    for (int rb = 0; rb < 2; rb++) {
      f32x4_t t;
      #pragma unroll
      for (int r = 0; r < 4; r++) {
        int row = rb * 16 + lhi * 4 + r;
        t[r] = bc + qs[row][0] * wa + qs[row][1] * wb;
      }
      acc[rb][cb] = t;
    }
  }

  int a0off = swz16(llo * 4 + lhi) * 8;
  int a1off = swz16((llo + 16) * 4 + lhi) * 8;
  for (int kc = 0; kc < 8; kc++) {
    int cur = kc & 1;
    if (kc < 7) { stageA(kc + 1, cur ^ 1); stageB(kc + 1, cur ^ 1); }
    u32x4_t a0h = *(const u32x4_t*)&AstH[cur][a0off];
    u32x4_t a0l = *(const u32x4_t*)&AstL[cur][a0off];
    u32x4_t a1h = *(const u32x4_t*)&AstH[cur][a1off];
    u32x4_t a1l = *(const u32x4_t*)&AstL[cur][a1off];
    #pragma unroll
    for (int cb = 0; cb < 4; cb++) {
      int off = swz16((wv * 64 + cb * 16 + llo) * 4 + lhi) * 8;
      u32x4_t bh = *(const u32x4_t*)&BstH[cur][off];
      u32x4_t bl = *(const u32x4_t*)&BstL[cur][off];
      acc[0][cb] = mfma16(a0h, bh, mfma16(a0h, bl, mfma16(a0l, bh, acc[0][cb])));
      acc[1][cb] = mfma16(a1h, bh, mfma16(a1h, bl, mfma16(a1l, bh, acc[1][cb])));
    }
    __syncthreads();
  }

  float po[2][4][3];
  #pragma unroll
  for (int rb = 0; rb < 2; rb++)
    #pragma unroll
    for (int r = 0; r < 4; r++) { po[rb][r][0] = 0.f; po[rb][r][1] = 0.f; po[rb][r][2] = 0.f; }
  #pragma unroll
  for (int rb = 0; rb < 2; rb++)
    #pragma unroll
    for (int cb = 0; cb < 4; cb++) {
      int col = wv * 64 + cb * 16 + llo;
      float w0 = Wd2[col * 3], w1 = Wd2[col * 3 + 1], w2 = Wd2[col * 3 + 2];
      f32x4_t v = acc[rb][cb];
      #pragma unroll
      for (int r = 0; r < 4; r++) {
        float hv = fmaxf(v[r], 0.f);
        po[rb][r][0] += hv * w0; po[rb][r][1] += hv * w1; po[rb][r][2] += hv * w2;
      }
    }
  #pragma unroll
  for (int o = 8; o; o >>= 1)
    #pragma unroll
    for (int rb = 0; rb < 2; rb++)
      #pragma unroll
      for (int r = 0; r < 4; r++) {
        po[rb][r][0] += __shfl_xor(po[rb][r][0], o);
        po[rb][r][1] += __shfl_xor(po[rb][r][1], o);
        po[rb][r][2] += __shfl_xor(po[rb][r][2], o);
      }
  if (llo == 0) {
    #pragma unroll
    for (int rb = 0; rb < 2; rb++)
      #pragma unroll
      for (int r = 0; r < 4; r++) {
        int row = rb * 16 + lhi * 4 + r;
        red[wv][row][0] = po[rb][r][0];
        red[wv][row][1] = po[rb][r][1];
        red[wv][row][2] = po[rb][r][2];
      }
  }
  __syncthreads();
  if (tid < 96) {
    int row = tid / 3, o = tid % 3;
    float s = red[0][row][o] + red[1][row][o] + red[2][row][o] + red[3][row][o] + bd2[o];
    out[((size_t)bt * 32 + row) * 3 + o] = s;
  }
}

extern "C" void kernel_launch(void* const* d_in, const int* in_sizes, int n_in,
                              void* d_out, int out_size, void* d_ws, size_t ws_size,
                              hipStream_t stream) {
  const float* inx = (const float*)d_in[0];
  const float* iny = (const float*)d_in[1];
  const float* qxy = (const float*)d_in[2];
  const float* npos = (const float*)d_in[3];
  const float* We1 = (const float*)d_in[4];
  const float* be1 = (const float*)d_in[5];
  const float* We2 = (const float*)d_in[6];
  const float* be2 = (const float*)d_in[7];
  const float* Wg  = (const float*)d_in[8];
  const float* bg  = (const float*)d_in[9];
  const float* lng = (const float*)d_in[10];
  const float* lnb = (const float*)d_in[11];
  const float* Wd1 = (const float*)d_in[12];
  const float* bd1 = (const float*)d_in[13];
  const float* Wd2 = (const float*)d_in[14];
  const float* bd2 = (const float*)d_in[15];
  const int* eidx  = (const int*)d_in[16];
  float* out = (float*)d_out;

  char* w = (char*)d_ws;
  auto carve = [&](size_t n) { char* p = w; w += (n + 255) & ~(size_t)255; return p; };
  char* encR = carve((size_t)2 * BB * NP * FF * 2);                          // 32 MB
  unsigned short* encTh = (unsigned short*)encR;
  unsigned short* encTl = (unsigned short*)(encR + (size_t)BB * NP * FF * 2);
  unsigned short* latTh = encTh;   // alias (dead after proj1)
  unsigned short* latTl = encTl;
  float* xA = (float*)carve((size_t)BB * NN * FF * 4);                       // 8 MB
  float* xB = (float*)carve((size_t)BB * NN * FF * 4);                       // 8 MB
  unsigned short* xTh = (unsigned short*)carve((size_t)BB * NN * FF * 2);    // 4 MB
  unsigned short* xTl = (unsigned short*)carve((size_t)BB * NN * FF * 2);    // 4 MB
  float* part = (float*)carve((size_t)4 * BB * NN * FF * 4);                 // 32 MB
  float* mI   = (float*)carve((size_t)BB * NP * 4);
  float* liI  = (float*)carve((size_t)BB * NP * 4);
  float* mQ   = (float*)carve((size_t)BB * NP * 4);
  float* liQ  = (float*)carve((size_t)BB * NP * 4);
  unsigned short* WTe2h = (unsigned short*)carve((size_t)8 * 256 * 32 * 2);
  unsigned short* WTe2l = (unsigned short*)carve((size_t)8 * 256 * 32 * 2);
  unsigned short* WTgh  = (unsigned short*)carve((size_t)8 * 256 * 32 * 2);
  unsigned short* WTgl  = (unsigned short*)carve((size_t)8 * 256 * 32 * 2);
  unsigned short* WTd1h = (unsigned short*)carve((size_t)8 * 256 * 32 * 2);
  unsigned short* WTd1l = (unsigned short*)carve((size_t)8 * 256 * 32 * 2);
  float* sposW = (float*)carve((size_t)NN * FF * 4);
  float* dinv = (float*)carve(NN * 4);
  float* spos = (float*)carve(NN * 2 * 4);
  float* csw  = (float*)carve((NE + NN) * 4);
  int* coff   = (int*)carve((NN + 1) * 4);
  int* csrc   = (int*)carve((NE + NN) * 4);
  int* cntg   = (int*)carve((size_t)NSEG * NN * 4);

  const int* esrc = eidx;
  const int* edst = eidx + NE;

  k_cnt<<<dim3(NSEG), dim3(1024), 0, stream>>>(edst, cntg);
  k_scan2<<<dim3(1), dim3(1024), 0, stream>>>(cntg, dinv, coff);
  k_fill2<<<dim3(NSEG + 1), dim3(1024), 0, stream>>>(esrc, edst, dinv, coff, cntg, csrc, csw);
  k_spos<<<dim3(4), dim3(256), 0, stream>>>(npos, coff, csrc, csw, spos);
  k_posb<<<dim3(NN), dim3(256), 0, stream>>>(spos, Wg, bg, sposW);
  k_pack_w<<<dim3(8, 3), dim3(256), 0, stream>>>(We2, Wg, Wd1, WTe2h, WTe2l, WTgh, WTgl,
                                                 WTd1h, WTd1l);

  k_stats<<<dim3(BB * NP / 4, 2), dim3(256), 0, stream>>>(inx, qxy, npos, mI, liI, mQ, liQ);
  k_encoder<<<dim3(BB * NP / 32), dim3(256), 0, stream>>>(inx, iny, We1, be1, WTe2h, WTe2l, be2,
                                                          encTh, encTl);
  k_proj1<<<dim3(1024), dim3(256), 0, stream>>>(inx, mI, liI, npos, encTh, encTl, part);
  k_reduce<<<dim3(BB * NN * FF / 1024), dim3(256), 0, stream>>>(part, xA);
  for (int s = 0; s < NSTEP; s++) {
    const float* xi = (s & 1) ? xB : xA;
    float* xo = (s & 1) ? xA : xB;
    k_msg2<<<dim3(256), dim3(512), 0, stream>>>(xi, xo, sposW, coff, csrc, csw,
                                                WTgh, WTgl, lng, lnb,
                                                (s == NSTEP - 1) ? 1 : 0, xTh, xTl);
  }
  k_proj2<<<dim3(1024), dim3(256), 0, stream>>>(qxy, mQ, liQ, npos, xTh, xTl, latTh, latTl);
  k_decoder<<<dim3(BB * NP / 32), dim3(256), 0, stream>>>(latTh, latTl, qxy, WTd1h, WTd1l,
                                                          bd1, Wd1, Wd2, bd2, out);
}

// Round 9
// 561.191 us; speedup vs baseline: 3.3044x; 1.0658x over previous
//
#include <hip/hip_runtime.h>

#define BB 8
#define NP 4096    // NPTS == NQ
#define NN 1024
#define NE 8192
#define FF 256
#define TS 264
#define NSTEP 16
#define NSEG 64
#define SEGSZ 128  // NSEG*SEGSZ == NE

typedef float f32x4_t __attribute__((ext_vector_type(4)));
typedef __bf16 bf16x8_t __attribute__((ext_vector_type(8)));
typedef unsigned int u32x4_t __attribute__((ext_vector_type(4)));
typedef unsigned int u32x2_t __attribute__((ext_vector_type(2)));

// hardware RNE f32->bf16; bit-identical to SW round-to-nearest-even on normals
static __device__ __forceinline__ unsigned short f2bf(float f) {
  return __builtin_bit_cast(unsigned short, static_cast<__bf16>(f));
}
static __device__ __forceinline__ float ashf(unsigned short s) {
  union { unsigned u; float f; } t; t.u = (unsigned)s << 16; return t.f;
}
// split a,b into hi/lo bf16 pairs packed as u32
static __device__ __forceinline__ void split_pk(float a, float b, unsigned& h, unsigned& l) {
  unsigned short ha = f2bf(a), hb = f2bf(b);
  unsigned short la = f2bf(a - ashf(ha)), lb = f2bf(b - ashf(hb));
  h = (unsigned)ha | ((unsigned)hb << 16);
  l = (unsigned)la | ((unsigned)lb << 16);
}
static __device__ __forceinline__ f32x4_t mfma16(u32x4_t a, u32x4_t b, f32x4_t c) {
  return __builtin_amdgcn_mfma_f32_16x16x32_bf16(
      __builtin_bit_cast(bf16x8_t, a), __builtin_bit_cast(bf16x8_t, b), c, 0, 0, 0);
}
// 16B-entry XOR swizzle: spreads 64-byte fragment rows over all 32 LDS banks
static __device__ __forceinline__ int swz16(int e) { return e ^ ((e >> 3) & 7); }

// ---------------- graph preprocessing (segmented, deterministic) ----------------
__global__ __launch_bounds__(1024) void k_cnt(const int* __restrict__ dstA,
                                              int* __restrict__ cntg) {
  __shared__ int ds[SEGSZ];
  int seg = blockIdx.x, n = threadIdx.x;
  if (n < SEGSZ) ds[n] = dstA[seg * SEGSZ + n];
  __syncthreads();
  int c = 0;
  #pragma unroll 8
  for (int e = 0; e < SEGSZ; e++) c += (ds[e] == n) ? 1 : 0;
  cntg[seg * NN + n] = c;
}

__global__ __launch_bounds__(1024) void k_scan2(const int* __restrict__ cntg,
    float* __restrict__ dinv, int* __restrict__ csr_off) {
  __shared__ int s[NN];
  int n = threadIdx.x;
  int c = 1;
  for (int sg = 0; sg < NSEG; sg++) c += cntg[sg * NN + n];
  dinv[n] = rsqrtf((float)c);
  s[n] = c;
  __syncthreads();
  for (int st = 1; st < NN; st <<= 1) {
    int v = (n >= st) ? s[n - st] : 0;
    __syncthreads();
    s[n] += v;
    __syncthreads();
  }
  csr_off[n] = s[n] - c;
  if (n == NN - 1) csr_off[NN] = s[n];
}

__global__ __launch_bounds__(1024) void k_fill2(const int* __restrict__ srcA,
    const int* __restrict__ dstA, const float* __restrict__ dinv,
    const int* __restrict__ csr_off, const int* __restrict__ cntg,
    int* __restrict__ csr_src, float* __restrict__ csr_w) {
  int n = threadIdx.x;
  if (blockIdx.x == NSEG) {
    int pos = csr_off[n + 1] - 1;               // self loop last
    csr_src[pos] = n;
    csr_w[pos] = dinv[n] * dinv[n];
    return;
  }
  __shared__ int ds[SEGSZ], ss[SEGSZ];
  int seg = blockIdx.x;
  if (n < SEGSZ) { ds[n] = dstA[seg * SEGSZ + n]; ss[n] = srcA[seg * SEGSZ + n]; }
  __syncthreads();
  int base = csr_off[n];
  for (int s2 = 0; s2 < seg; s2++) base += cntg[s2 * NN + n];
  float dn = dinv[n];
  for (int e = 0; e < SEGSZ; e++) {
    if (ds[e] == n) {
      int sv = ss[e];
      csr_src[base] = sv;
      csr_w[base] = dinv[sv] * dn;
      base++;
    }
  }
}

__global__ __launch_bounds__(256) void k_spos(const float* __restrict__ npos,
    const int* __restrict__ csr_off, const int* __restrict__ csr_src,
    const float* __restrict__ csr_w, float* __restrict__ spos) {
  int n = blockIdx.x * 256 + threadIdx.x;
  if (n >= NN) return;
  float sx = 0.f, sy = 0.f;
  int e1 = csr_off[n + 1];
  for (int e = csr_off[n]; e < e1; e++) {
    float w = csr_w[e]; int s = csr_src[e];
    sx += w * npos[2 * s]; sy += w * npos[2 * s + 1];
  }
  spos[2 * n] = sx; spos[2 * n + 1] = sy;
}

__global__ __launch_bounds__(256) void k_posb(const float* __restrict__ spos,
    const float* __restrict__ Wg, const float* __restrict__ bg, float* __restrict__ sposW) {
  int n = blockIdx.x, f = threadIdx.x;
  sposW[(size_t)n * FF + f] = spos[2 * n] * Wg[f] + spos[2 * n + 1] * Wg[FF + f] + bg[f];
}

// ---------------- softmax stats (inputs and queries in one launch) ----------------
__global__ __launch_bounds__(256) void k_stats(const float* __restrict__ inx,
    const float* __restrict__ qxy, const float* __restrict__ npos,
    float* __restrict__ mI, float* __restrict__ liI,
    float* __restrict__ mQ, float* __restrict__ liQ) {
  const float* xy = blockIdx.y ? qxy : inx;
  float* mOut = blockIdx.y ? mQ : mI;
  float* liOut = blockIdx.y ? liQ : liI;
  int wv = threadIdx.x >> 6, lane = threadIdx.x & 63;
  int pt = blockIdx.x * 4 + wv;
  float px = xy[pt * 2], py = xy[pt * 2 + 1];
  float s[16];
  float m = -1e30f;
  #pragma unroll
  for (int k = 0; k < 16; k++) {
    int n = lane + 64 * k;
    float2 np = ((const float2*)npos)[n];
    float dx = px - np.x, dy = py - np.y;
    float v = -(dx * dx + dy * dy);
    s[k] = v; m = fmaxf(m, v);
  }
  #pragma unroll
  for (int o = 32; o; o >>= 1) m = fmaxf(m, __shfl_xor(m, o));
  float l = 0.f;
  #pragma unroll
  for (int k = 0; k < 16; k++) l += __expf(s[k] - m);
  #pragma unroll
  for (int o = 32; o; o >>= 1) l += __shfl_xor(l, o);
  if (lane == 0) { mOut[pt] = m; liOut[pt] = 1.0f / l; }
}

// ---------------- weight prepack: WT[kc][n][kk] bf16 hi+lo ----------------
__global__ __launch_bounds__(256) void k_pack_w(const float* __restrict__ We2,
    const float* __restrict__ Wg, const float* __restrict__ Wd1,
    unsigned short* __restrict__ WTe2h, unsigned short* __restrict__ WTe2l,
    unsigned short* __restrict__ WTgh, unsigned short* __restrict__ WTgl,
    unsigned short* __restrict__ WTd1h, unsigned short* __restrict__ WTd1l) {
  int kc = blockIdx.x, which = blockIdx.y, n = threadIdx.x;
  const float* W = (which == 0) ? We2 : (which == 1) ? (Wg + 2 * FF) : Wd1;
  unsigned short* Dh = (which == 0) ? WTe2h : (which == 1) ? WTgh : WTd1h;
  unsigned short* Dl = (which == 0) ? WTe2l : (which == 1) ? WTgl : WTd1l;
  unsigned hu[16], lu[16];
  #pragma unroll
  for (int i = 0; i < 16; i++) {
    float a = W[(kc * 32 + 2 * i) * FF + n];
    float b = W[(kc * 32 + 2 * i + 1) * FF + n];
    split_pk(a, b, hu[i], lu[i]);
  }
  u32x4_t* dvh = (u32x4_t*)(Dh + ((size_t)kc * 256 + n) * 32);
  u32x4_t* dvl = (u32x4_t*)(Dl + ((size_t)kc * 256 + n) * 32);
  #pragma unroll
  for (int i = 0; i < 4; i++) {
    u32x4_t th = {hu[4 * i], hu[4 * i + 1], hu[4 * i + 2], hu[4 * i + 3]};
    u32x4_t tl = {lu[4 * i], lu[4 * i + 1], lu[4 * i + 2], lu[4 * i + 3]};
    dvh[i] = th; dvl[i] = tl;
  }
}

// ---------------- encoder: L1 fp32 VALU, L2 split-MFMA; writes encT hi+lo ----------------
__global__ __launch_bounds__(256) void k_encoder(const float* __restrict__ inx,
    const float* __restrict__ iny, const float* __restrict__ We1,
    const float* __restrict__ be1, const unsigned short* __restrict__ WTe2h,
    const unsigned short* __restrict__ WTe2l, const float* __restrict__ be2,
    unsigned short* __restrict__ encTh, unsigned short* __restrict__ encTl) {
  __shared__ float xin[32][8];
  __shared__ float h[32][TS];
  __shared__ unsigned short Bh[8192];
  __shared__ unsigned short Bl[8192];
  int tid = threadIdx.x;
  int row0 = blockIdx.x * 32;
  int wv = tid >> 6, L = tid & 63, lhi = L >> 4, llo = L & 15;

  if (tid < 160) {
    int pt = tid / 5, d = tid % 5;
    int r = row0 + pt;
    xin[pt][d] = (d < 2) ? inx[r * 2 + d] : iny[r * 3 + (d - 2)];
  }
  __syncthreads();
  {
    int f = tid;
    float w0 = We1[f], w1 = We1[256 + f], w2 = We1[512 + f], w3 = We1[768 + f], w4 = We1[1024 + f];
    float bb = be1[f];
    #pragma unroll 4
    for (int pt = 0; pt < 32; pt++) {
      float v = bb + xin[pt][0]*w0 + xin[pt][1]*w1 + xin[pt][2]*w2 + xin[pt][3]*w3 + xin[pt][4]*w4;
      h[pt][f] = fmaxf(v, 0.f);
    }
  }

  f32x4_t acc[2][4];
  #pragma unroll
  for (int cb = 0; cb < 4; cb++) {
    float bc = be2[wv * 64 + cb * 16 + llo];
    f32x4_t t = {bc, bc, bc, bc};
    acc[0][cb] = t; acc[1][cb] = t;
  }

  for (int kc = 0; kc < 8; kc++) {
    __syncthreads();
    {
      const u32x4_t* sh = (const u32x4_t*)(WTe2h + (size_t)kc * 8192);
      const u32x4_t* sl = (const u32x4_t*)(WTe2l + (size_t)kc * 8192);
      u32x4_t* dh = (u32x4_t*)Bh;
      u32x4_t* dl = (u32x4_t*)Bl;
      #pragma unroll
      for (int i = 0; i < 4; i++) {
        int e = tid + i * 256;
        int es = swz16(e);
        dh[es] = sh[e]; dl[es] = sl[e];
      }
    }
    __syncthreads();
    int kbase = kc * 32 + lhi * 8;
    u32x4_t a0h, a0l, a1h, a1l;
    {
      float p[8];
      *(f32x4_t*)p = *(const f32x4_t*)&h[llo][kbase];
      *(f32x4_t*)(p + 4) = *(const f32x4_t*)&h[llo][kbase + 4];
      unsigned hw[4], lw[4];
      #pragma unroll
      for (int i = 0; i < 4; i++) split_pk(p[2 * i], p[2 * i + 1], hw[i], lw[i]);
      u32x4_t th = {hw[0], hw[1], hw[2], hw[3]}; a0h = th;
      u32x4_t tl = {lw[0], lw[1], lw[2], lw[3]}; a0l = tl;
    }
    {
      float p[8];
      *(f32x4_t*)p = *(const f32x4_t*)&h[llo + 16][kbase];
      *(f32x4_t*)(p + 4) = *(const f32x4_t*)&h[llo + 16][kbase + 4];
      unsigned hw[4], lw[4];
      #pragma unroll
      for (int i = 0; i < 4; i++) split_pk(p[2 * i], p[2 * i + 1], hw[i], lw[i]);
      u32x4_t th = {hw[0], hw[1], hw[2], hw[3]}; a1h = th;
      u32x4_t tl = {lw[0], lw[1], lw[2], lw[3]}; a1l = tl;
    }
    #pragma unroll
    for (int cb = 0; cb < 4; cb++) {
      int col = wv * 64 + cb * 16 + llo;
      int off = swz16(col * 4 + lhi) * 8;
      u32x4_t bh = *(const u32x4_t*)&Bh[off];
      u32x4_t bl = *(const u32x4_t*)&Bl[off];
      acc[0][cb] = mfma16(a0h, bh, mfma16(a0h, bl, mfma16(a0l, bh, acc[0][cb])));
      acc[1][cb] = mfma16(a1h, bh, mfma16(a1h, bl, mfma16(a1l, bh, acc[1][cb])));
    }
  }
  #pragma unroll
  for (int rb = 0; rb < 2; rb++)
    #pragma unroll
    for (int cb = 0; cb < 4; cb++) {
      int col = wv * 64 + cb * 16 + llo;
      f32x4_t v = acc[rb][cb];
      size_t idx = ((size_t)blockIdx.x * 256 + col) * 32 + rb * 16 + lhi * 4;
      unsigned hw0, lw0, hw1, lw1;
      split_pk(v[0], v[1], hw0, lw0);
      split_pk(v[2], v[3], hw1, lw1);
      u32x2_t wh = {hw0, hw1}; *(u32x2_t*)&encTh[idx] = wh;
      u32x2_t wl = {lw0, lw1}; *(u32x2_t*)&encTl[idx] = wl;
    }
}

// ---------------- proj1 (split-K, single-buffer LDS + reg prefetch) ----------------
__global__ __launch_bounds__(256, 4) void k_proj1(const float* __restrict__ inx,
    const float* __restrict__ mI, const float* __restrict__ liI,
    const float* __restrict__ npos, const unsigned short* __restrict__ encTh,
    const unsigned short* __restrict__ encTl, float* __restrict__ part) {
  __shared__ unsigned short BstH[8192];
  __shared__ unsigned short BstL[8192];
  __shared__ unsigned short AstH[1024];
  __shared__ unsigned short AstL[1024];
  int tid = threadIdx.x;
  // XCD-aware decode: each XCD owns 4 (b,z)-slices; 32 n-blocks per slice stay local
  int id = blockIdx.x;
  int xcd = id & 7, kid = id >> 3;
  int slice = xcd * 4 + (kid >> 5);
  int n0 = (kid & 31) * 32;
  int b = slice >> 2, z = slice & 3;
  int wv = tid >> 6, L = tid & 63, lhi = L >> 4, llo = L & 15;
  int an = tid >> 3, t7 = tid & 7, ap = t7 * 4;
  float2 npv = ((const float2*)npos)[n0 + an];
  int pbase0 = b * NP + z * 1024;
  int aoff = swz16(an * 4 + (t7 >> 1)) * 8 + (t7 & 1) * 4;

  u32x4_t rbh[4], rbl[4];
  unsigned ch0, ch1, cl0, cl1;

  auto coordA = [&](int kc) {
    int p = pbase0 + kc * 32 + ap;
    float c[4];
    #pragma unroll
    for (int j = 0; j < 4; j++) {
      float2 pxy = ((const float2*)inx)[p + j];
      float mm = mI[p + j], ll = liI[p + j];
      float dx = pxy.x - npv.x, dy = pxy.y - npv.y;
      c[j] = __expf(-(dx * dx + dy * dy) - mm) * ll;
    }
    split_pk(c[0], c[1], ch0, cl0);
    split_pk(c[2], c[3], ch1, cl1);
  };
  auto loadB = [&](int kc) {
    const u32x4_t* sh = (const u32x4_t*)(encTh + (size_t)(b * 128 + z * 32 + kc) * 8192);
    const u32x4_t* sl = (const u32x4_t*)(encTl + (size_t)(b * 128 + z * 32 + kc) * 8192);
    #pragma unroll
    for (int i = 0; i < 4; i++) { rbh[i] = sh[tid + i * 256]; rbl[i] = sl[tid + i * 256]; }
  };

  f32x4_t acc[2][4];
  #pragma unroll
  for (int i = 0; i < 2; i++)
    #pragma unroll
    for (int j = 0; j < 4; j++) { f32x4_t t = {0.f, 0.f, 0.f, 0.f}; acc[i][j] = t; }

  coordA(0);
  loadB(0);
  int a0off = swz16(llo * 4 + lhi) * 8;
  int a1off = swz16((llo + 16) * 4 + lhi) * 8;
  for (int kc = 0; kc < 32; kc++) {
    __syncthreads();                       // previous compute done reading LDS
    #pragma unroll
    for (int i = 0; i < 4; i++) {
      int es = swz16(tid + i * 256);
      ((u32x4_t*)BstH)[es] = rbh[i];
      ((u32x4_t*)BstL)[es] = rbl[i];
    }
    { u32x2_t wh = {ch0, ch1}; *(u32x2_t*)&AstH[aoff] = wh; }
    { u32x2_t wl = {cl0, cl1}; *(u32x2_t*)&AstL[aoff] = wl; }
    __syncthreads();
    if (kc < 31) { loadB(kc + 1); coordA(kc + 1); }   // in flight / co-issue during MFMA
    u32x4_t a0h = *(const u32x4_t*)&AstH[a0off];
    u32x4_t a0l = *(const u32x4_t*)&AstL[a0off];
    u32x4_t a1h = *(const u32x4_t*)&AstH[a1off];
    u32x4_t a1l = *(const u32x4_t*)&AstL[a1off];
    #pragma unroll
    for (int cb = 0; cb < 4; cb++) {
      int off = swz16((wv * 64 + cb * 16 + llo) * 4 + lhi) * 8;
      u32x4_t bh = *(const u32x4_t*)&BstH[off];
      u32x4_t bl = *(const u32x4_t*)&BstL[off];
      acc[0][cb] = mfma16(a0h, bh, mfma16(a0h, bl, mfma16(a0l, bh, acc[0][cb])));
      acc[1][cb] = mfma16(a1h, bh, mfma16(a1h, bl, mfma16(a1l, bh, acc[1][cb])));
    }
  }
  float* op = part + (((size_t)(z * BB + b)) * NN + n0) * FF;
  #pragma unroll
  for (int rb = 0; rb < 2; rb++)
    #pragma unroll
    for (int cb = 0; cb < 4; cb++) {
      int col = wv * 64 + cb * 16 + llo;
      f32x4_t v = acc[rb][cb];
      #pragma unroll
      for (int r = 0; r < 4; r++) op[(rb * 16 + lhi * 4 + r) * FF + col] = v[r];
    }
}

// reduce split-K parts -> x (fp32)
__global__ __launch_bounds__(256) void k_reduce(const float* __restrict__ part,
                                                float* __restrict__ x) {
  size_t i = ((size_t)blockIdx.x * 256 + threadIdx.x) * 4;
  const size_t S = (size_t)BB * NN * FF;
  f32x4_t a = *(const f32x4_t*)&part[i];
  f32x4_t b = *(const f32x4_t*)&part[S + i];
  f32x4_t c = *(const f32x4_t*)&part[2 * S + i];
  f32x4_t d = *(const f32x4_t*)&part[3 * S + i];
  f32x4_t r = (a + b) + (c + d);
  *(f32x4_t*)&x[i] = r;
}

// ---------------- fused msg step (512 thr, reg-staged LDS dbuf, 1 barrier/kc) ----------------
__global__ __launch_bounds__(512) void k_msg2(const float* __restrict__ x_in,
    float* __restrict__ x_out, const float* __restrict__ sposW,
    const int* __restrict__ coff, const int* __restrict__ csrc,
    const float* __restrict__ csw, const unsigned short* __restrict__ WTgh,
    const unsigned short* __restrict__ WTgl, const float* __restrict__ lng,
    const float* __restrict__ lnb, int last,
    unsigned short* __restrict__ xTh, unsigned short* __restrict__ xTl) {
  __shared__ unsigned Ah[32][132];
  __shared__ unsigned Al[32][132];
  __shared__ unsigned short Bh[2][8192];
  __shared__ unsigned short Bl[2][8192];
  __shared__ float redS[32][8];
  __shared__ float redQ[32][8];
  int tid = threadIdx.x;
  // XCD-aware: batch b pinned to one XCD so x(b) stays in its L2
  int id = blockIdx.x;
  int b = id & 7;
  int nb = id >> 3;
  int n0 = nb * 32;
  int wv = tid >> 6, L = tid & 63, lhi = L >> 4, llo = L & 15;

  u32x4_t rbh[2], rbl[2];
  auto loadB = [&](int kc) {
    const u32x4_t* sh = (const u32x4_t*)(WTgh + (size_t)kc * 8192);
    const u32x4_t* sl = (const u32x4_t*)(WTgl + (size_t)kc * 8192);
    #pragma unroll
    for (int i = 0; i < 2; i++) { rbh[i] = sh[tid + i * 512]; rbl[i] = sl[tid + i * 512]; }
  };
  auto writeB = [&](int buf) {
    u32x4_t* dh = (u32x4_t*)Bh[buf];
    u32x4_t* dl = (u32x4_t*)Bl[buf];
    #pragma unroll
    for (int i = 0; i < 2; i++) {
      int es = swz16(tid + i * 512);
      dh[es] = rbh[i]; dl[es] = rbl[i];
    }
  };

  loadB(0);   // in flight during the long gather

  // gather phase: 16 threads per row, 16 features each; per-feature edge order unchanged
  {
    int row = tid >> 4, seg = tid & 15;
    int n = n0 + row;
    float g[16];
    #pragma unroll
    for (int i = 0; i < 16; i++) g[i] = 0.f;
    int e0 = coff[n], e1 = coff[n + 1];
    for (int e = e0; e < e1; e++) {
      float w = csw[e];
      int s = csrc[e];
      const f32x4_t* px = (const f32x4_t*)(x_in + ((size_t)b * NN + s) * FF + seg * 16);
      #pragma unroll
      for (int i = 0; i < 4; i++) {
        f32x4_t v = px[i];
        g[4*i]   += w * v[0]; g[4*i+1] += w * v[1];
        g[4*i+2] += w * v[2]; g[4*i+3] += w * v[3];
      }
    }
    #pragma unroll
    for (int i = 0; i < 8; i++) {
      unsigned h, l;
      split_pk(g[2 * i], g[2 * i + 1], h, l);
      Ah[row][seg * 8 + i] = h;
      Al[row][seg * 8 + i] = l;
    }
  }
  writeB(0);
  __syncthreads();

  f32x4_t acc[2][2];
  #pragma unroll
  for (int i = 0; i < 2; i++)
    #pragma unroll
    for (int j = 0; j < 2; j++) { f32x4_t t = {0.f, 0.f, 0.f, 0.f}; acc[i][j] = t; }

  for (int kc = 0; kc < 8; kc++) {
    int cur = kc & 1;
    if (kc < 7) loadB(kc + 1);          // loads in flight under MFMA
    u32x4_t a0h = *(const u32x4_t*)&Ah[llo][kc * 16 + lhi * 4];
    u32x4_t a0l = *(const u32x4_t*)&Al[llo][kc * 16 + lhi * 4];
    u32x4_t a1h = *(const u32x4_t*)&Ah[llo + 16][kc * 16 + lhi * 4];
    u32x4_t a1l = *(const u32x4_t*)&Al[llo + 16][kc * 16 + lhi * 4];
    #pragma unroll
    for (int cb = 0; cb < 2; cb++) {
      int off = swz16((wv * 32 + cb * 16 + llo) * 4 + lhi) * 8;
      u32x4_t bh = *(const u32x4_t*)&Bh[cur][off];
      u32x4_t bl = *(const u32x4_t*)&Bl[cur][off];
      acc[0][cb] = mfma16(a0h, bh, mfma16(a0h, bl, mfma16(a0l, bh, acc[0][cb])));
      acc[1][cb] = mfma16(a1h, bh, mfma16(a1h, bl, mfma16(a1l, bh, acc[1][cb])));
    }
    if (kc < 7) writeB(cur ^ 1);
    __syncthreads();
  }

  // epilogue: + sposW + residual, then LayerNorm
  #pragma unroll
  for (int rb = 0; rb < 2; rb++)
    #pragma unroll
    for (int cb = 0; cb < 2; cb++) {
      int col = wv * 32 + cb * 16 + llo;
      #pragma unroll
      for (int r = 0; r < 4; r++) {
        int row = rb * 16 + lhi * 4 + r;
        float sw = sposW[(size_t)(n0 + row) * FF + col];
        float xr = x_in[((size_t)b * NN + n0 + row) * FF + col];
        acc[rb][cb][r] += sw + xr;
      }
    }
  float ps[2][4], pq[2][4];
  #pragma unroll
  for (int rb = 0; rb < 2; rb++)
    #pragma unroll
    for (int r = 0; r < 4; r++) {
      float s = 0.f, q = 0.f;
      #pragma unroll
      for (int cb = 0; cb < 2; cb++) { float y = acc[rb][cb][r]; s += y; q += y * y; }
      #pragma unroll
      for (int m = 1; m < 16; m <<= 1) { s += __shfl_xor(s, m); q += __shfl_xor(q, m); }
      ps[rb][r] = s; pq[rb][r] = q;
    }
  if (llo == 0) {
    #pragma unroll
    for (int rb = 0; rb < 2; rb++)
      #pragma unroll
      for (int r = 0; r < 4; r++) {
        int row = rb * 16 + lhi * 4 + r;
        redS[row][wv] = ps[rb][r];
        redQ[row][wv] = pq[rb][r];
      }
  }
  __syncthreads();
  float mrs[2][4][2];
  #pragma unroll
  for (int rb = 0; rb < 2; rb++)
    #pragma unroll
    for (int r = 0; r < 4; r++) {
      int row = rb * 16 + lhi * 4 + r;
      float S = 0.f, Q = 0.f;
      #pragma unroll
      for (int wq = 0; wq < 8; wq++) { S += redS[row][wq]; Q += redQ[row][wq]; }
      float mean = S * (1.f / 256.f);
      float var = Q * (1.f / 256.f) - mean * mean;
      mrs[rb][r][0] = mean;
      mrs[rb][r][1] = rsqrtf(var + 1e-5f);
    }
  #pragma unroll
  for (int cb = 0; cb < 2; cb++) {
    int col = wv * 32 + cb * 16 + llo;
    float gg = lng[col], bb = lnb[col];
    #pragma unroll
    for (int rb = 0; rb < 2; rb++)
      #pragma unroll
      for (int r = 0; r < 4; r++) {
        int row = rb * 16 + lhi * 4 + r;
        float o = (acc[rb][cb][r] - mrs[rb][r][0]) * mrs[rb][r][1] * gg + bb;
        if (!last) {
          x_out[((size_t)b * NN + n0 + row) * FF + col] = o;
        } else {
          size_t idx = (((size_t)b * 32 + nb) * 256 + col) * 32 + row;
          unsigned short hh = f2bf(o);
          xTh[idx] = hh;
          xTl[idx] = f2bf(o - ashf(hh));
        }
      }
  }
}

// ---------------- proj2 (single-buffer LDS + reg prefetch) ----------------
__global__ __launch_bounds__(256, 3) void k_proj2(const float* __restrict__ qxy,
    const float* __restrict__ mQ, const float* __restrict__ liQ,
    const float* __restrict__ npos, const unsigned short* __restrict__ xTh,
    const unsigned short* __restrict__ xTl, unsigned short* __restrict__ latTh,
    unsigned short* __restrict__ latTl) {
  __shared__ unsigned short BstH[8192];
  __shared__ unsigned short BstL[8192];
  __shared__ unsigned short AstH[1024];
  __shared__ unsigned short AstL[1024];
  __shared__ float nps[NN * 2];
  int tid = threadIdx.x;
  // XCD-aware: batch b pinned to one XCD so xT(b) stays in its L2
  int id = blockIdx.x;
  int b = id & 7;
  int q0b = id >> 3;             // 0..127
  int q0 = q0b * 32;
  int bt = b * 128 + q0b;
  int wv = tid >> 6, L = tid & 63, lhi = L >> 4, llo = L & 15;
  int aq = tid >> 3, t7 = tid & 7, an4 = t7 * 4;
  int aoff = swz16(aq * 4 + (t7 >> 1)) * 8 + (t7 & 1) * 4;

  {
    const f32x4_t* s4 = (const f32x4_t*)npos;
    *(f32x4_t*)&nps[tid * 4] = s4[tid];
    *(f32x4_t*)&nps[(tid + 256) * 4] = s4[tid + 256];
  }
  int qg = b * NP + q0 + aq;
  float2 qv = ((const float2*)qxy)[qg];
  float qm = mQ[qg], qli = liQ[qg];
  __syncthreads();

  u32x4_t rbh[4], rbl[4];
  unsigned ch0, ch1, cl0, cl1;

  auto coordA = [&](int kc) {
    int nb = kc * 32 + an4;
    float c[4];
    #pragma unroll
    for (int j = 0; j < 4; j++) {
      float nx = nps[(nb + j) * 2], ny = nps[(nb + j) * 2 + 1];
      float dx = qv.x - nx, dy = qv.y - ny;
      c[j] = __expf(-(dx * dx + dy * dy) - qm) * qli;
    }
    split_pk(c[0], c[1], ch0, cl0);
    split_pk(c[2], c[3], ch1, cl1);
  };
  auto loadB = [&](int kc) {
    const u32x4_t* sh = (const u32x4_t*)(xTh + (size_t)(b * 32 + kc) * 8192);
    const u32x4_t* sl = (const u32x4_t*)(xTl + (size_t)(b * 32 + kc) * 8192);
    #pragma unroll
    for (int i = 0; i < 4; i++) { rbh[i] = sh[tid + i * 256]; rbl[i] = sl[tid + i * 256]; }
  };

  f32x4_t acc[2][4];
  #pragma unroll
  for (int i = 0; i < 2; i++)
    #pragma unroll
    for (int j = 0; j < 4; j++) { f32x4_t t = {0.f, 0.f, 0.f, 0.f}; acc[i][j] = t; }

  coordA(0);
  loadB(0);
  int a0off = swz16(llo * 4 + lhi) * 8;
  int a1off = swz16((llo + 16) * 4 + lhi) * 8;
  for (int kc = 0; kc < 32; kc++) {
    __syncthreads();
    #pragma unroll
    for (int i = 0; i < 4; i++) {
      int es = swz16(tid + i * 256);
      ((u32x4_t*)BstH)[es] = rbh[i];
      ((u32x4_t*)BstL)[es] = rbl[i];
    }
    { u32x2_t wh = {ch0, ch1}; *(u32x2_t*)&AstH[aoff] = wh; }
    { u32x2_t wl = {cl0, cl1}; *(u32x2_t*)&AstL[aoff] = wl; }
    __syncthreads();
    if (kc < 31) { loadB(kc + 1); coordA(kc + 1); }
    u32x4_t a0h = *(const u32x4_t*)&AstH[a0off];
    u32x4_t a0l = *(const u32x4_t*)&AstL[a0off];
    u32x4_t a1h = *(const u32x4_t*)&AstH[a1off];
    u32x4_t a1l = *(const u32x4_t*)&AstL[a1off];
    #pragma unroll
    for (int cb = 0; cb < 4; cb++) {
      int off = swz16((wv * 64 + cb * 16 + llo) * 4 + lhi) * 8;
      u32x4_t bh = *(const u32x4_t*)&BstH[off];
      u32x4_t bl = *(const u32x4_t*)&BstL[off];
      acc[0][cb] = mfma16(a0h, bh, mfma16(a0h, bl, mfma16(a0l, bh, acc[0][cb])));
      acc[1][cb] = mfma16(a1h, bh, mfma16(a1h, bl, mfma16(a1l, bh, acc[1][cb])));
    }
  }
  #pragma unroll
  for (int rb = 0; rb < 2; rb++)
    #pragma unroll
    for (int cb = 0; cb < 4; cb++) {
      int col = wv * 64 + cb * 16 + llo;
      int fc = col >> 5, kk = col & 31;
      f32x4_t v = acc[rb][cb];
      #pragma unroll
      for (int r = 0; r < 4; r++) {
        size_t idx = ((size_t)bt * 8 + fc) * 1024 + (rb * 16 + lhi * 4 + r) * 32 + kk;
        unsigned short hh = f2bf(v[r]);
        latTh[idx] = hh;
        latTl[idx] = f2bf(v[r] - ashf(hh));
      }
    }
}

// ---------------- decoder (single-buffer LDS + reg prefetch) ----------------
__global__ __launch_bounds__(256, 4) void k_decoder(const unsigned short* __restrict__ latTh,
    const unsigned short* __restrict__ latTl, const float* __restrict__ qxy,
    const unsigned short* __restrict__ WTd1h, const unsigned short* __restrict__ WTd1l,
    const float* __restrict__ bd1, const float* __restrict__ Wd1,
    const float* __restrict__ Wd2, const float* __restrict__ bd2, float* __restrict__ out) {
  __shared__ unsigned short BstH[8192];
  __shared__ unsigned short BstL[8192];
  __shared__ unsigned short AstH[1024];
  __shared__ unsigned short AstL[1024];
  __shared__ float qs[32][2];
  __shared__ float red[4][32][3];
  int tid = threadIdx.x;
  int bt = blockIdx.x;
  int wv = tid >> 6, L = tid & 63, lhi = L >> 4, llo = L & 15;

  u32x4_t rbh[4], rbl[4], ra;
  auto loadB = [&](int kc) {
    const u32x4_t* sh = (const u32x4_t*)(WTd1h + (size_t)kc * 8192);
    const u32x4_t* sl = (const u32x4_t*)(WTd1l + (size_t)kc * 8192);
    #pragma unroll
    for (int i = 0; i < 4; i++) { rbh[i] = sh[tid + i * 256]; rbl[i] = sl[tid + i * 256]; }
  };
  auto loadA = [&](int kc) {
    if (tid < 128)
      ra = ((const u32x4_t*)(latTh + ((size_t)bt * 8 + kc) * 1024))[tid];
    else
      ra = ((const u32x4_t*)(latTl + ((size_t)bt * 8 + kc) * 1024))[tid - 128];
  };

  if (tid < 64) qs[tid >> 1][tid & 1] = qxy[((size_t)bt * 32 + (tid >> 1)) * 2 + (tid & 1)];
  loadB(0); loadA(0);
  __syncthreads();

  f32x4_t acc[2][4];
  #pragma unroll
  for (int cb = 0; cb < 4; cb++) {
    int col = wv * 64 + cb * 16 + llo;
    float wa = Wd1[256 * FF + col], wb = Wd1[257 * FF + col], bc = bd1[col];
    #pragma unroll
    for (int rb = 0; rb < 2; rb++) {
      f32x4_t t;
      #pragma unroll
      for (int r = 0; r < 4; r++) {
        int row = rb * 16 + lhi * 4 + r;
        t[r] = bc + qs[row][0] * wa + qs[row][1] * wb;
      }
      acc[rb][cb] = t;
    }
  }

  int a0off = swz16(llo * 4 + lhi) * 8;
  int a1off = swz16((llo + 16) * 4 + lhi) * 8;
  for (int kc = 0; kc < 8; kc++) {
    __syncthreads();
    #pragma unroll
    for (int i = 0; i < 4; i++) {
      int es = swz16(tid + i * 256);
      ((u32x4_t*)BstH)[es] = rbh[i];
      ((u32x4_t*)BstL)[es] = rbl[i];
    }
    if (tid < 128) ((u32x4_t*)AstH)[swz16(tid)] = ra;
    else ((u32x4_t*)AstL)[swz16(tid - 128)] = ra;
    __syncthreads();
    if (kc < 7) { loadB(kc + 1); loadA(kc + 1); }
    u32x4_t a0h = *(const u32x4_t*)&AstH[a0off];
    u32x4_t a0l = *(const u32x4_t*)&AstL[a0off];
    u32x4_t a1h = *(const u32x4_t*)&AstH[a1off];
    u32x4_t a1l = *(const u32x4_t*)&AstL[a1off];
    #pragma unroll
    for (int cb = 0; cb < 4; cb++) {
      int off = swz16((wv * 64 + cb * 16 + llo) * 4 + lhi) * 8;
      u32x4_t bh = *(const u32x4_t*)&BstH[off];
      u32x4_t bl = *(const u32x4_t*)&BstL[off];
      acc[0][cb] = mfma16(a0h, bh, mfma16(a0h, bl, mfma16(a0l, bh, acc[0][cb])));
      acc[1][cb] = mfma16(a1h, bh, mfma16(a1h, bl, mfma16(a1l, bh, acc[1][cb])));
    }
  }

  float po[2][4][3];
  #pragma unroll
  for (int rb = 0; rb < 2; rb++)
    #pragma unroll
    for (int r = 0; r < 4; r++) { po[rb][r][0] = 0.f; po[rb][r][1] = 0.f; po[rb][r][2] = 0.f; }
  #pragma unroll
  for (int rb = 0; rb < 2; rb++)
    #pragma unroll
    for (int cb = 0; cb < 4; cb++) {
      int col = wv * 64 + cb * 16 + llo;
      float w0 = Wd2[col * 3], w1 = Wd2[col * 3 + 1], w2 = Wd2[col * 3 + 2];
      f32x4_t v = acc[rb][cb];
      #pragma unroll
      for (int r = 0; r < 4; r++) {
        float hv = fmaxf(v[r], 0.f);
        po[rb][r][0] += hv * w0; po[rb][r][1] += hv * w1; po[rb][r][2] += hv * w2;
      }
    }
  #pragma unroll
  for (int o = 8; o; o >>= 1)
    #pragma unroll
    for (int rb = 0; rb < 2; rb++)
      #pragma unroll
      for (int r = 0; r < 4; r++) {
        po[rb][r][0] += __shfl_xor(po[rb][r][0], o);
        po[rb][r][1] += __shfl_xor(po[rb][r][1], o);
        po[rb][r][2] += __shfl_xor(po[rb][r][2], o);
      }
  if (llo == 0) {
    #pragma unroll
    for (int rb = 0; rb < 2; rb++)
      #pragma unroll
      for (int r = 0; r < 4; r++) {
        int row = rb * 16 + lhi * 4 + r;
        red[wv][row][0] = po[rb][r][0];
        red[wv][row][1] = po[rb][r][1];
        red[wv][row][2] = po[rb][r][2];
      }
  }
  __syncthreads();
  if (tid < 96) {
    int row = tid / 3, o = tid % 3;
    float s = red[0][row][o] + red[1][row][o] + red[2][row][o] + red[3][row][o] + bd2[o];
    out[((size_t)bt * 32 + row) * 3 + o] = s;
  }
}

extern "C" void kernel_launch(void* const* d_in, const int* in_sizes, int n_in,
                              void* d_out, int out_size, void* d_ws, size_t ws_size,
                              hipStream_t stream) {
  const float* inx = (const float*)d_in[0];
  const float* iny = (const float*)d_in[1];
  const float* qxy = (const float*)d_in[2];
  const float* npos = (const float*)d_in[3];
  const float* We1 = (const float*)d_in[4];
  const float* be1 = (const float*)d_in[5];
  const float* We2 = (const float*)d_in[6];
  const float* be2 = (const float*)d_in[7];
  const float* Wg  = (const float*)d_in[8];
  const float* bg  = (const float*)d_in[9];
  const float* lng = (const float*)d_in[10];
  const float* lnb = (const float*)d_in[11];
  const float* Wd1 = (const float*)d_in[12];
  const float* bd1 = (const float*)d_in[13];
  const float* Wd2 = (const float*)d_in[14];
  const float* bd2 = (const float*)d_in[15];
  const int* eidx  = (const int*)d_in[16];
  float* out = (float*)d_out;

  char* w = (char*)d_ws;
  auto carve = [&](size_t n) { char* p = w; w += (n + 255) & ~(size_t)255; return p; };
  char* encR = carve((size_t)2 * BB * NP * FF * 2);                          // 32 MB
  unsigned short* encTh = (unsigned short*)encR;
  unsigned short* encTl = (unsigned short*)(encR + (size_t)BB * NP * FF * 2);
  unsigned short* latTh = encTh;   // alias (dead after proj1)
  unsigned short* latTl = encTl;
  float* xA = (float*)carve((size_t)BB * NN * FF * 4);                       // 8 MB
  float* xB = (float*)carve((size_t)BB * NN * FF * 4);                       // 8 MB
  unsigned short* xTh = (unsigned short*)carve((size_t)BB * NN * FF * 2);    // 4 MB
  unsigned short* xTl = (unsigned short*)carve((size_t)BB * NN * FF * 2);    // 4 MB
  float* part = (float*)carve((size_t)4 * BB * NN * FF * 4);                 // 32 MB
  float* mI   = (float*)carve((size_t)BB * NP * 4);
  float* liI  = (float*)carve((size_t)BB * NP * 4);
  float* mQ   = (float*)carve((size_t)BB * NP * 4);
  float* liQ  = (float*)carve((size_t)BB * NP * 4);
  unsigned short* WTe2h = (unsigned short*)carve((size_t)8 * 256 * 32 * 2);
  unsigned short* WTe2l = (unsigned short*)carve((size_t)8 * 256 * 32 * 2);
  unsigned short* WTgh  = (unsigned short*)carve((size_t)8 * 256 * 32 * 2);
  unsigned short* WTgl  = (unsigned short*)carve((size_t)8 * 256 * 32 * 2);
  unsigned short* WTd1h = (unsigned short*)carve((size_t)8 * 256 * 32 * 2);
  unsigned short* WTd1l = (unsigned short*)carve((size_t)8 * 256 * 32 * 2);
  float* sposW = (float*)carve((size_t)NN * FF * 4);
  float* dinv = (float*)carve(NN * 4);
  float* spos = (float*)carve(NN * 2 * 4);
  float* csw  = (float*)carve((NE + NN) * 4);
  int* coff   = (int*)carve((NN + 1) * 4);
  int* csrc   = (int*)carve((NE + NN) * 4);
  int* cntg   = (int*)carve((size_t)NSEG * NN * 4);

  const int* esrc = eidx;
  const int* edst = eidx + NE;

  k_cnt<<<dim3(NSEG), dim3(1024), 0, stream>>>(edst, cntg);
  k_scan2<<<dim3(1), dim3(1024), 0, stream>>>(cntg, dinv, coff);
  k_fill2<<<dim3(NSEG + 1), dim3(1024), 0, stream>>>(esrc, edst, dinv, coff, cntg, csrc, csw);
  k_spos<<<dim3(4), dim3(256), 0, stream>>>(npos, coff, csrc, csw, spos);
  k_posb<<<dim3(NN), dim3(256), 0, stream>>>(spos, Wg, bg, sposW);
  k_pack_w<<<dim3(8, 3), dim3(256), 0, stream>>>(We2, Wg, Wd1, WTe2h, WTe2l, WTgh, WTgl,
                                                 WTd1h, WTd1l);

  k_stats<<<dim3(BB * NP / 4, 2), dim3(256), 0, stream>>>(inx, qxy, npos, mI, liI, mQ, liQ);
  k_encoder<<<dim3(BB * NP / 32), dim3(256), 0, stream>>>(inx, iny, We1, be1, WTe2h, WTe2l, be2,
                                                          encTh, encTl);
  k_proj1<<<dim3(1024), dim3(256), 0, stream>>>(inx, mI, liI, npos, encTh, encTl, part);
  k_reduce<<<dim3(BB * NN * FF / 1024), dim3(256), 0, stream>>>(part, xA);
  for (int s = 0; s < NSTEP; s++) {
    const float* xi = (s & 1) ? xB : xA;
    float* xo = (s & 1) ? xA : xB;
    k_msg2<<<dim3(256), dim3(512), 0, stream>>>(xi, xo, sposW, coff, csrc, csw,
                                                WTgh, WTgl, lng, lnb,
                                                (s == NSTEP - 1) ? 1 : 0, xTh, xTl);
  }
  k_proj2<<<dim3(1024), dim3(256), 0, stream>>>(qxy, mQ, liQ, npos, xTh, xTl, latTh, latTl);
  k_decoder<<<dim3(BB * NP / 32), dim3(256), 0, stream>>>(latTh, latTl, qxy, WTd1h, WTd1l,
                                                          bd1, Wd1, Wd2, bd2, out);
}

// Round 10
// 547.683 us; speedup vs baseline: 3.3859x; 1.0247x over previous
//
#include <hip/hip_runtime.h>

#define BB 8
#define NP 4096    // NPTS == NQ
#define NN 1024
#define NE 8192
#define FF 256
#define TS 264
#define NSTEP 16
#define NSEG 64
#define SEGSZ 128  // NSEG*SEGSZ == NE

typedef float f32x4_t __attribute__((ext_vector_type(4)));
typedef __bf16 bf16x8_t __attribute__((ext_vector_type(8)));
typedef unsigned int u32x4_t __attribute__((ext_vector_type(4)));
typedef unsigned int u32x2_t __attribute__((ext_vector_type(2)));

// hardware RNE f32->bf16; bit-identical to SW round-to-nearest-even on normals
static __device__ __forceinline__ unsigned short f2bf(float f) {
  return __builtin_bit_cast(unsigned short, static_cast<__bf16>(f));
}
static __device__ __forceinline__ float ashf(unsigned short s) {
  union { unsigned u; float f; } t; t.u = (unsigned)s << 16; return t.f;
}
// split a,b into hi/lo bf16 pairs packed as u32
static __device__ __forceinline__ void split_pk(float a, float b, unsigned& h, unsigned& l) {
  unsigned short ha = f2bf(a), hb = f2bf(b);
  unsigned short la = f2bf(a - ashf(ha)), lb = f2bf(b - ashf(hb));
  h = (unsigned)ha | ((unsigned)hb << 16);
  l = (unsigned)la | ((unsigned)lb << 16);
}
static __device__ __forceinline__ f32x4_t mfma16(u32x4_t a, u32x4_t b, f32x4_t c) {
  return __builtin_amdgcn_mfma_f32_16x16x32_bf16(
      __builtin_bit_cast(bf16x8_t, a), __builtin_bit_cast(bf16x8_t, b), c, 0, 0, 0);
}
// 16B-entry XOR swizzle: spreads 64-byte fragment rows over all 32 LDS banks
static __device__ __forceinline__ int swz16(int e) { return e ^ ((e >> 3) & 7); }

// ---------------- graph preprocessing (segmented, deterministic) ----------------
__global__ __launch_bounds__(1024) void k_cnt(const int* __restrict__ dstA,
                                              int* __restrict__ cntg) {
  __shared__ int ds[SEGSZ];
  int seg = blockIdx.x, n = threadIdx.x;
  if (n < SEGSZ) ds[n] = dstA[seg * SEGSZ + n];
  __syncthreads();
  int c = 0;
  #pragma unroll 8
  for (int e = 0; e < SEGSZ; e++) c += (ds[e] == n) ? 1 : 0;
  cntg[seg * NN + n] = c;
}

__global__ __launch_bounds__(1024) void k_scan2(const int* __restrict__ cntg,
    float* __restrict__ dinv, int* __restrict__ csr_off) {
  __shared__ int s[NN];
  int n = threadIdx.x;
  int c = 1;
  for (int sg = 0; sg < NSEG; sg++) c += cntg[sg * NN + n];
  dinv[n] = rsqrtf((float)c);
  s[n] = c;
  __syncthreads();
  for (int st = 1; st < NN; st <<= 1) {
    int v = (n >= st) ? s[n - st] : 0;
    __syncthreads();
    s[n] += v;
    __syncthreads();
  }
  csr_off[n] = s[n] - c;
  if (n == NN - 1) csr_off[NN] = s[n];
}

__global__ __launch_bounds__(1024) void k_fill2(const int* __restrict__ srcA,
    const int* __restrict__ dstA, const float* __restrict__ dinv,
    const int* __restrict__ csr_off, const int* __restrict__ cntg,
    int* __restrict__ csr_src, float* __restrict__ csr_w) {
  int n = threadIdx.x;
  if (blockIdx.x == NSEG) {
    int pos = csr_off[n + 1] - 1;               // self loop last
    csr_src[pos] = n;
    csr_w[pos] = dinv[n] * dinv[n];
    return;
  }
  __shared__ int ds[SEGSZ], ss[SEGSZ];
  int seg = blockIdx.x;
  if (n < SEGSZ) { ds[n] = dstA[seg * SEGSZ + n]; ss[n] = srcA[seg * SEGSZ + n]; }
  __syncthreads();
  int base = csr_off[n];
  for (int s2 = 0; s2 < seg; s2++) base += cntg[s2 * NN + n];
  float dn = dinv[n];
  for (int e = 0; e < SEGSZ; e++) {
    if (ds[e] == n) {
      int sv = ss[e];
      csr_src[base] = sv;
      csr_w[base] = dinv[sv] * dn;
      base++;
    }
  }
}

__global__ __launch_bounds__(256) void k_spos(const float* __restrict__ npos,
    const int* __restrict__ csr_off, const int* __restrict__ csr_src,
    const float* __restrict__ csr_w, float* __restrict__ spos) {
  int n = blockIdx.x * 256 + threadIdx.x;
  if (n >= NN) return;
  float sx = 0.f, sy = 0.f;
  int e1 = csr_off[n + 1];
  for (int e = csr_off[n]; e < e1; e++) {
    float w = csr_w[e]; int s = csr_src[e];
    sx += w * npos[2 * s]; sy += w * npos[2 * s + 1];
  }
  spos[2 * n] = sx; spos[2 * n + 1] = sy;
}

__global__ __launch_bounds__(256) void k_posb(const float* __restrict__ spos,
    const float* __restrict__ Wg, const float* __restrict__ bg, float* __restrict__ sposW) {
  int n = blockIdx.x, f = threadIdx.x;
  sposW[(size_t)n * FF + f] = spos[2 * n] * Wg[f] + spos[2 * n + 1] * Wg[FF + f] + bg[f];
}

// ---------------- softmax stats (inputs and queries in one launch) ----------------
__global__ __launch_bounds__(256) void k_stats(const float* __restrict__ inx,
    const float* __restrict__ qxy, const float* __restrict__ npos,
    float* __restrict__ mI, float* __restrict__ liI,
    float* __restrict__ mQ, float* __restrict__ liQ) {
  const float* xy = blockIdx.y ? qxy : inx;
  float* mOut = blockIdx.y ? mQ : mI;
  float* liOut = blockIdx.y ? liQ : liI;
  int wv = threadIdx.x >> 6, lane = threadIdx.x & 63;
  int pt = blockIdx.x * 4 + wv;
  float px = xy[pt * 2], py = xy[pt * 2 + 1];
  float s[16];
  float m = -1e30f;
  #pragma unroll
  for (int k = 0; k < 16; k++) {
    int n = lane + 64 * k;
    float2 np = ((const float2*)npos)[n];
    float dx = px - np.x, dy = py - np.y;
    float v = -(dx * dx + dy * dy);
    s[k] = v; m = fmaxf(m, v);
  }
  #pragma unroll
  for (int o = 32; o; o >>= 1) m = fmaxf(m, __shfl_xor(m, o));
  float l = 0.f;
  #pragma unroll
  for (int k = 0; k < 16; k++) l += __expf(s[k] - m);
  #pragma unroll
  for (int o = 32; o; o >>= 1) l += __shfl_xor(l, o);
  if (lane == 0) { mOut[pt] = m; liOut[pt] = 1.0f / l; }
}

// ---------------- weight prepack: WT[kc][n][kk] bf16 hi+lo ----------------
__global__ __launch_bounds__(256) void k_pack_w(const float* __restrict__ We2,
    const float* __restrict__ Wg, const float* __restrict__ Wd1,
    unsigned short* __restrict__ WTe2h, unsigned short* __restrict__ WTe2l,
    unsigned short* __restrict__ WTgh, unsigned short* __restrict__ WTgl,
    unsigned short* __restrict__ WTd1h, unsigned short* __restrict__ WTd1l) {
  int kc = blockIdx.x, which = blockIdx.y, n = threadIdx.x;
  const float* W = (which == 0) ? We2 : (which == 1) ? (Wg + 2 * FF) : Wd1;
  unsigned short* Dh = (which == 0) ? WTe2h : (which == 1) ? WTgh : WTd1h;
  unsigned short* Dl = (which == 0) ? WTe2l : (which == 1) ? WTgl : WTd1l;
  unsigned hu[16], lu[16];
  #pragma unroll
  for (int i = 0; i < 16; i++) {
    float a = W[(kc * 32 + 2 * i) * FF + n];
    float b = W[(kc * 32 + 2 * i + 1) * FF + n];
    split_pk(a, b, hu[i], lu[i]);
  }
  u32x4_t* dvh = (u32x4_t*)(Dh + ((size_t)kc * 256 + n) * 32);
  u32x4_t* dvl = (u32x4_t*)(Dl + ((size_t)kc * 256 + n) * 32);
  #pragma unroll
  for (int i = 0; i < 4; i++) {
    u32x4_t th = {hu[4 * i], hu[4 * i + 1], hu[4 * i + 2], hu[4 * i + 3]};
    u32x4_t tl = {lu[4 * i], lu[4 * i + 1], lu[4 * i + 2], lu[4 * i + 3]};
    dvh[i] = th; dvl[i] = tl;
  }
}

// ---------------- encoder: L1 fp32 VALU, L2 split-MFMA; writes encT hi+lo ----------------
__global__ __launch_bounds__(256) void k_encoder(const float* __restrict__ inx,
    const float* __restrict__ iny, const float* __restrict__ We1,
    const float* __restrict__ be1, const unsigned short* __restrict__ WTe2h,
    const unsigned short* __restrict__ WTe2l, const float* __restrict__ be2,
    unsigned short* __restrict__ encTh, unsigned short* __restrict__ encTl) {
  __shared__ float xin[32][8];
  __shared__ float h[32][TS];
  __shared__ unsigned short Bh[8192];
  __shared__ unsigned short Bl[8192];
  int tid = threadIdx.x;
  int row0 = blockIdx.x * 32;
  int wv = tid >> 6, L = tid & 63, lhi = L >> 4, llo = L & 15;

  if (tid < 160) {
    int pt = tid / 5, d = tid % 5;
    int r = row0 + pt;
    xin[pt][d] = (d < 2) ? inx[r * 2 + d] : iny[r * 3 + (d - 2)];
  }
  __syncthreads();
  {
    int f = tid;
    float w0 = We1[f], w1 = We1[256 + f], w2 = We1[512 + f], w3 = We1[768 + f], w4 = We1[1024 + f];
    float bb = be1[f];
    #pragma unroll 4
    for (int pt = 0; pt < 32; pt++) {
      float v = bb + xin[pt][0]*w0 + xin[pt][1]*w1 + xin[pt][2]*w2 + xin[pt][3]*w3 + xin[pt][4]*w4;
      h[pt][f] = fmaxf(v, 0.f);
    }
  }

  f32x4_t acc[2][4];
  #pragma unroll
  for (int cb = 0; cb < 4; cb++) {
    float bc = be2[wv * 64 + cb * 16 + llo];
    f32x4_t t = {bc, bc, bc, bc};
    acc[0][cb] = t; acc[1][cb] = t;
  }

  for (int kc = 0; kc < 8; kc++) {
    __syncthreads();
    {
      const u32x4_t* sh = (const u32x4_t*)(WTe2h + (size_t)kc * 8192);
      const u32x4_t* sl = (const u32x4_t*)(WTe2l + (size_t)kc * 8192);
      u32x4_t* dh = (u32x4_t*)Bh;
      u32x4_t* dl = (u32x4_t*)Bl;
      #pragma unroll
      for (int i = 0; i < 4; i++) {
        int e = tid + i * 256;
        int es = swz16(e);
        dh[es] = sh[e]; dl[es] = sl[e];
      }
    }
    __syncthreads();
    int kbase = kc * 32 + lhi * 8;
    u32x4_t a0h, a0l, a1h, a1l;
    {
      float p[8];
      *(f32x4_t*)p = *(const f32x4_t*)&h[llo][kbase];
      *(f32x4_t*)(p + 4) = *(const f32x4_t*)&h[llo][kbase + 4];
      unsigned hw[4], lw[4];
      #pragma unroll
      for (int i = 0; i < 4; i++) split_pk(p[2 * i], p[2 * i + 1], hw[i], lw[i]);
      u32x4_t th = {hw[0], hw[1], hw[2], hw[3]}; a0h = th;
      u32x4_t tl = {lw[0], lw[1], lw[2], lw[3]}; a0l = tl;
    }
    {
      float p[8];
      *(f32x4_t*)p = *(const f32x4_t*)&h[llo + 16][kbase];
      *(f32x4_t*)(p + 4) = *(const f32x4_t*)&h[llo + 16][kbase + 4];
      unsigned hw[4], lw[4];
      #pragma unroll
      for (int i = 0; i < 4; i++) split_pk(p[2 * i], p[2 * i + 1], hw[i], lw[i]);
      u32x4_t th = {hw[0], hw[1], hw[2], hw[3]}; a1h = th;
      u32x4_t tl = {lw[0], lw[1], lw[2], lw[3]}; a1l = tl;
    }
    #pragma unroll
    for (int cb = 0; cb < 4; cb++) {
      int col = wv * 64 + cb * 16 + llo;
      int off = swz16(col * 4 + lhi) * 8;
      u32x4_t bh = *(const u32x4_t*)&Bh[off];
      u32x4_t bl = *(const u32x4_t*)&Bl[off];
      acc[0][cb] = mfma16(a0h, bh, mfma16(a0h, bl, mfma16(a0l, bh, acc[0][cb])));
      acc[1][cb] = mfma16(a1h, bh, mfma16(a1h, bl, mfma16(a1l, bh, acc[1][cb])));
    }
  }
  #pragma unroll
  for (int rb = 0; rb < 2; rb++)
    #pragma unroll
    for (int cb = 0; cb < 4; cb++) {
      int col = wv * 64 + cb * 16 + llo;
      f32x4_t v = acc[rb][cb];
      size_t idx = ((size_t)blockIdx.x * 256 + col) * 32 + rb * 16 + lhi * 4;
      unsigned hw0, lw0, hw1, lw1;
      split_pk(v[0], v[1], hw0, lw0);
      split_pk(v[2], v[3], hw1, lw1);
      u32x2_t wh = {hw0, hw1}; *(u32x2_t*)&encTh[idx] = wh;
      u32x2_t wl = {lw0, lw1}; *(u32x2_t*)&encTl[idx] = wl;
    }
}

// ---------------- proj1 (split-K, 64-row tile, single-buffer LDS + reg prefetch) ----------------
__global__ __launch_bounds__(256, 3) void k_proj1(const float* __restrict__ inx,
    const float* __restrict__ mI, const float* __restrict__ liI,
    const float* __restrict__ npos, const unsigned short* __restrict__ encTh,
    const unsigned short* __restrict__ encTl, float* __restrict__ part) {
  __shared__ unsigned short BstH[8192];
  __shared__ unsigned short BstL[8192];
  __shared__ unsigned short AstH[2048];
  __shared__ unsigned short AstL[2048];
  int tid = threadIdx.x;
  // XCD-aware decode: each XCD owns 4 (b,z)-slices; 16 n-blocks (of 64) per slice stay local
  int id = blockIdx.x;
  int xcd = id & 7, kid = id >> 3;
  int slice = xcd * 4 + (kid >> 4);
  int n0 = (kid & 15) * 64;
  int b = slice >> 2, z = slice & 3;
  int wv = tid >> 6, L = tid & 63, lhi = L >> 4, llo = L & 15;
  int an = tid >> 2, t3 = tid & 3, ap = t3 * 8;
  float2 npv = ((const float2*)npos)[n0 + an];
  int pbase0 = b * NP + z * 1024;
  int aoff = swz16(an * 4 + t3) * 8;

  u32x4_t rbh[4], rbl[4], chv, clv;

  auto coordA = [&](int kc) {
    int p = pbase0 + kc * 32 + ap;
    float c[8];
    #pragma unroll
    for (int j = 0; j < 8; j++) {
      float2 pxy = ((const float2*)inx)[p + j];
      float mm = mI[p + j], ll = liI[p + j];
      float dx = pxy.x - npv.x, dy = pxy.y - npv.y;
      c[j] = __expf(-(dx * dx + dy * dy) - mm) * ll;
    }
    unsigned h[4], l[4];
    #pragma unroll
    for (int j = 0; j < 4; j++) split_pk(c[2 * j], c[2 * j + 1], h[j], l[j]);
    u32x4_t th = {h[0], h[1], h[2], h[3]}; chv = th;
    u32x4_t tl = {l[0], l[1], l[2], l[3]}; clv = tl;
  };
  auto loadB = [&](int kc) {
    const u32x4_t* sh = (const u32x4_t*)(encTh + (size_t)(b * 128 + z * 32 + kc) * 8192);
    const u32x4_t* sl = (const u32x4_t*)(encTl + (size_t)(b * 128 + z * 32 + kc) * 8192);
    #pragma unroll
    for (int i = 0; i < 4; i++) { rbh[i] = sh[tid + i * 256]; rbl[i] = sl[tid + i * 256]; }
  };

  f32x4_t acc[4][4];
  #pragma unroll
  for (int i = 0; i < 4; i++)
    #pragma unroll
    for (int j = 0; j < 4; j++) { f32x4_t t = {0.f, 0.f, 0.f, 0.f}; acc[i][j] = t; }

  coordA(0);
  loadB(0);
  int aroff[4];
  #pragma unroll
  for (int rb = 0; rb < 4; rb++) aroff[rb] = swz16((llo + 16 * rb) * 4 + lhi) * 8;
  for (int kc = 0; kc < 32; kc++) {
    __syncthreads();                       // previous compute done reading LDS
    #pragma unroll
    for (int i = 0; i < 4; i++) {
      int es = swz16(tid + i * 256);
      ((u32x4_t*)BstH)[es] = rbh[i];
      ((u32x4_t*)BstL)[es] = rbl[i];
    }
    *(u32x4_t*)&AstH[aoff] = chv;
    *(u32x4_t*)&AstL[aoff] = clv;
    __syncthreads();
    if (kc < 31) { loadB(kc + 1); coordA(kc + 1); }   // in flight / co-issue during MFMA
    u32x4_t ah[4], al[4];
    #pragma unroll
    for (int rb = 0; rb < 4; rb++) {
      ah[rb] = *(const u32x4_t*)&AstH[aroff[rb]];
      al[rb] = *(const u32x4_t*)&AstL[aroff[rb]];
    }
    #pragma unroll
    for (int cb = 0; cb < 4; cb++) {
      int off = swz16((wv * 64 + cb * 16 + llo) * 4 + lhi) * 8;
      u32x4_t bh = *(const u32x4_t*)&BstH[off];
      u32x4_t bl = *(const u32x4_t*)&BstL[off];
      #pragma unroll
      for (int rb = 0; rb < 4; rb++)
        acc[rb][cb] = mfma16(ah[rb], bh, mfma16(ah[rb], bl, mfma16(al[rb], bh, acc[rb][cb])));
    }
  }
  float* op = part + (((size_t)(z * BB + b)) * NN + n0) * FF;
  #pragma unroll
  for (int rb = 0; rb < 4; rb++)
    #pragma unroll
    for (int cb = 0; cb < 4; cb++) {
      int col = wv * 64 + cb * 16 + llo;
      f32x4_t v = acc[rb][cb];
      #pragma unroll
      for (int r = 0; r < 4; r++) op[(rb * 16 + lhi * 4 + r) * FF + col] = v[r];
    }
}

// reduce split-K parts -> x (fp32)
__global__ __launch_bounds__(256) void k_reduce(const float* __restrict__ part,
                                                float* __restrict__ x) {
  size_t i = ((size_t)blockIdx.x * 256 + threadIdx.x) * 4;
  const size_t S = (size_t)BB * NN * FF;
  f32x4_t a = *(const f32x4_t*)&part[i];
  f32x4_t b = *(const f32x4_t*)&part[S + i];
  f32x4_t c = *(const f32x4_t*)&part[2 * S + i];
  f32x4_t d = *(const f32x4_t*)&part[3 * S + i];
  f32x4_t r = (a + b) + (c + d);
  *(f32x4_t*)&x[i] = r;
}

// ---------------- fused msg step (512 thr, reg-staged LDS dbuf, 1 barrier/kc) ----------------
__global__ __launch_bounds__(512) void k_msg2(const float* __restrict__ x_in,
    float* __restrict__ x_out, const float* __restrict__ sposW,
    const int* __restrict__ coff, const int* __restrict__ csrc,
    const float* __restrict__ csw, const unsigned short* __restrict__ WTgh,
    const unsigned short* __restrict__ WTgl, const float* __restrict__ lng,
    const float* __restrict__ lnb, int last,
    unsigned short* __restrict__ xTh, unsigned short* __restrict__ xTl) {
  __shared__ unsigned Ah[32][132];
  __shared__ unsigned Al[32][132];
  __shared__ unsigned short Bh[2][8192];
  __shared__ unsigned short Bl[2][8192];
  __shared__ float redS[32][8];
  __shared__ float redQ[32][8];
  int tid = threadIdx.x;
  // XCD-aware: batch b pinned to one XCD so x(b) stays in its L2
  int id = blockIdx.x;
  int b = id & 7;
  int nb = id >> 3;
  int n0 = nb * 32;
  int wv = tid >> 6, L = tid & 63, lhi = L >> 4, llo = L & 15;

  u32x4_t rbh[2], rbl[2];
  auto loadB = [&](int kc) {
    const u32x4_t* sh = (const u32x4_t*)(WTgh + (size_t)kc * 8192);
    const u32x4_t* sl = (const u32x4_t*)(WTgl + (size_t)kc * 8192);
    #pragma unroll
    for (int i = 0; i < 2; i++) { rbh[i] = sh[tid + i * 512]; rbl[i] = sl[tid + i * 512]; }
  };
  auto writeB = [&](int buf) {
    u32x4_t* dh = (u32x4_t*)Bh[buf];
    u32x4_t* dl = (u32x4_t*)Bl[buf];
    #pragma unroll
    for (int i = 0; i < 2; i++) {
      int es = swz16(tid + i * 512);
      dh[es] = rbh[i]; dl[es] = rbl[i];
    }
  };

  loadB(0);   // in flight during the long gather

  // gather phase: 16 threads per row, 16 features each; per-feature edge order unchanged
  {
    int row = tid >> 4, seg = tid & 15;
    int n = n0 + row;
    float g[16];
    #pragma unroll
    for (int i = 0; i < 16; i++) g[i] = 0.f;
    int e0 = coff[n], e1 = coff[n + 1];
    for (int e = e0; e < e1; e++) {
      float w = csw[e];
      int s = csrc[e];
      const f32x4_t* px = (const f32x4_t*)(x_in + ((size_t)b * NN + s) * FF + seg * 16);
      #pragma unroll
      for (int i = 0; i < 4; i++) {
        f32x4_t v = px[i];
        g[4*i]   += w * v[0]; g[4*i+1] += w * v[1];
        g[4*i+2] += w * v[2]; g[4*i+3] += w * v[3];
      }
    }
    #pragma unroll
    for (int i = 0; i < 8; i++) {
      unsigned h, l;
      split_pk(g[2 * i], g[2 * i + 1], h, l);
      Ah[row][seg * 8 + i] = h;
      Al[row][seg * 8 + i] = l;
    }
  }
  writeB(0);

  // preload residual + sposW sums (hidden under GEMM loop)
  f32x4_t szr[2][2];
  #pragma unroll
  for (int rb = 0; rb < 2; rb++)
    #pragma unroll
    for (int cb = 0; cb < 2; cb++) {
      int col = wv * 32 + cb * 16 + llo;
      #pragma unroll
      for (int r = 0; r < 4; r++) {
        int row = rb * 16 + lhi * 4 + r;
        szr[rb][cb][r] = sposW[(size_t)(n0 + row) * FF + col]
                       + x_in[((size_t)b * NN + n0 + row) * FF + col];
      }
    }
  __syncthreads();

  f32x4_t acc[2][2];
  #pragma unroll
  for (int i = 0; i < 2; i++)
    #pragma unroll
    for (int j = 0; j < 2; j++) { f32x4_t t = {0.f, 0.f, 0.f, 0.f}; acc[i][j] = t; }

  for (int kc = 0; kc < 8; kc++) {
    int cur = kc & 1;
    if (kc < 7) loadB(kc + 1);          // loads in flight under MFMA
    u32x4_t a0h = *(const u32x4_t*)&Ah[llo][kc * 16 + lhi * 4];
    u32x4_t a0l = *(const u32x4_t*)&Al[llo][kc * 16 + lhi * 4];
    u32x4_t a1h = *(const u32x4_t*)&Ah[llo + 16][kc * 16 + lhi * 4];
    u32x4_t a1l = *(const u32x4_t*)&Al[llo + 16][kc * 16 + lhi * 4];
    #pragma unroll
    for (int cb = 0; cb < 2; cb++) {
      int off = swz16((wv * 32 + cb * 16 + llo) * 4 + lhi) * 8;
      u32x4_t bh = *(const u32x4_t*)&Bh[cur][off];
      u32x4_t bl = *(const u32x4_t*)&Bl[cur][off];
      acc[0][cb] = mfma16(a0h, bh, mfma16(a0h, bl, mfma16(a0l, bh, acc[0][cb])));
      acc[1][cb] = mfma16(a1h, bh, mfma16(a1h, bl, mfma16(a1l, bh, acc[1][cb])));
    }
    if (kc < 7) writeB(cur ^ 1);
    __syncthreads();
  }

  // epilogue: + (sposW + residual), then LayerNorm
  #pragma unroll
  for (int rb = 0; rb < 2; rb++)
    #pragma unroll
    for (int cb = 0; cb < 2; cb++) {
      #pragma unroll
      for (int r = 0; r < 4; r++) acc[rb][cb][r] += szr[rb][cb][r];
    }
  float ps[2][4], pq[2][4];
  #pragma unroll
  for (int rb = 0; rb < 2; rb++)
    #pragma unroll
    for (int r = 0; r < 4; r++) {
      float s = 0.f, q = 0.f;
      #pragma unroll
      for (int cb = 0; cb < 2; cb++) { float y = acc[rb][cb][r]; s += y; q += y * y; }
      #pragma unroll
      for (int m = 1; m < 16; m <<= 1) { s += __shfl_xor(s, m); q += __shfl_xor(q, m); }
      ps[rb][r] = s; pq[rb][r] = q;
    }
  if (llo == 0) {
    #pragma unroll
    for (int rb = 0; rb < 2; rb++)
      #pragma unroll
      for (int r = 0; r < 4; r++) {
        int row = rb * 16 + lhi * 4 + r;
        redS[row][wv] = ps[rb][r];
        redQ[row][wv] = pq[rb][r];
      }
  }
  __syncthreads();
  float mrs[2][4][2];
  #pragma unroll
  for (int rb = 0; rb < 2; rb++)
    #pragma unroll
    for (int r = 0; r < 4; r++) {
      int row = rb * 16 + lhi * 4 + r;
      float S = 0.f, Q = 0.f;
      #pragma unroll
      for (int wq = 0; wq < 8; wq++) { S += redS[row][wq]; Q += redQ[row][wq]; }
      float mean = S * (1.f / 256.f);
      float var = Q * (1.f / 256.f) - mean * mean;
      mrs[rb][r][0] = mean;
      mrs[rb][r][1] = rsqrtf(var + 1e-5f);
    }
  #pragma unroll
  for (int cb = 0; cb < 2; cb++) {
    int col = wv * 32 + cb * 16 + llo;
    float gg = lng[col], bb = lnb[col];
    #pragma unroll
    for (int rb = 0; rb < 2; rb++)
      #pragma unroll
      for (int r = 0; r < 4; r++) {
        int row = rb * 16 + lhi * 4 + r;
        float o = (acc[rb][cb][r] - mrs[rb][r][0]) * mrs[rb][r][1] * gg + bb;
        if (!last) {
          x_out[((size_t)b * NN + n0 + row) * FF + col] = o;
        } else {
          size_t idx = (((size_t)b * 32 + nb) * 256 + col) * 32 + row;
          unsigned short hh = f2bf(o);
          xTh[idx] = hh;
          xTl[idx] = f2bf(o - ashf(hh));
        }
      }
  }
}

// ---------------- proj2 (64-row tile, single-buffer LDS + reg prefetch) ----------------
__global__ __launch_bounds__(256, 3) void k_proj2(const float* __restrict__ qxy,
    const float* __restrict__ mQ, const float* __restrict__ liQ,
    const float* __restrict__ npos, const unsigned short* __restrict__ xTh,
    const unsigned short* __restrict__ xTl, unsigned short* __restrict__ latTh,
    unsigned short* __restrict__ latTl) {
  __shared__ unsigned short BstH[8192];
  __shared__ unsigned short BstL[8192];
  __shared__ unsigned short AstH[2048];
  __shared__ unsigned short AstL[2048];
  __shared__ float nps[NN * 2];
  int tid = threadIdx.x;
  // XCD-aware: batch b pinned to one XCD so xT(b) stays in its L2
  int id = blockIdx.x;
  int b = id & 7;
  int q64 = id >> 3;             // 0..63 (64-row block)
  int q0 = q64 * 64;
  int wv = tid >> 6, L = tid & 63, lhi = L >> 4, llo = L & 15;
  int aq = tid >> 2, t3 = tid & 3, an8 = t3 * 8;
  int aoff = swz16(aq * 4 + t3) * 8;

  {
    const f32x4_t* s4 = (const f32x4_t*)npos;
    *(f32x4_t*)&nps[tid * 4] = s4[tid];
    *(f32x4_t*)&nps[(tid + 256) * 4] = s4[tid + 256];
  }
  int qg = b * NP + q0 + aq;
  float2 qv = ((const float2*)qxy)[qg];
  float qm = mQ[qg], qli = liQ[qg];
  __syncthreads();

  u32x4_t rbh[4], rbl[4], chv, clv;

  auto coordA = [&](int kc) {
    int nb = kc * 32 + an8;
    float c[8];
    #pragma unroll
    for (int j = 0; j < 8; j++) {
      float nx = nps[(nb + j) * 2], ny = nps[(nb + j) * 2 + 1];
      float dx = qv.x - nx, dy = qv.y - ny;
      c[j] = __expf(-(dx * dx + dy * dy) - qm) * qli;
    }
    unsigned h[4], l[4];
    #pragma unroll
    for (int j = 0; j < 4; j++) split_pk(c[2 * j], c[2 * j + 1], h[j], l[j]);
    u32x4_t th = {h[0], h[1], h[2], h[3]}; chv = th;
    u32x4_t tl = {l[0], l[1], l[2], l[3]}; clv = tl;
  };
  auto loadB = [&](int kc) {
    const u32x4_t* sh = (const u32x4_t*)(xTh + (size_t)(b * 32 + kc) * 8192);
    const u32x4_t* sl = (const u32x4_t*)(xTl + (size_t)(b * 32 + kc) * 8192);
    #pragma unroll
    for (int i = 0; i < 4; i++) { rbh[i] = sh[tid + i * 256]; rbl[i] = sl[tid + i * 256]; }
  };

  f32x4_t acc[4][4];
  #pragma unroll
  for (int i = 0; i < 4; i++)
    #pragma unroll
    for (int j = 0; j < 4; j++) { f32x4_t t = {0.f, 0.f, 0.f, 0.f}; acc[i][j] = t; }

  coordA(0);
  loadB(0);
  int aroff[4];
  #pragma unroll
  for (int rb = 0; rb < 4; rb++) aroff[rb] = swz16((llo + 16 * rb) * 4 + lhi) * 8;
  for (int kc = 0; kc < 32; kc++) {
    __syncthreads();
    #pragma unroll
    for (int i = 0; i < 4; i++) {
      int es = swz16(tid + i * 256);
      ((u32x4_t*)BstH)[es] = rbh[i];
      ((u32x4_t*)BstL)[es] = rbl[i];
    }
    *(u32x4_t*)&AstH[aoff] = chv;
    *(u32x4_t*)&AstL[aoff] = clv;
    __syncthreads();
    if (kc < 31) { loadB(kc + 1); coordA(kc + 1); }
    u32x4_t ah[4], al[4];
    #pragma unroll
    for (int rb = 0; rb < 4; rb++) {
      ah[rb] = *(const u32x4_t*)&AstH[aroff[rb]];
      al[rb] = *(const u32x4_t*)&AstL[aroff[rb]];
    }
    #pragma unroll
    for (int cb = 0; cb < 4; cb++) {
      int off = swz16((wv * 64 + cb * 16 + llo) * 4 + lhi) * 8;
      u32x4_t bh = *(const u32x4_t*)&BstH[off];
      u32x4_t bl = *(const u32x4_t*)&BstL[off];
      #pragma unroll
      for (int rb = 0; rb < 4; rb++)
        acc[rb][cb] = mfma16(ah[rb], bh, mfma16(ah[rb], bl, mfma16(al[rb], bh, acc[rb][cb])));
    }
  }
  #pragma unroll
  for (int rb = 0; rb < 4; rb++)
    #pragma unroll
    for (int cb = 0; cb < 4; cb++) {
      int col = wv * 64 + cb * 16 + llo;
      int fc = col >> 5, kk = col & 31;
      f32x4_t v = acc[rb][cb];
      #pragma unroll
      for (int r = 0; r < 4; r++) {
        int row = rb * 16 + lhi * 4 + r;                 // 0..63
        int bt = b * 128 + q64 * 2 + (row >> 5);
        size_t idx = ((size_t)bt * 8 + fc) * 1024 + (row & 31) * 32 + kk;
        unsigned short hh = f2bf(v[r]);
        latTh[idx] = hh;
        latTl[idx] = f2bf(v[r] - ashf(hh));
      }
    }
}

// ---------------- decoder (single-buffer LDS + reg prefetch) ----------------
__global__ __launch_bounds__(256, 4) void k_decoder(const unsigned short* __restrict__ latTh,
    const unsigned short* __restrict__ latTl, const float* __restrict__ qxy,
    const unsigned short* __restrict__ WTd1h, const unsigned short* __restrict__ WTd1l,
    const float* __restrict__ bd1, const float* __restrict__ Wd1,
    const float* __restrict__ Wd2, const float* __restrict__ bd2, float* __restrict__ out) {
  __shared__ unsigned short BstH[8192];
  __shared__ unsigned short BstL[8192];
  __shared__ unsigned short AstH[1024];
  __shared__ unsigned short AstL[1024];
  __shared__ float qs[32][2];
  __shared__ float red[4][32][3];
  int tid = threadIdx.x;
  int bt = blockIdx.x;
  int wv = tid >> 6, L = tid & 63, lhi = L >> 4, llo = L & 15;

  u32x4_t rbh[4], rbl[4], ra;
  auto loadB = [&](int kc) {
    const u32x4_t* sh = (const u32x4_t*)(WTd1h + (size_t)kc * 8192);
    const u32x4_t* sl = (const u32x4_t*)(WTd1l + (size_t)kc * 8192);
    #pragma unroll
    for (int i = 0; i < 4; i++) { rbh[i] = sh[tid + i * 256]; rbl[i] = sl[tid + i * 256]; }
  };
  auto loadA = [&](int kc) {
    if (tid < 128)
      ra = ((const u32x4_t*)(latTh + ((size_t)bt * 8 + kc) * 1024))[tid];
    else
      ra = ((const u32x4_t*)(latTl + ((size_t)bt * 8 + kc) * 1024))[tid - 128];
  };

  if (tid < 64) qs[tid >> 1][tid & 1] = qxy[((size_t)bt * 32 + (tid >> 1)) * 2 + (tid & 1)];
  loadB(0); loadA(0);
  __syncthreads();

  f32x4_t acc[2][4];
  #pragma unroll
  for (int cb = 0; cb < 4; cb++) {
    int col = wv * 64 + cb * 16 + llo;
    float wa = Wd1[256 * FF + col], wb = Wd1[257 * FF + col], bc = bd1[col];
    #pragma unroll
    for (int rb = 0; rb < 2; rb++) {
      f32x4_t t;
      #pragma unroll
      for (int r = 0; r < 4; r++) {
        int row = rb * 16 + lhi * 4 + r;
        t[r] = bc + qs[row][0] * wa + qs[row][1] * wb;
      }
      acc[rb][cb] = t;
    }
  }

  int a0off = swz16(llo * 4 + lhi) * 8;
  int a1off = swz16((llo + 16) * 4 + lhi) * 8;
  for (int kc = 0; kc < 8; kc++) {
    __syncthreads();
    #pragma unroll
    for (int i = 0; i < 4; i++) {
      int es = swz16(tid + i * 256);
      ((u32x4_t*)BstH)[es] = rbh[i];
      ((u32x4_t*)BstL)[es] = rbl[i];
    }
    if (tid < 128) ((u32x4_t*)AstH)[swz16(tid)] = ra;
    else ((u32x4_t*)AstL)[swz16(tid - 128)] = ra;
    __syncthreads();
    if (kc < 7) { loadB(kc + 1); loadA(kc + 1); }
    u32x4_t a0h = *(const u32x4_t*)&AstH[a0off];
    u32x4_t a0l = *(const u32x4_t*)&AstL[a0off];
    u32x4_t a1h = *(const u32x4_t*)&AstH[a1off];
    u32x4_t a1l = *(const u32x4_t*)&AstL[a1off];
    #pragma unroll
    for (int cb = 0; cb < 4; cb++) {
      int off = swz16((wv * 64 + cb * 16 + llo) * 4 + lhi) * 8;
      u32x4_t bh = *(const u32x4_t*)&BstH[off];
      u32x4_t bl = *(const u32x4_t*)&BstL[off];
      acc[0][cb] = mfma16(a0h, bh, mfma16(a0h, bl, mfma16(a0l, bh, acc[0][cb])));
      acc[1][cb] = mfma16(a1h, bh, mfma16(a1h, bl, mfma16(a1l, bh, acc[1][cb])));
    }
  }

  float po[2][4][3];
  #pragma unroll
  for (int rb = 0; rb < 2; rb++)
    #pragma unroll
    for (int r = 0; r < 4; r++) { po[rb][r][0] = 0.f; po[rb][r][1] = 0.f; po[rb][r][2] = 0.f; }
  #pragma unroll
  for (int rb = 0; rb < 2; rb++)
    #pragma unroll
    for (int cb = 0; cb < 4; cb++) {
      int col = wv * 64 + cb * 16 + llo;
      float w0 = Wd2[col * 3], w1 = Wd2[col * 3 + 1], w2 = Wd2[col * 3 + 2];
      f32x4_t v = acc[rb][cb];
      #pragma unroll
      for (int r = 0; r < 4; r++) {
        float hv = fmaxf(v[r], 0.f);
        po[rb][r][0] += hv * w0; po[rb][r][1] += hv * w1; po[rb][r][2] += hv * w2;
      }
    }
  #pragma unroll
  for (int o = 8; o; o >>= 1)
    #pragma unroll
    for (int rb = 0; rb < 2; rb++)
      #pragma unroll
      for (int r = 0; r < 4; r++) {
        po[rb][r][0] += __shfl_xor(po[rb][r][0], o);
        po[rb][r][1] += __shfl_xor(po[rb][r][1], o);
        po[rb][r][2] += __shfl_xor(po[rb][r][2], o);
      }
  if (llo == 0) {
    #pragma unroll
    for (int rb = 0; rb < 2; rb++)
      #pragma unroll
      for (int r = 0; r < 4; r++) {
        int row = rb * 16 + lhi * 4 + r;
        red[wv][row][0] = po[rb][r][0];
        red[wv][row][1] = po[rb][r][1];
        red[wv][row][2] = po[rb][r][2];
      }
  }
  __syncthreads();
  if (tid < 96) {
    int row = tid / 3, o = tid % 3;
    float s = red[0][row][o] + red[1][row][o] + red[2][row][o] + red[3][row][o] + bd2[o];
    out[((size_t)bt * 32 + row) * 3 + o] = s;
  }
}

extern "C" void kernel_launch(void* const* d_in, const int* in_sizes, int n_in,
                              void* d_out, int out_size, void* d_ws, size_t ws_size,
                              hipStream_t stream) {
  const float* inx = (const float*)d_in[0];
  const float* iny = (const float*)d_in[1];
  const float* qxy = (const float*)d_in[2];
  const float* npos = (const float*)d_in[3];
  const float* We1 = (const float*)d_in[4];
  const float* be1 = (const float*)d_in[5];
  const float* We2 = (const float*)d_in[6];
  const float* be2 = (const float*)d_in[7];
  const float* Wg  = (const float*)d_in[8];
  const float* bg  = (const float*)d_in[9];
  const float* lng = (const float*)d_in[10];
  const float* lnb = (const float*)d_in[11];
  const float* Wd1 = (const float*)d_in[12];
  const float* bd1 = (const float*)d_in[13];
  const float* Wd2 = (const float*)d_in[14];
  const float* bd2 = (const float*)d_in[15];
  const int* eidx  = (const int*)d_in[16];
  float* out = (float*)d_out;

  char* w = (char*)d_ws;
  auto carve = [&](size_t n) { char* p = w; w += (n + 255) & ~(size_t)255; return p; };
  char* encR = carve((size_t)2 * BB * NP * FF * 2);                          // 32 MB
  unsigned short* encTh = (unsigned short*)encR;
  unsigned short* encTl = (unsigned short*)(encR + (size_t)BB * NP * FF * 2);
  unsigned short* latTh = encTh;   // alias (dead after proj1)
  unsigned short* latTl = encTl;
  float* xA = (float*)carve((size_t)BB * NN * FF * 4);                       // 8 MB
  float* xB = (float*)carve((size_t)BB * NN * FF * 4);                       // 8 MB
  unsigned short* xTh = (unsigned short*)carve((size_t)BB * NN * FF * 2);    // 4 MB
  unsigned short* xTl = (unsigned short*)carve((size_t)BB * NN * FF * 2);    // 4 MB
  float* part = (float*)carve((size_t)4 * BB * NN * FF * 4);                 // 32 MB
  float* mI   = (float*)carve((size_t)BB * NP * 4);
  float* liI  = (float*)carve((size_t)BB * NP * 4);
  float* mQ   = (float*)carve((size_t)BB * NP * 4);
  float* liQ  = (float*)carve((size_t)BB * NP * 4);
  unsigned short* WTe2h = (unsigned short*)carve((size_t)8 * 256 * 32 * 2);
  unsigned short* WTe2l = (unsigned short*)carve((size_t)8 * 256 * 32 * 2);
  unsigned short* WTgh  = (unsigned short*)carve((size_t)8 * 256 * 32 * 2);
  unsigned short* WTgl  = (unsigned short*)carve((size_t)8 * 256 * 32 * 2);
  unsigned short* WTd1h = (unsigned short*)carve((size_t)8 * 256 * 32 * 2);
  unsigned short* WTd1l = (unsigned short*)carve((size_t)8 * 256 * 32 * 2);
  float* sposW = (float*)carve((size_t)NN * FF * 4);
  float* dinv = (float*)carve(NN * 4);
  float* spos = (float*)carve(NN * 2 * 4);
  float* csw  = (float*)carve((NE + NN) * 4);
  int* coff   = (int*)carve((NN + 1) * 4);
  int* csrc   = (int*)carve((NE + NN) * 4);
  int* cntg   = (int*)carve((size_t)NSEG * NN * 4);

  const int* esrc = eidx;
  const int* edst = eidx + NE;

  k_cnt<<<dim3(NSEG), dim3(1024), 0, stream>>>(edst, cntg);
  k_scan2<<<dim3(1), dim3(1024), 0, stream>>>(cntg, dinv, coff);
  k_fill2<<<dim3(NSEG + 1), dim3(1024), 0, stream>>>(esrc, edst, dinv, coff, cntg, csrc, csw);
  k_spos<<<dim3(4), dim3(256), 0, stream>>>(npos, coff, csrc, csw, spos);
  k_posb<<<dim3(NN), dim3(256), 0, stream>>>(spos, Wg, bg, sposW);
  k_pack_w<<<dim3(8, 3), dim3(256), 0, stream>>>(We2, Wg, Wd1, WTe2h, WTe2l, WTgh, WTgl,
                                                 WTd1h, WTd1l);

  k_stats<<<dim3(BB * NP / 4, 2), dim3(256), 0, stream>>>(inx, qxy, npos, mI, liI, mQ, liQ);
  k_encoder<<<dim3(BB * NP / 32), dim3(256), 0, stream>>>(inx, iny, We1, be1, WTe2h, WTe2l, be2,
                                                          encTh, encTl);
  k_proj1<<<dim3(512), dim3(256), 0, stream>>>(inx, mI, liI, npos, encTh, encTl, part);
  k_reduce<<<dim3(BB * NN * FF / 1024), dim3(256), 0, stream>>>(part, xA);
  for (int s = 0; s < NSTEP; s++) {
    const float* xi = (s & 1) ? xB : xA;
    float* xo = (s & 1) ? xA : xB;
    k_msg2<<<dim3(256), dim3(512), 0, stream>>>(xi, xo, sposW, coff, csrc, csw,
                                                WTgh, WTgl, lng, lnb,
                                                (s == NSTEP - 1) ? 1 : 0, xTh, xTl);
  }
  k_proj2<<<dim3(512), dim3(256), 0, stream>>>(qxy, mQ, liQ, npos, xTh, xTl, latTh, latTl);
  k_decoder<<<dim3(BB * NP / 32), dim3(256), 0, stream>>>(latTh, latTl, qxy, WTd1h, WTd1l,
                                                          bd1, Wd1, Wd2, bd2, out);
}

// Round 11
// 533.771 us; speedup vs baseline: 3.4741x; 1.0261x over previous
//
#include <hip/hip_runtime.h>

#define BB 8
#define NP 4096    // NPTS == NQ
#define NN 1024
#define NE 8192
#define FF 256
#define TS 264
#define NSTEP 16
#define NSEG 64
#define SEGSZ 128  // NSEG*SEGSZ == NE
#define EMAX 1536  // per-block staged CSR records (mean ~288)

typedef float f32x4_t __attribute__((ext_vector_type(4)));
typedef __bf16 bf16x8_t __attribute__((ext_vector_type(8)));
typedef unsigned int u32x4_t __attribute__((ext_vector_type(4)));
typedef unsigned int u32x2_t __attribute__((ext_vector_type(2)));

// hardware RNE f32->bf16; bit-identical to SW round-to-nearest-even on normals
static __device__ __forceinline__ unsigned short f2bf(float f) {
  return __builtin_bit_cast(unsigned short, static_cast<__bf16>(f));
}
static __device__ __forceinline__ float ashf(unsigned short s) {
  union { unsigned u; float f; } t; t.u = (unsigned)s << 16; return t.f;
}
// split a,b into hi/lo bf16 pairs packed as u32
static __device__ __forceinline__ void split_pk(float a, float b, unsigned& h, unsigned& l) {
  unsigned short ha = f2bf(a), hb = f2bf(b);
  unsigned short la = f2bf(a - ashf(ha)), lb = f2bf(b - ashf(hb));
  h = (unsigned)ha | ((unsigned)hb << 16);
  l = (unsigned)la | ((unsigned)lb << 16);
}
static __device__ __forceinline__ f32x4_t mfma16(u32x4_t a, u32x4_t b, f32x4_t c) {
  return __builtin_amdgcn_mfma_f32_16x16x32_bf16(
      __builtin_bit_cast(bf16x8_t, a), __builtin_bit_cast(bf16x8_t, b), c, 0, 0, 0);
}
// 16B-entry XOR swizzle: spreads 64-byte fragment rows over all 32 LDS banks
static __device__ __forceinline__ int swz16(int e) { return e ^ ((e >> 3) & 7); }

// ---------------- graph preprocessing (segmented, deterministic) ----------------
__global__ __launch_bounds__(1024) void k_cnt(const int* __restrict__ dstA,
                                              int* __restrict__ cntg) {
  __shared__ int ds[SEGSZ];
  int seg = blockIdx.x, n = threadIdx.x;
  if (n < SEGSZ) ds[n] = dstA[seg * SEGSZ + n];
  __syncthreads();
  int c = 0;
  #pragma unroll 8
  for (int e = 0; e < SEGSZ; e++) c += (ds[e] == n) ? 1 : 0;
  cntg[seg * NN + n] = c;
}

__global__ __launch_bounds__(1024) void k_scan2(const int* __restrict__ cntg,
    float* __restrict__ dinv, int* __restrict__ csr_off) {
  __shared__ int s[NN];
  int n = threadIdx.x;
  int c = 1;
  for (int sg = 0; sg < NSEG; sg++) c += cntg[sg * NN + n];
  dinv[n] = rsqrtf((float)c);
  s[n] = c;
  __syncthreads();
  for (int st = 1; st < NN; st <<= 1) {
    int v = (n >= st) ? s[n - st] : 0;
    __syncthreads();
    s[n] += v;
    __syncthreads();
  }
  csr_off[n] = s[n] - c;
  if (n == NN - 1) csr_off[NN] = s[n];
}

__global__ __launch_bounds__(1024) void k_fill2(const int* __restrict__ srcA,
    const int* __restrict__ dstA, const float* __restrict__ dinv,
    const int* __restrict__ csr_off, const int* __restrict__ cntg,
    int* __restrict__ csr_src, float* __restrict__ csr_w) {
  int n = threadIdx.x;
  if (blockIdx.x == NSEG) {
    int pos = csr_off[n + 1] - 1;               // self loop last
    csr_src[pos] = n;
    csr_w[pos] = dinv[n] * dinv[n];
    return;
  }
  __shared__ int ds[SEGSZ], ss[SEGSZ];
  int seg = blockIdx.x;
  if (n < SEGSZ) { ds[n] = dstA[seg * SEGSZ + n]; ss[n] = srcA[seg * SEGSZ + n]; }
  __syncthreads();
  int base = csr_off[n];
  for (int s2 = 0; s2 < seg; s2++) base += cntg[s2 * NN + n];
  float dn = dinv[n];
  for (int e = 0; e < SEGSZ; e++) {
    if (ds[e] == n) {
      int sv = ss[e];
      csr_src[base] = sv;
      csr_w[base] = dinv[sv] * dn;
      base++;
    }
  }
}

__global__ __launch_bounds__(256) void k_spos(const float* __restrict__ npos,
    const int* __restrict__ csr_off, const int* __restrict__ csr_src,
    const float* __restrict__ csr_w, float* __restrict__ spos) {
  int n = blockIdx.x * 256 + threadIdx.x;
  if (n >= NN) return;
  float sx = 0.f, sy = 0.f;
  int e1 = csr_off[n + 1];
  for (int e = csr_off[n]; e < e1; e++) {
    float w = csr_w[e]; int s = csr_src[e];
    sx += w * npos[2 * s]; sy += w * npos[2 * s + 1];
  }
  spos[2 * n] = sx; spos[2 * n + 1] = sy;
}

__global__ __launch_bounds__(256) void k_posb(const float* __restrict__ spos,
    const float* __restrict__ Wg, const float* __restrict__ bg, float* __restrict__ sposW) {
  int n = blockIdx.x, f = threadIdx.x;
  sposW[(size_t)n * FF + f] = spos[2 * n] * Wg[f] + spos[2 * n + 1] * Wg[FF + f] + bg[f];
}

// ---------------- softmax stats (inputs and queries in one launch) ----------------
__global__ __launch_bounds__(256) void k_stats(const float* __restrict__ inx,
    const float* __restrict__ qxy, const float* __restrict__ npos,
    float* __restrict__ mI, float* __restrict__ liI,
    float* __restrict__ mQ, float* __restrict__ liQ) {
  const float* xy = blockIdx.y ? qxy : inx;
  float* mOut = blockIdx.y ? mQ : mI;
  float* liOut = blockIdx.y ? liQ : liI;
  int wv = threadIdx.x >> 6, lane = threadIdx.x & 63;
  int pt = blockIdx.x * 4 + wv;
  float px = xy[pt * 2], py = xy[pt * 2 + 1];
  float s[16];
  float m = -1e30f;
  #pragma unroll
  for (int k = 0; k < 16; k++) {
    int n = lane + 64 * k;
    float2 np = ((const float2*)npos)[n];
    float dx = px - np.x, dy = py - np.y;
    float v = -(dx * dx + dy * dy);
    s[k] = v; m = fmaxf(m, v);
  }
  #pragma unroll
  for (int o = 32; o; o >>= 1) m = fmaxf(m, __shfl_xor(m, o));
  float l = 0.f;
  #pragma unroll
  for (int k = 0; k < 16; k++) l += __expf(s[k] - m);
  #pragma unroll
  for (int o = 32; o; o >>= 1) l += __shfl_xor(l, o);
  if (lane == 0) { mOut[pt] = m; liOut[pt] = 1.0f / l; }
}

// ---------------- weight prepack: WT[kc][n][kk] bf16 hi+lo ----------------
__global__ __launch_bounds__(256) void k_pack_w(const float* __restrict__ We2,
    const float* __restrict__ Wg, const float* __restrict__ Wd1,
    unsigned short* __restrict__ WTe2h, unsigned short* __restrict__ WTe2l,
    unsigned short* __restrict__ WTgh, unsigned short* __restrict__ WTgl,
    unsigned short* __restrict__ WTd1h, unsigned short* __restrict__ WTd1l) {
  int kc = blockIdx.x, which = blockIdx.y, n = threadIdx.x;
  const float* W = (which == 0) ? We2 : (which == 1) ? (Wg + 2 * FF) : Wd1;
  unsigned short* Dh = (which == 0) ? WTe2h : (which == 1) ? WTgh : WTd1h;
  unsigned short* Dl = (which == 0) ? WTe2l : (which == 1) ? WTgl : WTd1l;
  unsigned hu[16], lu[16];
  #pragma unroll
  for (int i = 0; i < 16; i++) {
    float a = W[(kc * 32 + 2 * i) * FF + n];
    float b = W[(kc * 32 + 2 * i + 1) * FF + n];
    split_pk(a, b, hu[i], lu[i]);
  }
  u32x4_t* dvh = (u32x4_t*)(Dh + ((size_t)kc * 256 + n) * 32);
  u32x4_t* dvl = (u32x4_t*)(Dl + ((size_t)kc * 256 + n) * 32);
  #pragma unroll
  for (int i = 0; i < 4; i++) {
    u32x4_t th = {hu[4 * i], hu[4 * i + 1], hu[4 * i + 2], hu[4 * i + 3]};
    u32x4_t tl = {lu[4 * i], lu[4 * i + 1], lu[4 * i + 2], lu[4 * i + 3]};
    dvh[i] = th; dvl[i] = tl;
  }
}

// ---------------- encoder: L1 fp32 VALU, L2 split-MFMA; writes encT hi+lo ----------------
__global__ __launch_bounds__(256) void k_encoder(const float* __restrict__ inx,
    const float* __restrict__ iny, const float* __restrict__ We1,
    const float* __restrict__ be1, const unsigned short* __restrict__ WTe2h,
    const unsigned short* __restrict__ WTe2l, const float* __restrict__ be2,
    unsigned short* __restrict__ encTh, unsigned short* __restrict__ encTl) {
  __shared__ float xin[32][8];
  __shared__ float h[32][TS];
  __shared__ unsigned short Bh[8192];
  __shared__ unsigned short Bl[8192];
  int tid = threadIdx.x;
  int row0 = blockIdx.x * 32;
  int wv = tid >> 6, L = tid & 63, lhi = L >> 4, llo = L & 15;

  if (tid < 160) {
    int pt = tid / 5, d = tid % 5;
    int r = row0 + pt;
    xin[pt][d] = (d < 2) ? inx[r * 2 + d] : iny[r * 3 + (d - 2)];
  }
  __syncthreads();
  {
    int f = tid;
    float w0 = We1[f], w1 = We1[256 + f], w2 = We1[512 + f], w3 = We1[768 + f], w4 = We1[1024 + f];
    float bb = be1[f];
    #pragma unroll 4
    for (int pt = 0; pt < 32; pt++) {
      float v = bb + xin[pt][0]*w0 + xin[pt][1]*w1 + xin[pt][2]*w2 + xin[pt][3]*w3 + xin[pt][4]*w4;
      h[pt][f] = fmaxf(v, 0.f);
    }
  }

  f32x4_t acc[2][4];
  #pragma unroll
  for (int cb = 0; cb < 4; cb++) {
    float bc = be2[wv * 64 + cb * 16 + llo];
    f32x4_t t = {bc, bc, bc, bc};
    acc[0][cb] = t; acc[1][cb] = t;
  }

  for (int kc = 0; kc < 8; kc++) {
    __syncthreads();
    {
      const u32x4_t* sh = (const u32x4_t*)(WTe2h + (size_t)kc * 8192);
      const u32x4_t* sl = (const u32x4_t*)(WTe2l + (size_t)kc * 8192);
      u32x4_t* dh = (u32x4_t*)Bh;
      u32x4_t* dl = (u32x4_t*)Bl;
      #pragma unroll
      for (int i = 0; i < 4; i++) {
        int e = tid + i * 256;
        int es = swz16(e);
        dh[es] = sh[e]; dl[es] = sl[e];
      }
    }
    __syncthreads();
    int kbase = kc * 32 + lhi * 8;
    u32x4_t a0h, a0l, a1h, a1l;
    {
      float p[8];
      *(f32x4_t*)p = *(const f32x4_t*)&h[llo][kbase];
      *(f32x4_t*)(p + 4) = *(const f32x4_t*)&h[llo][kbase + 4];
      unsigned hw[4], lw[4];
      #pragma unroll
      for (int i = 0; i < 4; i++) split_pk(p[2 * i], p[2 * i + 1], hw[i], lw[i]);
      u32x4_t th = {hw[0], hw[1], hw[2], hw[3]}; a0h = th;
      u32x4_t tl = {lw[0], lw[1], lw[2], lw[3]}; a0l = tl;
    }
    {
      float p[8];
      *(f32x4_t*)p = *(const f32x4_t*)&h[llo + 16][kbase];
      *(f32x4_t*)(p + 4) = *(const f32x4_t*)&h[llo + 16][kbase + 4];
      unsigned hw[4], lw[4];
      #pragma unroll
      for (int i = 0; i < 4; i++) split_pk(p[2 * i], p[2 * i + 1], hw[i], lw[i]);
      u32x4_t th = {hw[0], hw[1], hw[2], hw[3]}; a1h = th;
      u32x4_t tl = {lw[0], lw[1], lw[2], lw[3]}; a1l = tl;
    }
    #pragma unroll
    for (int cb = 0; cb < 4; cb++) {
      int col = wv * 64 + cb * 16 + llo;
      int off = swz16(col * 4 + lhi) * 8;
      u32x4_t bh = *(const u32x4_t*)&Bh[off];
      u32x4_t bl = *(const u32x4_t*)&Bl[off];
      acc[0][cb] = mfma16(a0h, bh, mfma16(a0h, bl, mfma16(a0l, bh, acc[0][cb])));
      acc[1][cb] = mfma16(a1h, bh, mfma16(a1h, bl, mfma16(a1l, bh, acc[1][cb])));
    }
  }
  #pragma unroll
  for (int rb = 0; rb < 2; rb++)
    #pragma unroll
    for (int cb = 0; cb < 4; cb++) {
      int col = wv * 64 + cb * 16 + llo;
      f32x4_t v = acc[rb][cb];
      size_t idx = ((size_t)blockIdx.x * 256 + col) * 32 + rb * 16 + lhi * 4;
      unsigned hw0, lw0, hw1, lw1;
      split_pk(v[0], v[1], hw0, lw0);
      split_pk(v[2], v[3], hw1, lw1);
      u32x2_t wh = {hw0, hw1}; *(u32x2_t*)&encTh[idx] = wh;
      u32x2_t wl = {lw0, lw1}; *(u32x2_t*)&encTl[idx] = wl;
    }
}

// ---------------- proj1 (split-K, 32-row tile, single-buffer LDS + reg prefetch) ----------------
__global__ __launch_bounds__(256, 4) void k_proj1(const float* __restrict__ inx,
    const float* __restrict__ mI, const float* __restrict__ liI,
    const float* __restrict__ npos, const unsigned short* __restrict__ encTh,
    const unsigned short* __restrict__ encTl, float* __restrict__ part) {
  __shared__ unsigned short BstH[8192];
  __shared__ unsigned short BstL[8192];
  __shared__ unsigned short AstH[1024];
  __shared__ unsigned short AstL[1024];
  int tid = threadIdx.x;
  // XCD-aware decode: each XCD owns 4 (b,z)-slices; 32 n-blocks per slice stay local
  int id = blockIdx.x;
  int xcd = id & 7, kid = id >> 3;
  int slice = xcd * 4 + (kid >> 5);
  int n0 = (kid & 31) * 32;
  int b = slice >> 2, z = slice & 3;
  int wv = tid >> 6, L = tid & 63, lhi = L >> 4, llo = L & 15;
  int an = tid >> 3, t7 = tid & 7, ap = t7 * 4;
  float2 npv = ((const float2*)npos)[n0 + an];
  int pbase0 = b * NP + z * 1024;
  int aoff = swz16(an * 4 + (t7 >> 1)) * 8 + (t7 & 1) * 4;

  u32x4_t rbh[4], rbl[4];
  unsigned ch0, ch1, cl0, cl1;

  auto coordA = [&](int kc) {
    int p = pbase0 + kc * 32 + ap;
    float c[4];
    #pragma unroll
    for (int j = 0; j < 4; j++) {
      float2 pxy = ((const float2*)inx)[p + j];
      float mm = mI[p + j], ll = liI[p + j];
      float dx = pxy.x - npv.x, dy = pxy.y - npv.y;
      c[j] = __expf(-(dx * dx + dy * dy) - mm) * ll;
    }
    split_pk(c[0], c[1], ch0, cl0);
    split_pk(c[2], c[3], ch1, cl1);
  };
  auto loadB = [&](int kc) {
    const u32x4_t* sh = (const u32x4_t*)(encTh + (size_t)(b * 128 + z * 32 + kc) * 8192);
    const u32x4_t* sl = (const u32x4_t*)(encTl + (size_t)(b * 128 + z * 32 + kc) * 8192);
    #pragma unroll
    for (int i = 0; i < 4; i++) { rbh[i] = sh[tid + i * 256]; rbl[i] = sl[tid + i * 256]; }
  };

  f32x4_t acc[2][4];
  #pragma unroll
  for (int i = 0; i < 2; i++)
    #pragma unroll
    for (int j = 0; j < 4; j++) { f32x4_t t = {0.f, 0.f, 0.f, 0.f}; acc[i][j] = t; }

  coordA(0);
  loadB(0);
  int a0off = swz16(llo * 4 + lhi) * 8;
  int a1off = swz16((llo + 16) * 4 + lhi) * 8;
  for (int kc = 0; kc < 32; kc++) {
    __syncthreads();                       // previous compute done reading LDS
    #pragma unroll
    for (int i = 0; i < 4; i++) {
      int es = swz16(tid + i * 256);
      ((u32x4_t*)BstH)[es] = rbh[i];
      ((u32x4_t*)BstL)[es] = rbl[i];
    }
    { u32x2_t wh = {ch0, ch1}; *(u32x2_t*)&AstH[aoff] = wh; }
    { u32x2_t wl = {cl0, cl1}; *(u32x2_t*)&AstL[aoff] = wl; }
    __syncthreads();
    if (kc < 31) { loadB(kc + 1); coordA(kc + 1); }   // in flight / co-issue during MFMA
    u32x4_t a0h = *(const u32x4_t*)&AstH[a0off];
    u32x4_t a0l = *(const u32x4_t*)&AstL[a0off];
    u32x4_t a1h = *(const u32x4_t*)&AstH[a1off];
    u32x4_t a1l = *(const u32x4_t*)&AstL[a1off];
    #pragma unroll
    for (int cb = 0; cb < 4; cb++) {
      int off = swz16((wv * 64 + cb * 16 + llo) * 4 + lhi) * 8;
      u32x4_t bh = *(const u32x4_t*)&BstH[off];
      u32x4_t bl = *(const u32x4_t*)&BstL[off];
      acc[0][cb] = mfma16(a0h, bh, mfma16(a0h, bl, mfma16(a0l, bh, acc[0][cb])));
      acc[1][cb] = mfma16(a1h, bh, mfma16(a1h, bl, mfma16(a1l, bh, acc[1][cb])));
    }
  }
  float* op = part + (((size_t)(z * BB + b)) * NN + n0) * FF;
  #pragma unroll
  for (int rb = 0; rb < 2; rb++)
    #pragma unroll
    for (int cb = 0; cb < 4; cb++) {
      int col = wv * 64 + cb * 16 + llo;
      f32x4_t v = acc[rb][cb];
      #pragma unroll
      for (int r = 0; r < 4; r++) op[(rb * 16 + lhi * 4 + r) * FF + col] = v[r];
    }
}

// reduce split-K parts -> x (fp32)
__global__ __launch_bounds__(256) void k_reduce(const float* __restrict__ part,
                                                float* __restrict__ x) {
  size_t i = ((size_t)blockIdx.x * 256 + threadIdx.x) * 4;
  const size_t S = (size_t)BB * NN * FF;
  f32x4_t a = *(const f32x4_t*)&part[i];
  f32x4_t b = *(const f32x4_t*)&part[S + i];
  f32x4_t c = *(const f32x4_t*)&part[2 * S + i];
  f32x4_t d = *(const f32x4_t*)&part[3 * S + i];
  f32x4_t r = (a + b) + (c + d);
  *(f32x4_t*)&x[i] = r;
}

// ---------------- fused msg step (512 thr, LDS edge staging, reg-staged dbuf) ----------------
__global__ __launch_bounds__(512) void k_msg2(const float* __restrict__ x_in,
    float* __restrict__ x_out, const float* __restrict__ sposW,
    const int* __restrict__ coff, const int* __restrict__ csrc,
    const float* __restrict__ csw, const unsigned short* __restrict__ WTgh,
    const unsigned short* __restrict__ WTgl, const float* __restrict__ lng,
    const float* __restrict__ lnb, int last,
    unsigned short* __restrict__ xTh, unsigned short* __restrict__ xTl) {
  __shared__ unsigned Ah[32][132];
  __shared__ unsigned Al[32][132];
  __shared__ unsigned short Bh[2][8192];
  __shared__ unsigned short Bl[2][8192];
  __shared__ float redS[32][8];
  __shared__ float redQ[32][8];
  __shared__ int sed[EMAX];
  __shared__ float wed[EMAX];
  int tid = threadIdx.x;
  // XCD-aware: batch b pinned to one XCD so x(b) stays in its L2
  int id = blockIdx.x;
  int b = id & 7;
  int nb = id >> 3;
  int n0 = nb * 32;
  int wv = tid >> 6, L = tid & 63, lhi = L >> 4, llo = L & 15;

  u32x4_t rbh[2], rbl[2];
  auto loadB = [&](int kc) {
    const u32x4_t* sh = (const u32x4_t*)(WTgh + (size_t)kc * 8192);
    const u32x4_t* sl = (const u32x4_t*)(WTgl + (size_t)kc * 8192);
    #pragma unroll
    for (int i = 0; i < 2; i++) { rbh[i] = sh[tid + i * 512]; rbl[i] = sl[tid + i * 512]; }
  };
  auto writeB = [&](int buf) {
    u32x4_t* dh = (u32x4_t*)Bh[buf];
    u32x4_t* dl = (u32x4_t*)Bl[buf];
    #pragma unroll
    for (int i = 0; i < 2; i++) {
      int es = swz16(tid + i * 512);
      dh[es] = rbh[i]; dl[es] = rbl[i];
    }
  };

  loadB(0);   // in flight during edge staging + gather

  // stage this block's CSR records into LDS (coalesced)
  int e0b = coff[n0];
  int ecnt = coff[n0 + 32] - e0b;
  for (int i = tid; i < ecnt && i < EMAX; i += 512) {
    sed[i] = csrc[e0b + i];
    wed[i] = csw[e0b + i];
  }
  __syncthreads();

  // gather phase: 16 threads per row, 16 features each; per-feature edge order unchanged
  {
    int row = tid >> 4, seg = tid & 15;
    int n = n0 + row;
    float g[16];
    #pragma unroll
    for (int i = 0; i < 16; i++) g[i] = 0.f;
    int e0 = coff[n] - e0b, e1 = coff[n + 1] - e0b;
    for (int e = e0; e < e1; e++) {
      int s; float w;
      if (e < EMAX) { s = sed[e]; w = wed[e]; }
      else { s = csrc[e0b + e]; w = csw[e0b + e]; }
      const f32x4_t* px = (const f32x4_t*)(x_in + ((size_t)b * NN + s) * FF + seg * 16);
      #pragma unroll
      for (int i = 0; i < 4; i++) {
        f32x4_t v = px[i];
        g[4*i]   += w * v[0]; g[4*i+1] += w * v[1];
        g[4*i+2] += w * v[2]; g[4*i+3] += w * v[3];
      }
    }
    #pragma unroll
    for (int i = 0; i < 8; i++) {
      unsigned h, l;
      split_pk(g[2 * i], g[2 * i + 1], h, l);
      Ah[row][seg * 8 + i] = h;
      Al[row][seg * 8 + i] = l;
    }
  }
  writeB(0);

  // preload residual + sposW sums (hidden under GEMM loop)
  f32x4_t szr[2][2];
  #pragma unroll
  for (int rb = 0; rb < 2; rb++)
    #pragma unroll
    for (int cb = 0; cb < 2; cb++) {
      int col = wv * 32 + cb * 16 + llo;
      #pragma unroll
      for (int r = 0; r < 4; r++) {
        int row = rb * 16 + lhi * 4 + r;
        szr[rb][cb][r] = sposW[(size_t)(n0 + row) * FF + col]
                       + x_in[((size_t)b * NN + n0 + row) * FF + col];
      }
    }
  __syncthreads();

  f32x4_t acc[2][2];
  #pragma unroll
  for (int i = 0; i < 2; i++)
    #pragma unroll
    for (int j = 0; j < 2; j++) { f32x4_t t = {0.f, 0.f, 0.f, 0.f}; acc[i][j] = t; }

  for (int kc = 0; kc < 8; kc++) {
    int cur = kc & 1;
    if (kc < 7) loadB(kc + 1);          // loads in flight under MFMA
    u32x4_t a0h = *(const u32x4_t*)&Ah[llo][kc * 16 + lhi * 4];
    u32x4_t a0l = *(const u32x4_t*)&Al[llo][kc * 16 + lhi * 4];
    u32x4_t a1h = *(const u32x4_t*)&Ah[llo + 16][kc * 16 + lhi * 4];
    u32x4_t a1l = *(const u32x4_t*)&Al[llo + 16][kc * 16 + lhi * 4];
    #pragma unroll
    for (int cb = 0; cb < 2; cb++) {
      int off = swz16((wv * 32 + cb * 16 + llo) * 4 + lhi) * 8;
      u32x4_t bh = *(const u32x4_t*)&Bh[cur][off];
      u32x4_t bl = *(const u32x4_t*)&Bl[cur][off];
      acc[0][cb] = mfma16(a0h, bh, mfma16(a0h, bl, mfma16(a0l, bh, acc[0][cb])));
      acc[1][cb] = mfma16(a1h, bh, mfma16(a1h, bl, mfma16(a1l, bh, acc[1][cb])));
    }
    if (kc < 7) writeB(cur ^ 1);
    __syncthreads();
  }

  // epilogue: + (sposW + residual), then LayerNorm
  #pragma unroll
  for (int rb = 0; rb < 2; rb++)
    #pragma unroll
    for (int cb = 0; cb < 2; cb++) {
      #pragma unroll
      for (int r = 0; r < 4; r++) acc[rb][cb][r] += szr[rb][cb][r];
    }
  float ps[2][4], pq[2][4];
  #pragma unroll
  for (int rb = 0; rb < 2; rb++)
    #pragma unroll
    for (int r = 0; r < 4; r++) {
      float s = 0.f, q = 0.f;
      #pragma unroll
      for (int cb = 0; cb < 2; cb++) { float y = acc[rb][cb][r]; s += y; q += y * y; }
      #pragma unroll
      for (int m = 1; m < 16; m <<= 1) { s += __shfl_xor(s, m); q += __shfl_xor(q, m); }
      ps[rb][r] = s; pq[rb][r] = q;
    }
  if (llo == 0) {
    #pragma unroll
    for (int rb = 0; rb < 2; rb++)
      #pragma unroll
      for (int r = 0; r < 4; r++) {
        int row = rb * 16 + lhi * 4 + r;
        redS[row][wv] = ps[rb][r];
        redQ[row][wv] = pq[rb][r];
      }
  }
  __syncthreads();
  float mrs[2][4][2];
  #pragma unroll
  for (int rb = 0; rb < 2; rb++)
    #pragma unroll
    for (int r = 0; r < 4; r++) {
      int row = rb * 16 + lhi * 4 + r;
      float S = 0.f, Q = 0.f;
      #pragma unroll
      for (int wq = 0; wq < 8; wq++) { S += redS[row][wq]; Q += redQ[row][wq]; }
      float mean = S * (1.f / 256.f);
      float var = Q * (1.f / 256.f) - mean * mean;
      mrs[rb][r][0] = mean;
      mrs[rb][r][1] = rsqrtf(var + 1e-5f);
    }
  #pragma unroll
  for (int cb = 0; cb < 2; cb++) {
    int col = wv * 32 + cb * 16 + llo;
    float gg = lng[col], bb = lnb[col];
    #pragma unroll
    for (int rb = 0; rb < 2; rb++)
      #pragma unroll
      for (int r = 0; r < 4; r++) {
        int row = rb * 16 + lhi * 4 + r;
        float o = (acc[rb][cb][r] - mrs[rb][r][0]) * mrs[rb][r][1] * gg + bb;
        if (!last) {
          x_out[((size_t)b * NN + n0 + row) * FF + col] = o;
        } else {
          size_t idx = (((size_t)b * 32 + nb) * 256 + col) * 32 + row;
          unsigned short hh = f2bf(o);
          xTh[idx] = hh;
          xTl[idx] = f2bf(o - ashf(hh));
        }
      }
  }
}

// ---------------- proj2 (64-row tile, single-buffer LDS + reg prefetch) ----------------
__global__ __launch_bounds__(256, 3) void k_proj2(const float* __restrict__ qxy,
    const float* __restrict__ mQ, const float* __restrict__ liQ,
    const float* __restrict__ npos, const unsigned short* __restrict__ xTh,
    const unsigned short* __restrict__ xTl, unsigned short* __restrict__ latTh,
    unsigned short* __restrict__ latTl) {
  __shared__ unsigned short BstH[8192];
  __shared__ unsigned short BstL[8192];
  __shared__ unsigned short AstH[2048];
  __shared__ unsigned short AstL[2048];
  __shared__ float nps[NN * 2];
  int tid = threadIdx.x;
  // XCD-aware: batch b pinned to one XCD so xT(b) stays in its L2
  int id = blockIdx.x;
  int b = id & 7;
  int q64 = id >> 3;             // 0..63 (64-row block)
  int q0 = q64 * 64;
  int wv = tid >> 6, L = tid & 63, lhi = L >> 4, llo = L & 15;
  int aq = tid >> 2, t3 = tid & 3, an8 = t3 * 8;
  int aoff = swz16(aq * 4 + t3) * 8;

  {
    const f32x4_t* s4 = (const f32x4_t*)npos;
    *(f32x4_t*)&nps[tid * 4] = s4[tid];
    *(f32x4_t*)&nps[(tid + 256) * 4] = s4[tid + 256];
  }
  int qg = b * NP + q0 + aq;
  float2 qv = ((const float2*)qxy)[qg];
  float qm = mQ[qg], qli = liQ[qg];
  __syncthreads();

  u32x4_t rbh[4], rbl[4], chv, clv;

  auto coordA = [&](int kc) {
    int nb = kc * 32 + an8;
    float c[8];
    #pragma unroll
    for (int j = 0; j < 8; j++) {
      float nx = nps[(nb + j) * 2], ny = nps[(nb + j) * 2 + 1];
      float dx = qv.x - nx, dy = qv.y - ny;
      c[j] = __expf(-(dx * dx + dy * dy) - qm) * qli;
    }
    unsigned h[4], l[4];
    #pragma unroll
    for (int j = 0; j < 4; j++) split_pk(c[2 * j], c[2 * j + 1], h[j], l[j]);
    u32x4_t th = {h[0], h[1], h[2], h[3]}; chv = th;
    u32x4_t tl = {l[0], l[1], l[2], l[3]}; clv = tl;
  };
  auto loadB = [&](int kc) {
    const u32x4_t* sh = (const u32x4_t*)(xTh + (size_t)(b * 32 + kc) * 8192);
    const u32x4_t* sl = (const u32x4_t*)(xTl + (size_t)(b * 32 + kc) * 8192);
    #pragma unroll
    for (int i = 0; i < 4; i++) { rbh[i] = sh[tid + i * 256]; rbl[i] = sl[tid + i * 256]; }
  };

  f32x4_t acc[4][4];
  #pragma unroll
  for (int i = 0; i < 4; i++)
    #pragma unroll
    for (int j = 0; j < 4; j++) { f32x4_t t = {0.f, 0.f, 0.f, 0.f}; acc[i][j] = t; }

  coordA(0);
  loadB(0);
  int aroff[4];
  #pragma unroll
  for (int rb = 0; rb < 4; rb++) aroff[rb] = swz16((llo + 16 * rb) * 4 + lhi) * 8;
  for (int kc = 0; kc < 32; kc++) {
    __syncthreads();
    #pragma unroll
    for (int i = 0; i < 4; i++) {
      int es = swz16(tid + i * 256);
      ((u32x4_t*)BstH)[es] = rbh[i];
      ((u32x4_t*)BstL)[es] = rbl[i];
    }
    *(u32x4_t*)&AstH[aoff] = chv;
    *(u32x4_t*)&AstL[aoff] = clv;
    __syncthreads();
    if (kc < 31) { loadB(kc + 1); coordA(kc + 1); }
    u32x4_t ah[4], al[4];
    #pragma unroll
    for (int rb = 0; rb < 4; rb++) {
      ah[rb] = *(const u32x4_t*)&AstH[aroff[rb]];
      al[rb] = *(const u32x4_t*)&AstL[aroff[rb]];
    }
    #pragma unroll
    for (int cb = 0; cb < 4; cb++) {
      int off = swz16((wv * 64 + cb * 16 + llo) * 4 + lhi) * 8;
      u32x4_t bh = *(const u32x4_t*)&BstH[off];
      u32x4_t bl = *(const u32x4_t*)&BstL[off];
      #pragma unroll
      for (int rb = 0; rb < 4; rb++)
        acc[rb][cb] = mfma16(ah[rb], bh, mfma16(ah[rb], bl, mfma16(al[rb], bh, acc[rb][cb])));
    }
  }
  #pragma unroll
  for (int rb = 0; rb < 4; rb++)
    #pragma unroll
    for (int cb = 0; cb < 4; cb++) {
      int col = wv * 64 + cb * 16 + llo;
      int fc = col >> 5, kk = col & 31;
      f32x4_t v = acc[rb][cb];
      #pragma unroll
      for (int r = 0; r < 4; r++) {
        int row = rb * 16 + lhi * 4 + r;                 // 0..63
        int bt = b * 128 + q64 * 2 + (row >> 5);
        size_t idx = ((size_t)bt * 8 + fc) * 1024 + (row & 31) * 32 + kk;
        unsigned short hh = f2bf(v[r]);
        latTh[idx] = hh;
        latTl[idx] = f2bf(v[r] - ashf(hh));
      }
    }
}

// ---------------- decoder (single-buffer LDS + reg prefetch) ----------------
__global__ __launch_bounds__(256, 4) void k_decoder(const unsigned short* __restrict__ latTh,
    const unsigned short* __restrict__ latTl, const float* __restrict__ qxy,
    const unsigned short* __restrict__ WTd1h, const unsigned short* __restrict__ WTd1l,
    const float* __restrict__ bd1, const float* __restrict__ Wd1,
    const float* __restrict__ Wd2, const float* __restrict__ bd2, float* __restrict__ out) {
  __shared__ unsigned short BstH[8192];
  __shared__ unsigned short BstL[8192];
  __shared__ unsigned short AstH[1024];
  __shared__ unsigned short AstL[1024];
  __shared__ float qs[32][2];
  __shared__ float red[4][32][3];
  int tid = threadIdx.x;
  int bt = blockIdx.x;
  int wv = tid >> 6, L = tid & 63, lhi = L >> 4, llo = L & 15;

  u32x4_t rbh[4], rbl[4], ra;
  auto loadB = [&](int kc) {
    const u32x4_t* sh = (const u32x4_t*)(WTd1h + (size_t)kc * 8192);
    const u32x4_t* sl = (const u32x4_t*)(WTd1l + (size_t)kc * 8192);
    #pragma unroll
    for (int i = 0; i < 4; i++) { rbh[i] = sh[tid + i * 256]; rbl[i] = sl[tid + i * 256]; }
  };
  auto loadA = [&](int kc) {
    if (tid < 128)
      ra = ((const u32x4_t*)(latTh + ((size_t)bt * 8 + kc) * 1024))[tid];
    else
      ra = ((const u32x4_t*)(latTl + ((size_t)bt * 8 + kc) * 1024))[tid - 128];
  };

  if (tid < 64) qs[tid >> 1][tid & 1] = qxy[((size_t)bt * 32 + (tid >> 1)) * 2 + (tid & 1)];
  loadB(0); loadA(0);
  __syncthreads();

  f32x4_t acc[2][4];
  #pragma unroll
  for (int cb = 0; cb < 4; cb++) {
    int col = wv * 64 + cb * 16 + llo;
    float wa = Wd1[256 * FF + col], wb = Wd1[257 * FF + col], bc = bd1[col];
    #pragma unroll
    for (int rb = 0; rb < 2; rb++) {
      f32x4_t t;
      #pragma unroll
      for (int r = 0; r < 4; r++) {
        int row = rb * 16 + lhi * 4 + r;
        t[r] = bc + qs[row][0] * wa + qs[row][1] * wb;
      }
      acc[rb][cb] = t;
    }
  }

  int a0off = swz16(llo * 4 + lhi) * 8;
  int a1off = swz16((llo + 16) * 4 + lhi) * 8;
  for (int kc = 0; kc < 8; kc++) {
    __syncthreads();
    #pragma unroll
    for (int i = 0; i < 4; i++) {
      int es = swz16(tid + i * 256);
      ((u32x4_t*)BstH)[es] = rbh[i];
      ((u32x4_t*)BstL)[es] = rbl[i];
    }
    if (tid < 128) ((u32x4_t*)AstH)[swz16(tid)] = ra;
    else ((u32x4_t*)AstL)[swz16(tid - 128)] = ra;
    __syncthreads();
    if (kc < 7) { loadB(kc + 1); loadA(kc + 1); }
    u32x4_t a0h = *(const u32x4_t*)&AstH[a0off];
    u32x4_t a0l = *(const u32x4_t*)&AstL[a0off];
    u32x4_t a1h = *(const u32x4_t*)&AstH[a1off];
    u32x4_t a1l = *(const u32x4_t*)&AstL[a1off];
    #pragma unroll
    for (int cb = 0; cb < 4; cb++) {
      int off = swz16((wv * 64 + cb * 16 + llo) * 4 + lhi) * 8;
      u32x4_t bh = *(const u32x4_t*)&BstH[off];
      u32x4_t bl = *(const u32x4_t*)&BstL[off];
      acc[0][cb] = mfma16(a0h, bh, mfma16(a0h, bl, mfma16(a0l, bh, acc[0][cb])));
      acc[1][cb] = mfma16(a1h, bh, mfma16(a1h, bl, mfma16(a1l, bh, acc[1][cb])));
    }
  }

  float po[2][4][3];
  #pragma unroll
  for (int rb = 0; rb < 2; rb++)
    #pragma unroll
    for (int r = 0; r < 4; r++) { po[rb][r][0] = 0.f; po[rb][r][1] = 0.f; po[rb][r][2] = 0.f; }
  #pragma unroll
  for (int rb = 0; rb < 2; rb++)
    #pragma unroll
    for (int cb = 0; cb < 4; cb++) {
      int col = wv * 64 + cb * 16 + llo;
      float w0 = Wd2[col * 3], w1 = Wd2[col * 3 + 1], w2 = Wd2[col * 3 + 2];
      f32x4_t v = acc[rb][cb];
      #pragma unroll
      for (int r = 0; r < 4; r++) {
        float hv = fmaxf(v[r], 0.f);
        po[rb][r][0] += hv * w0; po[rb][r][1] += hv * w1; po[rb][r][2] += hv * w2;
      }
    }
  #pragma unroll
  for (int o = 8; o; o >>= 1)
    #pragma unroll
    for (int rb = 0; rb < 2; rb++)
      #pragma unroll
      for (int r = 0; r < 4; r++) {
        po[rb][r][0] += __shfl_xor(po[rb][r][0], o);
        po[rb][r][1] += __shfl_xor(po[rb][r][1], o);
        po[rb][r][2] += __shfl_xor(po[rb][r][2], o);
      }
  if (llo == 0) {
    #pragma unroll
    for (int rb = 0; rb < 2; rb++)
      #pragma unroll
      for (int r = 0; r < 4; r++) {
        int row = rb * 16 + lhi * 4 + r;
        red[wv][row][0] = po[rb][r][0];
        red[wv][row][1] = po[rb][r][1];
        red[wv][row][2] = po[rb][r][2];
      }
  }
  __syncthreads();
  if (tid < 96) {
    int row = tid / 3, o = tid % 3;
    float s = red[0][row][o] + red[1][row][o] + red[2][row][o] + red[3][row][o] + bd2[o];
    out[((size_t)bt * 32 + row) * 3 + o] = s;
  }
}

extern "C" void kernel_launch(void* const* d_in, const int* in_sizes, int n_in,
                              void* d_out, int out_size, void* d_ws, size_t ws_size,
                              hipStream_t stream) {
  const float* inx = (const float*)d_in[0];
  const float* iny = (const float*)d_in[1];
  const float* qxy = (const float*)d_in[2];
  const float* npos = (const float*)d_in[3];
  const float* We1 = (const float*)d_in[4];
  const float* be1 = (const float*)d_in[5];
  const float* We2 = (const float*)d_in[6];
  const float* be2 = (const float*)d_in[7];
  const float* Wg  = (const float*)d_in[8];
  const float* bg  = (const float*)d_in[9];
  const float* lng = (const float*)d_in[10];
  const float* lnb = (const float*)d_in[11];
  const float* Wd1 = (const float*)d_in[12];
  const float* bd1 = (const float*)d_in[13];
  const float* Wd2 = (const float*)d_in[14];
  const float* bd2 = (const float*)d_in[15];
  const int* eidx  = (const int*)d_in[16];
  float* out = (float*)d_out;

  char* w = (char*)d_ws;
  auto carve = [&](size_t n) { char* p = w; w += (n + 255) & ~(size_t)255; return p; };
  char* encR = carve((size_t)2 * BB * NP * FF * 2);                          // 32 MB
  unsigned short* encTh = (unsigned short*)encR;
  unsigned short* encTl = (unsigned short*)(encR + (size_t)BB * NP * FF * 2);
  unsigned short* latTh = encTh;   // alias (dead after proj1)
  unsigned short* latTl = encTl;
  float* xA = (float*)carve((size_t)BB * NN * FF * 4);                       // 8 MB
  float* xB = (float*)carve((size_t)BB * NN * FF * 4);                       // 8 MB
  unsigned short* xTh = (unsigned short*)carve((size_t)BB * NN * FF * 2);    // 4 MB
  unsigned short* xTl = (unsigned short*)carve((size_t)BB * NN * FF * 2);    // 4 MB
  float* part = (float*)carve((size_t)4 * BB * NN * FF * 4);                 // 32 MB
  float* mI   = (float*)carve((size_t)BB * NP * 4);
  float* liI  = (float*)carve((size_t)BB * NP * 4);
  float* mQ   = (float*)carve((size_t)BB * NP * 4);
  float* liQ  = (float*)carve((size_t)BB * NP * 4);
  unsigned short* WTe2h = (unsigned short*)carve((size_t)8 * 256 * 32 * 2);
  unsigned short* WTe2l = (unsigned short*)carve((size_t)8 * 256 * 32 * 2);
  unsigned short* WTgh  = (unsigned short*)carve((size_t)8 * 256 * 32 * 2);
  unsigned short* WTgl  = (unsigned short*)carve((size_t)8 * 256 * 32 * 2);
  unsigned short* WTd1h = (unsigned short*)carve((size_t)8 * 256 * 32 * 2);
  unsigned short* WTd1l = (unsigned short*)carve((size_t)8 * 256 * 32 * 2);
  float* sposW = (float*)carve((size_t)NN * FF * 4);
  float* dinv = (float*)carve(NN * 4);
  float* spos = (float*)carve(NN * 2 * 4);
  float* csw  = (float*)carve((NE + NN) * 4);
  int* coff   = (int*)carve((NN + 1) * 4);
  int* csrc   = (int*)carve((NE + NN) * 4);
  int* cntg   = (int*)carve((size_t)NSEG * NN * 4);

  const int* esrc = eidx;
  const int* edst = eidx + NE;

  k_cnt<<<dim3(NSEG), dim3(1024), 0, stream>>>(edst, cntg);
  k_scan2<<<dim3(1), dim3(1024), 0, stream>>>(cntg, dinv, coff);
  k_fill2<<<dim3(NSEG + 1), dim3(1024), 0, stream>>>(esrc, edst, dinv, coff, cntg, csrc, csw);
  k_spos<<<dim3(4), dim3(256), 0, stream>>>(npos, coff, csrc, csw, spos);
  k_posb<<<dim3(NN), dim3(256), 0, stream>>>(spos, Wg, bg, sposW);
  k_pack_w<<<dim3(8, 3), dim3(256), 0, stream>>>(We2, Wg, Wd1, WTe2h, WTe2l, WTgh, WTgl,
                                                 WTd1h, WTd1l);

  k_stats<<<dim3(BB * NP / 4, 2), dim3(256), 0, stream>>>(inx, qxy, npos, mI, liI, mQ, liQ);
  k_encoder<<<dim3(BB * NP / 32), dim3(256), 0, stream>>>(inx, iny, We1, be1, WTe2h, WTe2l, be2,
                                                          encTh, encTl);
  k_proj1<<<dim3(1024), dim3(256), 0, stream>>>(inx, mI, liI, npos, encTh, encTl, part);
  k_reduce<<<dim3(BB * NN * FF / 1024), dim3(256), 0, stream>>>(part, xA);
  for (int s = 0; s < NSTEP; s++) {
    const float* xi = (s & 1) ? xB : xA;
    float* xo = (s & 1) ? xA : xB;
    k_msg2<<<dim3(256), dim3(512), 0, stream>>>(xi, xo, sposW, coff, csrc, csw,
                                                WTgh, WTgl, lng, lnb,
                                                (s == NSTEP - 1) ? 1 : 0, xTh, xTl);
  }
  k_proj2<<<dim3(512), dim3(256), 0, stream>>>(qxy, mQ, liQ, npos, xTh, xTl, latTh, latTl);
  k_decoder<<<dim3(BB * NP / 32), dim3(256), 0, stream>>>(latTh, latTl, qxy, WTd1h, WTd1l,
                                                          bd1, Wd1, Wd2, bd2, out);
}